// Round 1
// baseline (9659.272 us; speedup 1.0000x reference)
//
#include <hip/hip_runtime.h>
#include <math.h>

#define B_   2048
#define D_   256
#define H_   8
#define DEP_ 32
#define P_   81
#define FF_  1024
#define CHW  (D_*P_)      // 20736
#define NPOS (B_*P_)      // 165888
#define KREL (D_*P_)      // 20736 (flattened x per batch)
#define NTOT (B_*CHW)     // 42467328
#define EPS_ 1e-5f

__device__ __forceinline__ float bf2f(unsigned short u){
    return __uint_as_float(((unsigned int)u) << 16);
}
__device__ __forceinline__ unsigned short f2bf(float f){
    unsigned int x = __float_as_uint(f);
    return (unsigned short)((x + 0x7FFFu + ((x >> 16) & 1u)) >> 16); // RNE
}

// ---------------- K00: rel_w1 -> bf16 ----------------
__global__ __launch_bounds__(256) void k_conv_w1(const float* __restrict__ w,
                                                 unsigned short* __restrict__ o, int n){
    int i = blockIdx.x * 256 + threadIdx.x;
    int st = gridDim.x * 256;
    for (; i < n; i += st) o[i] = f2bf(w[i]);
}

// ---------------- K0: h[b][j] = sum_i x[b,i]*rel_w1[j,i] ----------------
__global__ __launch_bounds__(256) void k_h(const float* __restrict__ x,
                                           const unsigned short* __restrict__ w1b,
                                           float* __restrict__ h){
    const int b = blockIdx.x, t = threadIdx.x;
    const float* xb = x + (size_t)b * CHW;
    float acc[32];
    #pragma unroll
    for (int j = 0; j < 32; ++j) acc[j] = 0.f;
    for (int i4 = t * 4; i4 < CHW; i4 += 1024){
        const float4 xv = *(const float4*)(xb + i4);
        #pragma unroll 8
        for (int j = 0; j < 32; ++j){
            const uint2 wv = *(const uint2*)(w1b + (size_t)j * KREL + i4);
            float w0 = bf2f((unsigned short)(wv.x & 0xffffu));
            float w1 = bf2f((unsigned short)(wv.x >> 16));
            float w2 = bf2f((unsigned short)(wv.y & 0xffffu));
            float w3 = bf2f((unsigned short)(wv.y >> 16));
            acc[j] += xv.x * w0 + xv.y * w1 + xv.z * w2 + xv.w * w3;
        }
    }
    __shared__ float red[264 * 33];
    #pragma unroll
    for (int j = 0; j < 32; ++j) red[t * 33 + j] = acc[j];
    __syncthreads();
    {
        const int j = t & 31, g = t >> 5; // 8 groups of 32 rows
        float s = 0.f;
        for (int r = g * 32; r < g * 32 + 32; ++r) s += red[r * 33 + j];
        red[(256 + g) * 33 + j] = s;
    }
    __syncthreads();
    if (t < 32){
        float v = 0.f;
        #pragma unroll
        for (int g2 = 0; g2 < 8; ++g2) v += red[(256 + g2) * 33 + t];
        h[b * 32 + t] = v;
    }
}

// ---------------- K1: per-batch attention -> att (into d_out) ----------------
// qkv row c (0..767): out[c][p] = sum_i qkv_w[c][i] * x[b][(c/96)*32+i][p]
// q: rows h*32+d ; k: 256+h*32+d ; v: 512+h*32+d
// scores = q @ (k + r) / sqrt(32); softmax over keys; att[h*32+d][p] = sum_j aw[p][j] v[j][d]
__global__ __launch_bounds__(256) void k_attn(const float* __restrict__ x,
                                              const float* __restrict__ qkvw,
                                              const float* __restrict__ relw2,
                                              const float* __restrict__ h,
                                              float* __restrict__ att){
    const int b = blockIdx.x, t = threadIdx.x;
    const float* xb = x + (size_t)b * CHW;
    __shared__ float A[81 * 33];   // q  [p][d] pitch 33
    __shared__ float Bm[32 * 81];  // k+r then v  [d][p]
    __shared__ float C[81 * 81];   // scores [pq][pk]
    __shared__ float R[32 * 81];   // r bias [d][p]
    __shared__ float hb[32];
    if (t < 32) hb[t] = h[b * 32 + t];
    __syncthreads();
    for (int m = t; m < 2592; m += 256){
        const float* wr = relw2 + (size_t)m * 32;
        float s = 0.f;
        #pragma unroll
        for (int j = 0; j < 32; ++j) s += hb[j] * wr[j];
        R[m] = s;  // m = d*81 + p
    }
    __syncthreads();
    const float scale = 0.17677669529663687f; // 1/sqrt(32)
    for (int hh = 0; hh < H_; ++hh){
        // q
        for (int idx = t; idx < 2592; idx += 256){
            int p = idx % 81, d = idx / 81;
            int row = hh * 32 + d;
            const float* wq = qkvw + row * 32;
            const float* xg = xb + (row / 96) * 32 * 81 + p;
            float s = 0.f;
            #pragma unroll
            for (int i = 0; i < 32; ++i) s += wq[i] * xg[i * 81];
            A[p * 33 + d] = s;
        }
        // k + r
        for (int idx = t; idx < 2592; idx += 256){
            int p = idx % 81, d = idx / 81;
            int row = 256 + hh * 32 + d;
            const float* wk = qkvw + row * 32;
            const float* xg = xb + (row / 96) * 32 * 81 + p;
            float s = R[d * 81 + p];
            #pragma unroll
            for (int i = 0; i < 32; ++i) s += wk[i] * xg[i * 81];
            Bm[d * 81 + p] = s;
        }
        __syncthreads();
        // scores
        for (int idx = t; idx < 6561; idx += 256){
            int pq = idx / 81, pk = idx - pq * 81;
            const float* arow = A + pq * 33;
            float s = 0.f;
            #pragma unroll 8
            for (int d = 0; d < 32; ++d) s += arow[d] * Bm[d * 81 + pk];
            C[idx] = s * scale;
        }
        __syncthreads();
        // v into Bm (scores already consumed into C)
        for (int idx = t; idx < 2592; idx += 256){
            int j = idx % 81, d = idx / 81;
            int row = 512 + hh * 32 + d;
            const float* wv = qkvw + row * 32;
            const float* xg = xb + (row / 96) * 32 * 81 + j;
            float s = 0.f;
            #pragma unroll
            for (int i = 0; i < 32; ++i) s += wv[i] * xg[i * 81];
            Bm[d * 81 + j] = s;
        }
        // softmax rows
        if (t < 81){
            float* crow = C + t * 81;
            float m = crow[0];
            for (int j = 1; j < 81; ++j) m = fmaxf(m, crow[j]);
            float s = 0.f;
            for (int j = 0; j < 81; ++j){ float e = __expf(crow[j] - m); crow[j] = e; s += e; }
            float inv = 1.f / s;
            for (int j = 0; j < 81; ++j) crow[j] *= inv;
        }
        __syncthreads();
        // att = aw @ v, store
        float* ob = att + (size_t)b * CHW + (hh * 32) * 81;
        for (int idx = t; idx < 2592; idx += 256){
            int p = idx % 81, d = idx / 81;
            const float* crow = C + p * 81;
            const float* vrow = Bm + d * 81;
            float s = 0.f;
            #pragma unroll 9
            for (int j = 0; j < 81; ++j) s += crow[j] * vrow[j];
            ob[d * 81 + p] = s;
        }
        __syncthreads();
    }
}

// ---------------- K1b: y = o_w @ att + x  (in-place over att in d_out) ----------------
__global__ __launch_bounds__(256) void k_oproj(const float* __restrict__ x,
                                               const float* __restrict__ ow,
                                               float* __restrict__ y){
    const int blk = blockIdx.x;
    const int b = blk >> 1, half = blk & 1;
    const int t = threadIdx.x;
    const int p0 = half * 41;
    const int np = half ? 40 : 41;
    __shared__ float att[256 * 41];
    __shared__ unsigned short owt[32 * 258]; // [c_local][o] pitch 258
    float* yb = y + (size_t)b * CHW;
    for (int idx = t; idx < 256 * 41; idx += 256){
        int pp = idx % 41, c = idx / 41;
        float v = 0.f;
        if (pp < np) v = yb[c * 81 + p0 + pp];
        att[c * 41 + pp] = v;
    }
    __syncthreads();
    float acc[41];
    const float* xrow = x + (size_t)b * CHW + t * 81 + p0;
    #pragma unroll
    for (int pp = 0; pp < 41; ++pp){
        float v = 0.f;
        if (pp < np) v = xrow[pp];
        acc[pp] = v;
    }
    for (int ct = 0; ct < 8; ++ct){
        __syncthreads();
        for (int idx = t; idx < 32 * 256; idx += 256){
            int cl = idx & 31, o2 = idx >> 5;
            owt[cl * 258 + o2] = f2bf(ow[o2 * 256 + ct * 32 + cl]);
        }
        __syncthreads();
        #pragma unroll 4
        for (int cl = 0; cl < 32; ++cl){
            float w = bf2f(owt[cl * 258 + t]);
            const float* arow = att + (ct * 32 + cl) * 41;
            #pragma unroll
            for (int pp = 0; pp < 41; ++pp) acc[pp] += w * arow[pp];
        }
    }
    __syncthreads();
    #pragma unroll
    for (int pp = 0; pp < 41; ++pp)
        if (pp < np) yb[t * 81 + p0 + pp] = acc[pp];
}

// ---------------- stats: per-channel mean / rstd over (B,P) ----------------
__global__ __launch_bounds__(256) void k_stats(const float* __restrict__ buf,
                                               float* __restrict__ mean, float* __restrict__ rstd){
    const int c = blockIdx.x, t = threadIdx.x;
    float s = 0.f, q = 0.f;
    for (int idx = t; idx < NPOS; idx += 256){
        int b = idx / 81, p = idx - b * 81;
        float v = buf[(size_t)b * CHW + c * 81 + p];
        s += v; q += v * v;
    }
    __shared__ float rs[256], rq[256];
    rs[t] = s; rq[t] = q;
    __syncthreads();
    for (int k = 128; k; k >>= 1){
        if (t < k){ rs[t] += rs[t + k]; rq[t] += rq[t + k]; }
        __syncthreads();
    }
    if (t == 0){
        float m = rs[0] / (float)NPOS;
        float var = rq[0] / (float)NPOS - m * m;
        mean[c] = m;
        rstd[c] = rsqrtf(var + EPS_);
    }
}

// ---------------- K3: fused FF, in-place z = x1 + W2*gelu(W1*x1) ----------------
__global__ __launch_bounds__(256) void k_ff(const float* __restrict__ w1,
                                            const float* __restrict__ w2,
                                            const float* __restrict__ mean1, const float* __restrict__ rstd1,
                                            const float* __restrict__ g1, const float* __restrict__ b1,
                                            float* __restrict__ yz){
    const int blk = blockIdx.x;
    const int b = blk / 6, tile = blk - b * 6;
    const int p0 = tile * 16;
    const int np = (81 - p0) < 16 ? (81 - p0) : 16;
    const int t = threadIdx.x;
    __shared__ __align__(16) float x1s[256 * 20];
    __shared__ __align__(16) float ff1s[64 * 20];
    __shared__ __align__(16) unsigned short wbuf[256 * 66]; // W1 chunk [64][258] or W2 chunk [256][66]
    float* zb = yz + (size_t)b * CHW;
    for (int idx = t; idx < 4096; idx += 256){
        int pp = idx & 15, c = idx >> 4;
        float v = 0.f;
        if (pp < np){
            float yv = zb[c * 81 + p0 + pp];
            v = (yv - mean1[c]) * rstd1[c] * g1[c] + b1[c];
        }
        x1s[c * 20 + pp] = v;
    }
    __syncthreads();
    float z[16];
    #pragma unroll
    for (int pp = 0; pp < 16; ++pp) z[pp] = x1s[t * 20 + pp]; // residual
    const int fl = t & 63, pg = t >> 6;
    for (int fc = 0; fc < 16; ++fc){
        // stage W1 chunk [64 f][256 c] pitch 258 (bf16)
        for (int idx = t; idx < 8192; idx += 256){
            int cc2 = idx & 127, fr = idx >> 7;
            const float2 wv = *(const float2*)(w1 + (size_t)(fc * 64 + fr) * 256 + cc2 * 2);
            ((unsigned int*)wbuf)[fr * 129 + cc2] =
                (unsigned int)f2bf(wv.x) | ((unsigned int)f2bf(wv.y) << 16);
        }
        __syncthreads();
        {   // ff1 = gelu(W1 @ x1) for this 64-row chunk
            float a0 = 0, a1 = 0, a2 = 0, a3 = 0;
            const unsigned short* wr = wbuf + fl * 258;
            const float* xcol = x1s + pg * 4;
            #pragma unroll 4
            for (int cc = 0; cc < 256; ++cc){
                float w = bf2f(wr[cc]);
                const float4 xq = *(const float4*)(xcol + cc * 20);
                a0 += w * xq.x; a1 += w * xq.y; a2 += w * xq.z; a3 += w * xq.w;
            }
            float* fr = ff1s + fl * 20 + pg * 4;
            fr[0] = 0.5f * a0 * (1.f + erff(a0 * 0.7071067811865475f));
            fr[1] = 0.5f * a1 * (1.f + erff(a1 * 0.7071067811865475f));
            fr[2] = 0.5f * a2 * (1.f + erff(a2 * 0.7071067811865475f));
            fr[3] = 0.5f * a3 * (1.f + erff(a3 * 0.7071067811865475f));
        }
        __syncthreads();
        // stage W2 chunk [256 c][64 f] pitch 66 (bf16)
        for (int idx = t; idx < 8192; idx += 256){
            int f2 = idx & 31, c = idx >> 5;
            const float2 wv = *(const float2*)(w2 + (size_t)c * 1024 + fc * 64 + f2 * 2);
            ((unsigned int*)wbuf)[c * 33 + f2] =
                (unsigned int)f2bf(wv.x) | ((unsigned int)f2bf(wv.y) << 16);
        }
        __syncthreads();
        {   // z += W2chunk @ ff1chunk
            const unsigned short* wr = wbuf + t * 66;
            #pragma unroll 2
            for (int f = 0; f < 64; ++f){
                float w = bf2f(wr[f]);
                const float* fr = ff1s + f * 20;
                const float4 q0 = *(const float4*)(fr);
                const float4 q1 = *(const float4*)(fr + 4);
                const float4 q2 = *(const float4*)(fr + 8);
                const float4 q3 = *(const float4*)(fr + 12);
                z[0] += w * q0.x;  z[1] += w * q0.y;  z[2] += w * q0.z;  z[3] += w * q0.w;
                z[4] += w * q1.x;  z[5] += w * q1.y;  z[6] += w * q1.z;  z[7] += w * q1.w;
                z[8] += w * q2.x;  z[9] += w * q2.y;  z[10] += w * q2.z; z[11] += w * q2.w;
                z[12] += w * q3.x; z[13] += w * q3.y; z[14] += w * q3.z; z[15] += w * q3.w;
            }
        }
        __syncthreads();
    }
    // write z back through LDS transpose (coalesced)
    #pragma unroll
    for (int pp = 0; pp < 16; ++pp) x1s[t * 20 + pp] = z[pp];
    __syncthreads();
    for (int idx = t; idx < 4096; idx += 256){
        int pp = idx & 15, c = idx >> 4;
        if (pp < np) zb[c * 81 + p0 + pp] = x1s[c * 20 + pp];
    }
}

// ---------------- K5: BN apply in-place ----------------
__global__ __launch_bounds__(256) void k_bnapply(float* __restrict__ z,
                                                 const float* __restrict__ mean, const float* __restrict__ rstd,
                                                 const float* __restrict__ g, const float* __restrict__ bia,
                                                 unsigned int n){
    unsigned int i = blockIdx.x * 256u + threadIdx.x;
    unsigned int st = gridDim.x * 256u;
    for (; i < n; i += st){
        int c = (int)((i / 81u) & 255u);
        float v = z[i];
        z[i] = (v - mean[c]) * rstd[c] * g[c] + bia[c];
    }
}

extern "C" void kernel_launch(void* const* d_in, const int* in_sizes, int n_in,
                              void* d_out, int out_size, void* d_ws, size_t ws_size,
                              hipStream_t stream){
    const float* x     = (const float*)d_in[0];
    const float* qkvw  = (const float*)d_in[1];
    const float* relw1 = (const float*)d_in[2];
    const float* relw2 = (const float*)d_in[3];
    const float* ow    = (const float*)d_in[4];
    const float* ffw1  = (const float*)d_in[5];
    const float* ffw2  = (const float*)d_in[6];
    const float* g1    = (const float*)d_in[7];
    const float* b1    = (const float*)d_in[8];
    const float* g2    = (const float*)d_in[9];
    const float* b2    = (const float*)d_in[10];
    float* out = (float*)d_out;
    char* ws = (char*)d_ws;

    unsigned short* w1b = (unsigned short*)ws;            // 663552 * 2 = 1,327,104 B
    float* h     = (float*)(ws + 1327104);                // 2048*32*4 = 262,144 B
    float* mean1 = (float*)(ws + 1589248);
    float* rstd1 = (float*)(ws + 1590272);
    float* mean2 = (float*)(ws + 1591296);
    float* rstd2 = (float*)(ws + 1592320);

    hipLaunchKernelGGL(k_conv_w1, dim3(1024), dim3(256), 0, stream, relw1, w1b, 663552);
    hipLaunchKernelGGL(k_h,       dim3(2048), dim3(256), 0, stream, x, w1b, h);
    hipLaunchKernelGGL(k_attn,    dim3(2048), dim3(256), 0, stream, x, qkvw, relw2, h, out);
    hipLaunchKernelGGL(k_oproj,   dim3(4096), dim3(256), 0, stream, x, ow, out);
    hipLaunchKernelGGL(k_stats,   dim3(256),  dim3(256), 0, stream, out, mean1, rstd1);
    hipLaunchKernelGGL(k_ff,      dim3(12288),dim3(256), 0, stream, ffw1, ffw2, mean1, rstd1, g1, b1, out);
    hipLaunchKernelGGL(k_stats,   dim3(256),  dim3(256), 0, stream, out, mean2, rstd2);
    hipLaunchKernelGGL(k_bnapply, dim3(2048), dim3(256), 0, stream, out, mean2, rstd2, g2, b2, (unsigned int)NTOT);
}

// Round 2
// 3793.256 us; speedup vs baseline: 2.5464x; 2.5464x over previous
//
#include <hip/hip_runtime.h>
#include <math.h>

#define B_   2048
#define D_   256
#define H_   8
#define DEP_ 32
#define P_   81
#define FF_  1024
#define CHW  (D_*P_)      // 20736
#define NPOS (B_*P_)      // 165888
#define KREL (D_*P_)      // 20736
#define NTOT (B_*CHW)     // 42467328
#define EPS_ 1e-5f

typedef __attribute__((ext_vector_type(8))) short short8v;
typedef __attribute__((ext_vector_type(4))) short short4v;
typedef __attribute__((ext_vector_type(4))) float f32x4;

__device__ __forceinline__ float bf2f(unsigned short u){
    return __uint_as_float(((unsigned int)u) << 16);
}
__device__ __forceinline__ unsigned short f2bf(float f){
    unsigned int x = __float_as_uint(f);
    return (unsigned short)((x + 0x7FFFu + ((x >> 16) & 1u)) >> 16); // RNE
}

// ---------------- generic f32 -> bf16 cast ----------------
__global__ __launch_bounds__(256) void k_f2bf(const float* __restrict__ w,
                                              unsigned short* __restrict__ o, int n){
    int i = blockIdx.x * 256 + threadIdx.x;
    int st = gridDim.x * 256;
    for (; i < n; i += st) o[i] = f2bf(w[i]);
}

// ---------------- K0: h[b][j] = sum_i x[b,i]*rel_w1[j,i] ----------------
__global__ __launch_bounds__(256) void k_h(const float* __restrict__ x,
                                           const unsigned short* __restrict__ w1b,
                                           float* __restrict__ h){
    const int b = blockIdx.x, t = threadIdx.x;
    const float* xb = x + (size_t)b * CHW;
    float acc[32];
    #pragma unroll
    for (int j = 0; j < 32; ++j) acc[j] = 0.f;
    for (int i4 = t * 4; i4 < CHW; i4 += 1024){
        const float4 xv = *(const float4*)(xb + i4);
        #pragma unroll 8
        for (int j = 0; j < 32; ++j){
            const uint2 wv = *(const uint2*)(w1b + (size_t)j * KREL + i4);
            float w0 = bf2f((unsigned short)(wv.x & 0xffffu));
            float w1 = bf2f((unsigned short)(wv.x >> 16));
            float w2 = bf2f((unsigned short)(wv.y & 0xffffu));
            float w3 = bf2f((unsigned short)(wv.y >> 16));
            acc[j] += xv.x * w0 + xv.y * w1 + xv.z * w2 + xv.w * w3;
        }
    }
    __shared__ float red[264 * 33];
    #pragma unroll
    for (int j = 0; j < 32; ++j) red[t * 33 + j] = acc[j];
    __syncthreads();
    {
        const int j = t & 31, g = t >> 5;
        float s = 0.f;
        for (int r = g * 32; r < g * 32 + 32; ++r) s += red[r * 33 + j];
        red[(256 + g) * 33 + j] = s;
    }
    __syncthreads();
    if (t < 32){
        float v = 0.f;
        #pragma unroll
        for (int g2 = 0; g2 < 8; ++g2) v += red[(256 + g2) * 33 + t];
        h[b * 32 + t] = v;
    }
}

// ---------------- K1: per-batch attention -> att (into d_out) ----------------
__global__ __launch_bounds__(256) void k_attn(const float* __restrict__ x,
                                              const float* __restrict__ qkvw,
                                              const float* __restrict__ relw2,
                                              const float* __restrict__ h,
                                              float* __restrict__ att){
    const int b = blockIdx.x, t = threadIdx.x;
    const float* xb = x + (size_t)b * CHW;
    __shared__ float A[81 * 33];
    __shared__ float Bm[32 * 81];
    __shared__ float C[81 * 81];
    __shared__ float R[32 * 81];
    __shared__ float hb[32];
    if (t < 32) hb[t] = h[b * 32 + t];
    __syncthreads();
    for (int m = t; m < 2592; m += 256){
        const float* wr = relw2 + (size_t)m * 32;
        float s = 0.f;
        #pragma unroll
        for (int j = 0; j < 32; ++j) s += hb[j] * wr[j];
        R[m] = s;
    }
    __syncthreads();
    const float scale = 0.17677669529663687f;
    for (int hh = 0; hh < H_; ++hh){
        for (int idx = t; idx < 2592; idx += 256){
            int p = idx % 81, d = idx / 81;
            int row = hh * 32 + d;
            const float* wq = qkvw + row * 32;
            const float* xg = xb + (row / 96) * 32 * 81 + p;
            float s = 0.f;
            #pragma unroll
            for (int i = 0; i < 32; ++i) s += wq[i] * xg[i * 81];
            A[p * 33 + d] = s;
        }
        for (int idx = t; idx < 2592; idx += 256){
            int p = idx % 81, d = idx / 81;
            int row = 256 + hh * 32 + d;
            const float* wk = qkvw + row * 32;
            const float* xg = xb + (row / 96) * 32 * 81 + p;
            float s = R[d * 81 + p];
            #pragma unroll
            for (int i = 0; i < 32; ++i) s += wk[i] * xg[i * 81];
            Bm[d * 81 + p] = s;
        }
        __syncthreads();
        for (int idx = t; idx < 6561; idx += 256){
            int pq = idx / 81, pk = idx - pq * 81;
            const float* arow = A + pq * 33;
            float s = 0.f;
            #pragma unroll 8
            for (int d = 0; d < 32; ++d) s += arow[d] * Bm[d * 81 + pk];
            C[idx] = s * scale;
        }
        __syncthreads();
        for (int idx = t; idx < 2592; idx += 256){
            int j = idx % 81, d = idx / 81;
            int row = 512 + hh * 32 + d;
            const float* wv = qkvw + row * 32;
            const float* xg = xb + (row / 96) * 32 * 81 + j;
            float s = 0.f;
            #pragma unroll
            for (int i = 0; i < 32; ++i) s += wv[i] * xg[i * 81];
            Bm[d * 81 + j] = s;
        }
        if (t < 81){
            float* crow = C + t * 81;
            float m = crow[0];
            for (int j = 1; j < 81; ++j) m = fmaxf(m, crow[j]);
            float s = 0.f;
            for (int j = 0; j < 81; ++j){ float e = __expf(crow[j] - m); crow[j] = e; s += e; }
            float inv = 1.f / s;
            for (int j = 0; j < 81; ++j) crow[j] *= inv;
        }
        __syncthreads();
        float* ob = att + (size_t)b * CHW + (hh * 32) * 81;
        for (int idx = t; idx < 2592; idx += 256){
            int p = idx % 81, d = idx / 81;
            const float* crow = C + p * 81;
            const float* vrow = Bm + d * 81;
            float s = 0.f;
            #pragma unroll 9
            for (int j = 0; j < 81; ++j) s += crow[j] * vrow[j];
            ob[d * 81 + p] = s;
        }
        __syncthreads();
    }
}

// ---------------- K1b: y = o_w @ att + x  (in-place over att in d_out) ----------------
__global__ __launch_bounds__(256) void k_oproj(const float* __restrict__ x,
                                               const float* __restrict__ ow,
                                               float* __restrict__ y){
    const int blk = blockIdx.x;
    const int b = blk >> 1, half = blk & 1;
    const int t = threadIdx.x;
    const int p0 = half * 41;
    const int np = half ? 40 : 41;
    __shared__ float att[256 * 41];
    __shared__ unsigned short owt[32 * 258];
    float* yb = y + (size_t)b * CHW;
    for (int idx = t; idx < 256 * 41; idx += 256){
        int pp = idx % 41, c = idx / 41;
        float v = 0.f;
        if (pp < np) v = yb[c * 81 + p0 + pp];
        att[c * 41 + pp] = v;
    }
    __syncthreads();
    float acc[41];
    const float* xrow = x + (size_t)b * CHW + t * 81 + p0;
    #pragma unroll
    for (int pp = 0; pp < 41; ++pp){
        float v = 0.f;
        if (pp < np) v = xrow[pp];
        acc[pp] = v;
    }
    for (int ct = 0; ct < 8; ++ct){
        __syncthreads();
        for (int idx = t; idx < 32 * 256; idx += 256){
            int cl = idx & 31, o2 = idx >> 5;
            owt[cl * 258 + o2] = f2bf(ow[o2 * 256 + ct * 32 + cl]);
        }
        __syncthreads();
        #pragma unroll 4
        for (int cl = 0; cl < 32; ++cl){
            float w = bf2f(owt[cl * 258 + t]);
            const float* arow = att + (ct * 32 + cl) * 41;
            #pragma unroll
            for (int pp = 0; pp < 41; ++pp) acc[pp] += w * arow[pp];
        }
    }
    __syncthreads();
    #pragma unroll
    for (int pp = 0; pp < 41; ++pp)
        if (pp < np) yb[t * 81 + p0 + pp] = acc[pp];
}

// ---------------- stats: per-channel mean / rstd over (B,P) ----------------
__global__ __launch_bounds__(256) void k_stats(const float* __restrict__ buf,
                                               float* __restrict__ mean, float* __restrict__ rstd){
    const int c = blockIdx.x, t = threadIdx.x;
    float s = 0.f, q = 0.f;
    for (int idx = t; idx < NPOS; idx += 256){
        int b = idx / 81, p = idx - b * 81;
        float v = buf[(size_t)b * CHW + c * 81 + p];
        s += v; q += v * v;
    }
    __shared__ float rs[256], rq[256];
    rs[t] = s; rq[t] = q;
    __syncthreads();
    for (int k = 128; k; k >>= 1){
        if (t < k){ rs[t] += rs[t + k]; rq[t] += rq[t + k]; }
        __syncthreads();
    }
    if (t == 0){
        float m = rs[0] / (float)NPOS;
        float var = rq[0] / (float)NPOS - m * m;
        mean[c] = m;
        rstd[c] = rsqrtf(var + EPS_);
    }
}

// ---------------- K3: fused FF via MFMA, in-place z = x1 + W2*gelu(W1*x1) ----------------
// block = 1 batch, 256 thr (4 waves). x1s [96 p][264 c] bf16; ffs [96 p][136 f] bf16.
__global__ __launch_bounds__(256, 2) void k_ff_mfma(const unsigned short* __restrict__ w1bf,
                                                    const unsigned short* __restrict__ w2bf,
                                                    const float* __restrict__ mean1, const float* __restrict__ rstd1,
                                                    const float* __restrict__ g1, const float* __restrict__ b1,
                                                    float* __restrict__ yz){
    const int b = blockIdx.x, t = threadIdx.x;
    const int lane = t & 63, w = t >> 6;
    const int lr = lane & 15, lh = lane >> 4;
    float* zb = yz + (size_t)b * CHW;

    __shared__ __align__(16) unsigned short x1s[96 * 264];      // 50688 B
    __shared__ __align__(16) unsigned char ubuf[26112];         // ffs / transpose tile
    unsigned short* ffs = (unsigned short*)ubuf;                // [96][136]
    float* tb = (float*)ubuf;                                   // [64][85]

    // zero pad rows p=81..95 (cols as u32: 132 per row)
    for (int idx = t; idx < 15 * 132; idx += 256){
        int r = idx / 132, c = idx - r * 132;
        *(unsigned int*)&x1s[(81 + r) * 264 + 2 * c] = 0;
    }
    // BN1 + transpose y[c][p] -> x1s[p][c] (bf16), 4 chunks of 64 channels
    for (int cc = 0; cc < 4; ++cc){
        for (int idx = t; idx < 64 * 81; idx += 256){
            int c = idx / 81, p = idx - c * 81;
            int gc = cc * 64 + c;
            float v = zb[gc * 81 + p];
            v = (v - mean1[gc]) * rstd1[gc] * g1[gc] + b1[gc];
            tb[c * 85 + p] = v;
        }
        __syncthreads();
        for (int idx = t; idx < 32 * 81; idx += 256){
            int c2 = idx & 31, p = idx >> 5;
            int c = 2 * c2;
            unsigned int pk = (unsigned int)f2bf(tb[c * 85 + p])
                            | ((unsigned int)f2bf(tb[(c + 1) * 85 + p]) << 16);
            *(unsigned int*)&x1s[p * 264 + cc * 64 + c] = pk;
        }
        __syncthreads();
    }

    const int cw = w * 64;
    f32x4 acc2[4][6];
    #pragma unroll
    for (int ci = 0; ci < 4; ++ci)
    #pragma unroll
    for (int pj = 0; pj < 6; ++pj)
        acc2[ci][pj] = (f32x4){0.f, 0.f, 0.f, 0.f};

    for (int fc = 0; fc < 8; ++fc){
        // ---- GEMM1: ff_chunk[128 f][96 p] = W1[fc*128.., :] @ x1
        f32x4 acc1[2][6];
        #pragma unroll
        for (int fi = 0; fi < 2; ++fi)
        #pragma unroll
        for (int pj = 0; pj < 6; ++pj)
            acc1[fi][pj] = (f32x4){0.f, 0.f, 0.f, 0.f};
        const int fbase = fc * 128 + w * 32;
        for (int ks = 0; ks < 8; ++ks){
            const int k0 = ks * 32 + lh * 8;
            short8v a0 = *(const short8v*)(w1bf + (size_t)(fbase + lr) * 256 + k0);
            short8v a1 = *(const short8v*)(w1bf + (size_t)(fbase + 16 + lr) * 256 + k0);
            #pragma unroll
            for (int pj = 0; pj < 6; ++pj){
                short8v bb = *(const short8v*)(x1s + (pj * 16 + lr) * 264 + k0);
                acc1[0][pj] = __builtin_amdgcn_mfma_f32_16x16x32_bf16(a0, bb, acc1[0][pj], 0, 0, 0);
                acc1[1][pj] = __builtin_amdgcn_mfma_f32_16x16x32_bf16(a1, bb, acc1[1][pj], 0, 0, 0);
            }
        }
        // ---- gelu + store chunk to ffs[p][f_local]
        #pragma unroll
        for (int fi = 0; fi < 2; ++fi)
        #pragma unroll
        for (int pj = 0; pj < 6; ++pj){
            int p = pj * 16 + lr;
            int fl = w * 32 + fi * 16 + lh * 4;
            short4v pk;
            #pragma unroll
            for (int r = 0; r < 4; ++r){
                float v = acc1[fi][pj][r];
                v = 0.5f * v * (1.f + erff(v * 0.70710678118654752f));
                pk[r] = (short)f2bf(v);
            }
            *(short4v*)&ffs[p * 136 + fl] = pk;
        }
        __syncthreads();
        // ---- GEMM2 partial: z[256 c][96 p] += W2[:, fc*128..] @ ff_chunk
        for (int ks = 0; ks < 4; ++ks){
            const int k0 = ks * 32 + lh * 8;
            short8v a2[4];
            #pragma unroll
            for (int ci = 0; ci < 4; ++ci)
                a2[ci] = *(const short8v*)(w2bf + (size_t)(cw + ci * 16 + lr) * 1024 + fc * 128 + k0);
            #pragma unroll
            for (int pj = 0; pj < 6; ++pj){
                short8v bb = *(const short8v*)(ffs + (pj * 16 + lr) * 136 + k0);
                #pragma unroll
                for (int ci = 0; ci < 4; ++ci)
                    acc2[ci][pj] = __builtin_amdgcn_mfma_f32_16x16x32_bf16(a2[ci], bb, acc2[ci][pj], 0, 0, 0);
            }
        }
        __syncthreads();
    }
    // ---- epilogue: z += x1 residual, store to yz[b][c][p]
    #pragma unroll
    for (int ci = 0; ci < 4; ++ci)
    #pragma unroll
    for (int pj = 0; pj < 6; ++pj){
        int p = pj * 16 + lr;
        if (p < 81){
            int c = cw + ci * 16 + lh * 4;
            short4v res = *(const short4v*)&x1s[p * 264 + c];
            #pragma unroll
            for (int r = 0; r < 4; ++r)
                zb[(c + r) * 81 + p] = acc2[ci][pj][r] + bf2f((unsigned short)res[r]);
        }
    }
}

// ---------------- K5: BN apply in-place ----------------
__global__ __launch_bounds__(256) void k_bnapply(float* __restrict__ z,
                                                 const float* __restrict__ mean, const float* __restrict__ rstd,
                                                 const float* __restrict__ g, const float* __restrict__ bia,
                                                 unsigned int n){
    unsigned int i = blockIdx.x * 256u + threadIdx.x;
    unsigned int st = gridDim.x * 256u;
    for (; i < n; i += st){
        int c = (int)((i / 81u) & 255u);
        float v = z[i];
        z[i] = (v - mean[c]) * rstd[c] * g[c] + bia[c];
    }
}

extern "C" void kernel_launch(void* const* d_in, const int* in_sizes, int n_in,
                              void* d_out, int out_size, void* d_ws, size_t ws_size,
                              hipStream_t stream){
    const float* x     = (const float*)d_in[0];
    const float* qkvw  = (const float*)d_in[1];
    const float* relw1 = (const float*)d_in[2];
    const float* relw2 = (const float*)d_in[3];
    const float* ow    = (const float*)d_in[4];
    const float* ffw1  = (const float*)d_in[5];
    const float* ffw2  = (const float*)d_in[6];
    const float* g1    = (const float*)d_in[7];
    const float* b1    = (const float*)d_in[8];
    const float* g2    = (const float*)d_in[9];
    const float* b2    = (const float*)d_in[10];
    float* out = (float*)d_out;
    char* ws = (char*)d_ws;

    unsigned short* w1rel = (unsigned short*)ws;          // 663552*2 = 1,327,104 B
    float* h     = (float*)(ws + 1327104);                // 262,144 B
    float* mean1 = (float*)(ws + 1589248);
    float* rstd1 = (float*)(ws + 1590272);
    float* mean2 = (float*)(ws + 1591296);
    float* rstd2 = (float*)(ws + 1592320);
    unsigned short* w1bf = (unsigned short*)(ws + 1593344); // 524,288 B
    unsigned short* w2bf = (unsigned short*)(ws + 2117632); // 524,288 B

    hipLaunchKernelGGL(k_f2bf, dim3(1024), dim3(256), 0, stream, relw1, w1rel, 663552);
    hipLaunchKernelGGL(k_f2bf, dim3(256),  dim3(256), 0, stream, ffw1, w1bf, 262144);
    hipLaunchKernelGGL(k_f2bf, dim3(256),  dim3(256), 0, stream, ffw2, w2bf, 262144);
    hipLaunchKernelGGL(k_h,    dim3(2048), dim3(256), 0, stream, x, w1rel, h);
    hipLaunchKernelGGL(k_attn, dim3(2048), dim3(256), 0, stream, x, qkvw, relw2, h, out);
    hipLaunchKernelGGL(k_oproj,dim3(4096), dim3(256), 0, stream, x, ow, out);
    hipLaunchKernelGGL(k_stats,dim3(256),  dim3(256), 0, stream, out, mean1, rstd1);
    hipLaunchKernelGGL(k_ff_mfma, dim3(2048), dim3(256), 0, stream, w1bf, w2bf, mean1, rstd1, g1, b1, out);
    hipLaunchKernelGGL(k_stats,dim3(256),  dim3(256), 0, stream, out, mean2, rstd2);
    hipLaunchKernelGGL(k_bnapply, dim3(2048), dim3(256), 0, stream, out, mean2, rstd2, g2, b2, (unsigned int)NTOT);
}

// Round 3
// 2390.978 us; speedup vs baseline: 4.0399x; 1.5865x over previous
//
#include <hip/hip_runtime.h>
#include <math.h>

#define B_   2048
#define D_   256
#define H_   8
#define DEP_ 32
#define P_   81
#define FF_  1024
#define CHW  (D_*P_)      // 20736
#define NPOS (B_*P_)      // 165888
#define KREL (D_*P_)      // 20736
#define NTOT (B_*CHW)     // 42467328
#define EPS_ 1e-5f

typedef __attribute__((ext_vector_type(8))) short short8v;
typedef __attribute__((ext_vector_type(4))) short short4v;
typedef __attribute__((ext_vector_type(4))) float f32x4;

__device__ __forceinline__ float bf2f(unsigned short u){
    return __uint_as_float(((unsigned int)u) << 16);
}
__device__ __forceinline__ unsigned short f2bf(float f){
    unsigned int x = __float_as_uint(f);
    return (unsigned short)((x + 0x7FFFu + ((x >> 16) & 1u)) >> 16); // RNE
}

// ---------------- generic f32 -> bf16 cast ----------------
__global__ __launch_bounds__(256) void k_f2bf(const float* __restrict__ w,
                                              unsigned short* __restrict__ o, int n){
    int i = blockIdx.x * 256 + threadIdx.x;
    int st = gridDim.x * 256;
    for (; i < n; i += st) o[i] = f2bf(w[i]);
}

// ---------------- K0: h[b][j] = sum_i x[b,i]*rel_w1[j,i] ----------------
__global__ __launch_bounds__(256) void k_h(const float* __restrict__ x,
                                           const unsigned short* __restrict__ w1b,
                                           float* __restrict__ h){
    const int b = blockIdx.x, t = threadIdx.x;
    const float* xb = x + (size_t)b * CHW;
    float acc[32];
    #pragma unroll
    for (int j = 0; j < 32; ++j) acc[j] = 0.f;
    for (int i4 = t * 4; i4 < CHW; i4 += 1024){
        const float4 xv = *(const float4*)(xb + i4);
        #pragma unroll 8
        for (int j = 0; j < 32; ++j){
            const uint2 wv = *(const uint2*)(w1b + (size_t)j * KREL + i4);
            float w0 = bf2f((unsigned short)(wv.x & 0xffffu));
            float w1 = bf2f((unsigned short)(wv.x >> 16));
            float w2 = bf2f((unsigned short)(wv.y & 0xffffu));
            float w3 = bf2f((unsigned short)(wv.y >> 16));
            acc[j] += xv.x * w0 + xv.y * w1 + xv.z * w2 + xv.w * w3;
        }
    }
    __shared__ float red[264 * 33];
    #pragma unroll
    for (int j = 0; j < 32; ++j) red[t * 33 + j] = acc[j];
    __syncthreads();
    {
        const int j = t & 31, g = t >> 5;
        float s = 0.f;
        for (int r = g * 32; r < g * 32 + 32; ++r) s += red[r * 33 + j];
        red[(256 + g) * 33 + j] = s;
    }
    __syncthreads();
    if (t < 32){
        float v = 0.f;
        #pragma unroll
        for (int g2 = 0; g2 < 8; ++g2) v += red[(256 + g2) * 33 + t];
        h[b * 32 + t] = v;
    }
}

// ---------------- K1: per-batch MFMA attention -> att (into d_out) ----------------
// 4 waves, wave w handles heads w and w+4 privately.
// scores^T = mfma(Kr, Q): lane holds (pk = mt*16+lh*4+r, pq = nt*16+lr) -> softmax over pk
// is register-local + 2 shfl_xor. P (bf16) -> per-nt tile -> PV.
__global__ __launch_bounds__(256, 1) void k_attn_mfma(const float* __restrict__ x,
                                                      const unsigned short* __restrict__ qkvwb,
                                                      const float* __restrict__ relw2,
                                                      const float* __restrict__ h,
                                                      float* __restrict__ att){
    const int b = blockIdx.x, t = threadIdx.x;
    const int lane = t & 63, w = t >> 6;
    const int lr = lane & 15, lh = lane >> 4;

    __shared__ __align__(16) unsigned short x1s[96 * 264];   // 50688 B  x^T bf16 [p][c]
    __shared__ __align__(16) unsigned short Rl[96 * 40];     // 7680 B   R [pk][d]
    __shared__ __align__(16) unsigned short qL[4][96 * 40];  // per-wave q [pq][d]
    __shared__ __align__(16) unsigned short krL[4][96 * 40]; // per-wave k+r [pk][d]
    __shared__ __align__(16) unsigned short vL[4][32 * 104]; // per-wave v [d][pk]
    __shared__ __align__(16) unsigned short pL[4][16 * 104]; // per-wave P tile [pq][pk]

    const float* xb = x + (size_t)b * CHW;

    // ---- R = relw2 @ h_b  -> Rl[pk][d] (bf16); zero pad rows
    {
        const float* hb = h + b * 32;
        float hreg[32];
        #pragma unroll
        for (int j = 0; j < 32; ++j) hreg[j] = hb[j];
        for (int idx = t; idx < 2592; idx += 256){
            int d = idx / 81, p = idx - d * 81;
            const float4* wr = (const float4*)(relw2 + (size_t)idx * 32);
            float s = 0.f;
            #pragma unroll
            for (int j = 0; j < 8; ++j){
                float4 wv = wr[j];
                s += wv.x * hreg[4*j] + wv.y * hreg[4*j+1] + wv.z * hreg[4*j+2] + wv.w * hreg[4*j+3];
            }
            Rl[p * 40 + d] = f2bf(s);
        }
        for (int idx = t; idx < 15 * 32; idx += 256){
            int p = 81 + (idx >> 5), d = idx & 31;
            Rl[p * 40 + d] = 0;
        }
    }
    // ---- zero x1s pad rows p=81..95
    for (int idx = t; idx < 15 * 132; idx += 256){
        int r = idx / 132, c = idx - r * 132;
        *(unsigned int*)&x1s[(81 + r) * 264 + 2 * c] = 0;
    }
    // ---- stage x^T -> x1s bf16 [p][c], bounce via qL region
    {
        float* tb = (float*)qL;  // [64][85] f32 = 21760 B
        for (int cc = 0; cc < 4; ++cc){
            for (int idx = t; idx < 64 * 81; idx += 256){
                int c = idx / 81, p = idx - c * 81;
                tb[c * 85 + p] = xb[(cc * 64 + c) * 81 + p];
            }
            __syncthreads();
            for (int idx = t; idx < 32 * 81; idx += 256){
                int c2 = idx & 31, p = idx >> 5;
                int c = 2 * c2;
                unsigned int pk = (unsigned int)f2bf(tb[c * 85 + p])
                                | ((unsigned int)f2bf(tb[(c + 1) * 85 + p]) << 16);
                *(unsigned int*)&x1s[p * 264 + cc * 64 + c] = pk;
            }
            __syncthreads();
        }
    }

    unsigned short* q_  = qL[w];
    unsigned short* kr_ = krL[w];
    unsigned short* v_  = vL[w];
    unsigned short* p_  = pL[w];

    for (int hi = 0; hi < 2; ++hi){
        const int hh = w + hi * 4;
        const int qrow = hh * 32, krow = 256 + hh * 32, vrow = 512 + hh * 32;
        const int gq = (qrow / 96) * 32, gk = (krow / 96) * 32, gv = (vrow / 96) * 32;

        // ---- Q GEMM: q_[pq][d]
        {
            short8v a0 = *(const short8v*)(qkvwb + (size_t)(qrow + lr) * 32 + lh * 8);
            short8v a1 = *(const short8v*)(qkvwb + (size_t)(qrow + 16 + lr) * 32 + lh * 8);
            #pragma unroll
            for (int nt = 0; nt < 6; ++nt){
                short8v bb = *(const short8v*)(x1s + (nt * 16 + lr) * 264 + gq + lh * 8);
                f32x4 c0 = {0.f,0.f,0.f,0.f}, c1 = {0.f,0.f,0.f,0.f};
                c0 = __builtin_amdgcn_mfma_f32_16x16x32_bf16(a0, bb, c0, 0, 0, 0);
                c1 = __builtin_amdgcn_mfma_f32_16x16x32_bf16(a1, bb, c1, 0, 0, 0);
                int p = nt * 16 + lr;
                short4v p0, p1;
                #pragma unroll
                for (int r = 0; r < 4; ++r){ p0[r] = (short)f2bf(c0[r]); p1[r] = (short)f2bf(c1[r]); }
                *(short4v*)(q_ + p * 40 + lh * 4)      = p0;
                *(short4v*)(q_ + p * 40 + 16 + lh * 4) = p1;
            }
        }
        // ---- K GEMM with acc init = R: kr_[pk][d]
        {
            short8v a0 = *(const short8v*)(qkvwb + (size_t)(krow + lr) * 32 + lh * 8);
            short8v a1 = *(const short8v*)(qkvwb + (size_t)(krow + 16 + lr) * 32 + lh * 8);
            #pragma unroll
            for (int nt = 0; nt < 6; ++nt){
                int p = nt * 16 + lr;
                short4v r0 = *(const short4v*)(Rl + p * 40 + lh * 4);
                short4v r1 = *(const short4v*)(Rl + p * 40 + 16 + lh * 4);
                f32x4 c0, c1;
                #pragma unroll
                for (int r = 0; r < 4; ++r){
                    c0[r] = bf2f((unsigned short)r0[r]);
                    c1[r] = bf2f((unsigned short)r1[r]);
                }
                short8v bb = *(const short8v*)(x1s + p * 264 + gk + lh * 8);
                c0 = __builtin_amdgcn_mfma_f32_16x16x32_bf16(a0, bb, c0, 0, 0, 0);
                c1 = __builtin_amdgcn_mfma_f32_16x16x32_bf16(a1, bb, c1, 0, 0, 0);
                short4v p0, p1;
                #pragma unroll
                for (int r = 0; r < 4; ++r){ p0[r] = (short)f2bf(c0[r]); p1[r] = (short)f2bf(c1[r]); }
                *(short4v*)(kr_ + p * 40 + lh * 4)      = p0;
                *(short4v*)(kr_ + p * 40 + 16 + lh * 4) = p1;
            }
        }
        // ---- V GEMM: v_[d][pk]
        {
            short8v a0 = *(const short8v*)(qkvwb + (size_t)(vrow + lr) * 32 + lh * 8);
            short8v a1 = *(const short8v*)(qkvwb + (size_t)(vrow + 16 + lr) * 32 + lh * 8);
            #pragma unroll
            for (int nt = 0; nt < 6; ++nt){
                short8v bb = *(const short8v*)(x1s + (nt * 16 + lr) * 264 + gv + lh * 8);
                f32x4 c0 = {0.f,0.f,0.f,0.f}, c1 = {0.f,0.f,0.f,0.f};
                c0 = __builtin_amdgcn_mfma_f32_16x16x32_bf16(a0, bb, c0, 0, 0, 0);
                c1 = __builtin_amdgcn_mfma_f32_16x16x32_bf16(a1, bb, c1, 0, 0, 0);
                int pk = nt * 16 + lr;
                #pragma unroll
                for (int r = 0; r < 4; ++r){
                    v_[(lh * 4 + r) * 104 + pk]        = f2bf(c0[r]);
                    v_[(16 + lh * 4 + r) * 104 + pk]   = f2bf(c1[r]);
                }
            }
        }
        // ---- scores^T, softmax, PV per pq-tile
        float* ob = att + (size_t)b * CHW + (size_t)(hh * 32) * 81;
        for (int nt = 0; nt < 6; ++nt){
            short8v bq = *(const short8v*)(q_ + (nt * 16 + lr) * 40 + lh * 8);
            f32x4 sc[6];
            #pragma unroll
            for (int mt = 0; mt < 6; ++mt){
                short8v ak = *(const short8v*)(kr_ + (mt * 16 + lr) * 40 + lh * 8);
                f32x4 z = {0.f,0.f,0.f,0.f};
                sc[mt] = __builtin_amdgcn_mfma_f32_16x16x32_bf16(ak, bq, z, 0, 0, 0);
            }
            // mask pk >= 81 (only mt=5: pk = 80 + lh*4 + r)
            sc[5][0] = (lh == 0) ? sc[5][0] : -1e30f;
            sc[5][1] = -1e30f; sc[5][2] = -1e30f; sc[5][3] = -1e30f;
            // max over pk (register + cross-lh)
            float mx = -1e30f;
            #pragma unroll
            for (int mt = 0; mt < 6; ++mt)
            #pragma unroll
            for (int r = 0; r < 4; ++r) mx = fmaxf(mx, sc[mt][r]);
            mx = fmaxf(mx, __shfl_xor(mx, 16));
            mx = fmaxf(mx, __shfl_xor(mx, 32));
            // exp & sum
            const float scl = 0.17677669529663687f;
            float sum = 0.f;
            #pragma unroll
            for (int mt = 0; mt < 6; ++mt)
            #pragma unroll
            for (int r = 0; r < 4; ++r){
                float e = __expf((sc[mt][r] - mx) * scl);
                sc[mt][r] = e; sum += e;
            }
            sum += __shfl_xor(sum, 16);
            sum += __shfl_xor(sum, 32);
            float inv = 1.f / sum;
            // write P tile [pq=lr][pk]
            #pragma unroll
            for (int mt = 0; mt < 6; ++mt){
                short4v pv;
                #pragma unroll
                for (int r = 0; r < 4; ++r) pv[r] = (short)f2bf(sc[mt][r] * inv);
                *(short4v*)(p_ + lr * 104 + mt * 16 + lh * 4) = pv;
            }
            // PV: att[pq][d] for this pq-tile
            f32x4 o0 = {0.f,0.f,0.f,0.f}, o1 = {0.f,0.f,0.f,0.f};
            #pragma unroll
            for (int ks = 0; ks < 3; ++ks){
                short8v ap  = *(const short8v*)(p_ + lr * 104 + ks * 32 + lh * 8);
                short8v bv0 = *(const short8v*)(v_ + lr * 104 + ks * 32 + lh * 8);
                short8v bv1 = *(const short8v*)(v_ + (16 + lr) * 104 + ks * 32 + lh * 8);
                o0 = __builtin_amdgcn_mfma_f32_16x16x32_bf16(ap, bv0, o0, 0, 0, 0);
                o1 = __builtin_amdgcn_mfma_f32_16x16x32_bf16(ap, bv1, o1, 0, 0, 0);
            }
            int pq0 = nt * 16 + lh * 4;
            #pragma unroll
            for (int r = 0; r < 4; ++r){
                int pq = pq0 + r;
                if (pq < 81){
                    ob[lr * 81 + pq]        = o0[r];
                    ob[(16 + lr) * 81 + pq] = o1[r];
                }
            }
        }
    }
}

// ---------------- K1b: y = o_w @ att + x  (in-place over att in d_out) ----------------
__global__ __launch_bounds__(256) void k_oproj(const float* __restrict__ x,
                                               const float* __restrict__ ow,
                                               float* __restrict__ y){
    const int blk = blockIdx.x;
    const int b = blk >> 1, half = blk & 1;
    const int t = threadIdx.x;
    const int p0 = half * 41;
    const int np = half ? 40 : 41;
    __shared__ float att[256 * 41];
    __shared__ unsigned short owt[32 * 258];
    float* yb = y + (size_t)b * CHW;
    for (int idx = t; idx < 256 * 41; idx += 256){
        int pp = idx % 41, c = idx / 41;
        float v = 0.f;
        if (pp < np) v = yb[c * 81 + p0 + pp];
        att[c * 41 + pp] = v;
    }
    __syncthreads();
    float acc[41];
    const float* xrow = x + (size_t)b * CHW + t * 81 + p0;
    #pragma unroll
    for (int pp = 0; pp < 41; ++pp){
        float v = 0.f;
        if (pp < np) v = xrow[pp];
        acc[pp] = v;
    }
    for (int ct = 0; ct < 8; ++ct){
        __syncthreads();
        for (int idx = t; idx < 32 * 256; idx += 256){
            int cl = idx & 31, o2 = idx >> 5;
            owt[cl * 258 + o2] = f2bf(ow[o2 * 256 + ct * 32 + cl]);
        }
        __syncthreads();
        #pragma unroll 4
        for (int cl = 0; cl < 32; ++cl){
            float w = bf2f(owt[cl * 258 + t]);
            const float* arow = att + (ct * 32 + cl) * 41;
            #pragma unroll
            for (int pp = 0; pp < 41; ++pp) acc[pp] += w * arow[pp];
        }
    }
    __syncthreads();
    #pragma unroll
    for (int pp = 0; pp < 41; ++pp)
        if (pp < np) yb[t * 81 + p0 + pp] = acc[pp];
}

// ---------------- stats: per-channel mean / rstd over (B,P) ----------------
__global__ __launch_bounds__(256) void k_stats(const float* __restrict__ buf,
                                               float* __restrict__ mean, float* __restrict__ rstd){
    const int c = blockIdx.x, t = threadIdx.x;
    float s = 0.f, q = 0.f;
    for (int idx = t; idx < NPOS; idx += 256){
        int b = idx / 81, p = idx - b * 81;
        float v = buf[(size_t)b * CHW + c * 81 + p];
        s += v; q += v * v;
    }
    __shared__ float rs[256], rq[256];
    rs[t] = s; rq[t] = q;
    __syncthreads();
    for (int k = 128; k; k >>= 1){
        if (t < k){ rs[t] += rs[t + k]; rq[t] += rq[t + k]; }
        __syncthreads();
    }
    if (t == 0){
        float m = rs[0] / (float)NPOS;
        float var = rq[0] / (float)NPOS - m * m;
        mean[c] = m;
        rstd[c] = rsqrtf(var + EPS_);
    }
}

// ---------------- K3: fused FF via MFMA, in-place z = x1 + W2*gelu(W1*x1) ----------------
__global__ __launch_bounds__(256, 2) void k_ff_mfma(const unsigned short* __restrict__ w1bf,
                                                    const unsigned short* __restrict__ w2bf,
                                                    const float* __restrict__ mean1, const float* __restrict__ rstd1,
                                                    const float* __restrict__ g1, const float* __restrict__ b1,
                                                    float* __restrict__ yz){
    const int b = blockIdx.x, t = threadIdx.x;
    const int lane = t & 63, w = t >> 6;
    const int lr = lane & 15, lh = lane >> 4;
    float* zb = yz + (size_t)b * CHW;

    __shared__ __align__(16) unsigned short x1s[96 * 264];
    __shared__ __align__(16) unsigned char ubuf[26112];
    unsigned short* ffs = (unsigned short*)ubuf;
    float* tb = (float*)ubuf;

    for (int idx = t; idx < 15 * 132; idx += 256){
        int r = idx / 132, c = idx - r * 132;
        *(unsigned int*)&x1s[(81 + r) * 264 + 2 * c] = 0;
    }
    for (int cc = 0; cc < 4; ++cc){
        for (int idx = t; idx < 64 * 81; idx += 256){
            int c = idx / 81, p = idx - c * 81;
            int gc = cc * 64 + c;
            float v = zb[gc * 81 + p];
            v = (v - mean1[gc]) * rstd1[gc] * g1[gc] + b1[gc];
            tb[c * 85 + p] = v;
        }
        __syncthreads();
        for (int idx = t; idx < 32 * 81; idx += 256){
            int c2 = idx & 31, p = idx >> 5;
            int c = 2 * c2;
            unsigned int pk = (unsigned int)f2bf(tb[c * 85 + p])
                            | ((unsigned int)f2bf(tb[(c + 1) * 85 + p]) << 16);
            *(unsigned int*)&x1s[p * 264 + cc * 64 + c] = pk;
        }
        __syncthreads();
    }

    const int cw = w * 64;
    f32x4 acc2[4][6];
    #pragma unroll
    for (int ci = 0; ci < 4; ++ci)
    #pragma unroll
    for (int pj = 0; pj < 6; ++pj)
        acc2[ci][pj] = (f32x4){0.f, 0.f, 0.f, 0.f};

    for (int fc = 0; fc < 8; ++fc){
        f32x4 acc1[2][6];
        #pragma unroll
        for (int fi = 0; fi < 2; ++fi)
        #pragma unroll
        for (int pj = 0; pj < 6; ++pj)
            acc1[fi][pj] = (f32x4){0.f, 0.f, 0.f, 0.f};
        const int fbase = fc * 128 + w * 32;
        for (int ks = 0; ks < 8; ++ks){
            const int k0 = ks * 32 + lh * 8;
            short8v a0 = *(const short8v*)(w1bf + (size_t)(fbase + lr) * 256 + k0);
            short8v a1 = *(const short8v*)(w1bf + (size_t)(fbase + 16 + lr) * 256 + k0);
            #pragma unroll
            for (int pj = 0; pj < 6; ++pj){
                short8v bb = *(const short8v*)(x1s + (pj * 16 + lr) * 264 + k0);
                acc1[0][pj] = __builtin_amdgcn_mfma_f32_16x16x32_bf16(a0, bb, acc1[0][pj], 0, 0, 0);
                acc1[1][pj] = __builtin_amdgcn_mfma_f32_16x16x32_bf16(a1, bb, acc1[1][pj], 0, 0, 0);
            }
        }
        #pragma unroll
        for (int fi = 0; fi < 2; ++fi)
        #pragma unroll
        for (int pj = 0; pj < 6; ++pj){
            int p = pj * 16 + lr;
            int fl = w * 32 + fi * 16 + lh * 4;
            short4v pk;
            #pragma unroll
            for (int r = 0; r < 4; ++r){
                float v = acc1[fi][pj][r];
                v = 0.5f * v * (1.f + erff(v * 0.70710678118654752f));
                pk[r] = (short)f2bf(v);
            }
            *(short4v*)&ffs[p * 136 + fl] = pk;
        }
        __syncthreads();
        for (int ks = 0; ks < 4; ++ks){
            const int k0 = ks * 32 + lh * 8;
            short8v a2[4];
            #pragma unroll
            for (int ci = 0; ci < 4; ++ci)
                a2[ci] = *(const short8v*)(w2bf + (size_t)(cw + ci * 16 + lr) * 1024 + fc * 128 + k0);
            #pragma unroll
            for (int pj = 0; pj < 6; ++pj){
                short8v bb = *(const short8v*)(ffs + (pj * 16 + lr) * 136 + k0);
                #pragma unroll
                for (int ci = 0; ci < 4; ++ci)
                    acc2[ci][pj] = __builtin_amdgcn_mfma_f32_16x16x32_bf16(a2[ci], bb, acc2[ci][pj], 0, 0, 0);
            }
        }
        __syncthreads();
    }
    #pragma unroll
    for (int ci = 0; ci < 4; ++ci)
    #pragma unroll
    for (int pj = 0; pj < 6; ++pj){
        int p = pj * 16 + lr;
        if (p < 81){
            int c = cw + ci * 16 + lh * 4;
            short4v res = *(const short4v*)&x1s[p * 264 + c];
            #pragma unroll
            for (int r = 0; r < 4; ++r)
                zb[(c + r) * 81 + p] = acc2[ci][pj][r] + bf2f((unsigned short)res[r]);
        }
    }
}

// ---------------- K5: BN apply in-place ----------------
__global__ __launch_bounds__(256) void k_bnapply(float* __restrict__ z,
                                                 const float* __restrict__ mean, const float* __restrict__ rstd,
                                                 const float* __restrict__ g, const float* __restrict__ bia,
                                                 unsigned int n){
    unsigned int i = blockIdx.x * 256u + threadIdx.x;
    unsigned int st = gridDim.x * 256u;
    for (; i < n; i += st){
        int c = (int)((i / 81u) & 255u);
        float v = z[i];
        z[i] = (v - mean[c]) * rstd[c] * g[c] + bia[c];
    }
}

extern "C" void kernel_launch(void* const* d_in, const int* in_sizes, int n_in,
                              void* d_out, int out_size, void* d_ws, size_t ws_size,
                              hipStream_t stream){
    const float* x     = (const float*)d_in[0];
    const float* qkvw  = (const float*)d_in[1];
    const float* relw1 = (const float*)d_in[2];
    const float* relw2 = (const float*)d_in[3];
    const float* ow    = (const float*)d_in[4];
    const float* ffw1  = (const float*)d_in[5];
    const float* ffw2  = (const float*)d_in[6];
    const float* g1    = (const float*)d_in[7];
    const float* b1    = (const float*)d_in[8];
    const float* g2    = (const float*)d_in[9];
    const float* b2    = (const float*)d_in[10];
    float* out = (float*)d_out;
    char* ws = (char*)d_ws;

    unsigned short* w1rel = (unsigned short*)ws;            // 1,327,104 B
    float* h     = (float*)(ws + 1327104);                  // 262,144 B
    float* mean1 = (float*)(ws + 1589248);
    float* rstd1 = (float*)(ws + 1590272);
    float* mean2 = (float*)(ws + 1591296);
    float* rstd2 = (float*)(ws + 1592320);
    unsigned short* w1bf  = (unsigned short*)(ws + 1593344); // 524,288 B
    unsigned short* w2bf  = (unsigned short*)(ws + 2117632); // 524,288 B
    unsigned short* qkvwb = (unsigned short*)(ws + 2641920); // 49,152 B

    hipLaunchKernelGGL(k_f2bf, dim3(1024), dim3(256), 0, stream, relw1, w1rel, 663552);
    hipLaunchKernelGGL(k_f2bf, dim3(256),  dim3(256), 0, stream, ffw1, w1bf, 262144);
    hipLaunchKernelGGL(k_f2bf, dim3(256),  dim3(256), 0, stream, ffw2, w2bf, 262144);
    hipLaunchKernelGGL(k_f2bf, dim3(96),   dim3(256), 0, stream, qkvw, qkvwb, 24576);
    hipLaunchKernelGGL(k_h,    dim3(2048), dim3(256), 0, stream, x, w1rel, h);
    hipLaunchKernelGGL(k_attn_mfma, dim3(2048), dim3(256), 0, stream, x, qkvwb, relw2, h, out);
    hipLaunchKernelGGL(k_oproj,dim3(4096), dim3(256), 0, stream, x, ow, out);
    hipLaunchKernelGGL(k_stats,dim3(256),  dim3(256), 0, stream, out, mean1, rstd1);
    hipLaunchKernelGGL(k_ff_mfma, dim3(2048), dim3(256), 0, stream, w1bf, w2bf, mean1, rstd1, g1, b1, out);
    hipLaunchKernelGGL(k_stats,dim3(256),  dim3(256), 0, stream, out, mean2, rstd2);
    hipLaunchKernelGGL(k_bnapply, dim3(2048), dim3(256), 0, stream, out, mean2, rstd2, g2, b2, (unsigned int)NTOT);
}

// Round 4
// 1705.187 us; speedup vs baseline: 5.6646x; 1.4022x over previous
//
#include <hip/hip_runtime.h>
#include <math.h>

#define B_   2048
#define D_   256
#define H_   8
#define DEP_ 32
#define P_   81
#define FF_  1024
#define CHW  (D_*P_)      // 20736
#define NPOS (B_*P_)      // 165888
#define KREL (D_*P_)      // 20736
#define NTOT (B_*CHW)     // 42467328
#define EPS_ 1e-5f

typedef __attribute__((ext_vector_type(8))) short short8v;
typedef __attribute__((ext_vector_type(4))) short short4v;
typedef __attribute__((ext_vector_type(4))) float f32x4;

__device__ __forceinline__ float bf2f(unsigned short u){
    return __uint_as_float(((unsigned int)u) << 16);
}
__device__ __forceinline__ unsigned short f2bf(float f){
    unsigned int x = __float_as_uint(f);
    return (unsigned short)((x + 0x7FFFu + ((x >> 16) & 1u)) >> 16); // RNE
}

// ---------------- generic f32 -> bf16 cast ----------------
__global__ __launch_bounds__(256) void k_f2bf(const float* __restrict__ w,
                                              unsigned short* __restrict__ o, int n){
    int i = blockIdx.x * 256 + threadIdx.x;
    int st = gridDim.x * 256;
    for (; i < n; i += st) o[i] = f2bf(w[i]);
}

// ---------------- K0: h[b][j] = sum_i x[b,i]*rel_w1[j,i] ----------------
__global__ __launch_bounds__(256) void k_h(const float* __restrict__ x,
                                           const unsigned short* __restrict__ w1b,
                                           float* __restrict__ h){
    const int b = blockIdx.x, t = threadIdx.x;
    const float* xb = x + (size_t)b * CHW;
    float acc[32];
    #pragma unroll
    for (int j = 0; j < 32; ++j) acc[j] = 0.f;
    for (int i4 = t * 4; i4 < CHW; i4 += 1024){
        const float4 xv = *(const float4*)(xb + i4);
        #pragma unroll 8
        for (int j = 0; j < 32; ++j){
            const uint2 wv = *(const uint2*)(w1b + (size_t)j * KREL + i4);
            float w0 = bf2f((unsigned short)(wv.x & 0xffffu));
            float w1 = bf2f((unsigned short)(wv.x >> 16));
            float w2 = bf2f((unsigned short)(wv.y & 0xffffu));
            float w3 = bf2f((unsigned short)(wv.y >> 16));
            acc[j] += xv.x * w0 + xv.y * w1 + xv.z * w2 + xv.w * w3;
        }
    }
    __shared__ float red[264 * 33];
    #pragma unroll
    for (int j = 0; j < 32; ++j) red[t * 33 + j] = acc[j];
    __syncthreads();
    {
        const int j = t & 31, g = t >> 5;
        float s = 0.f;
        for (int r = g * 32; r < g * 32 + 32; ++r) s += red[r * 33 + j];
        red[(256 + g) * 33 + j] = s;
    }
    __syncthreads();
    if (t < 32){
        float v = 0.f;
        #pragma unroll
        for (int g2 = 0; g2 < 8; ++g2) v += red[(256 + g2) * 33 + t];
        h[b * 32 + t] = v;
    }
}

// ---------------- K1: per-batch MFMA attention -> att (into d_out) ----------------
__global__ __launch_bounds__(256, 1) void k_attn_mfma(const float* __restrict__ x,
                                                      const unsigned short* __restrict__ qkvwb,
                                                      const float* __restrict__ relw2,
                                                      const float* __restrict__ h,
                                                      float* __restrict__ att){
    const int b = blockIdx.x, t = threadIdx.x;
    const int lane = t & 63, w = t >> 6;
    const int lr = lane & 15, lh = lane >> 4;

    __shared__ __align__(16) unsigned short x1s[96 * 264];   // x^T bf16 [p][c]
    __shared__ __align__(16) unsigned short Rl[96 * 40];     // R [pk][d]
    __shared__ __align__(16) unsigned short qL[4][96 * 40];
    __shared__ __align__(16) unsigned short krL[4][96 * 40];
    __shared__ __align__(16) unsigned short vL[4][32 * 104];
    __shared__ __align__(16) unsigned short pL[4][16 * 104];

    const float* xb = x + (size_t)b * CHW;

    {
        const float* hb = h + b * 32;
        float hreg[32];
        #pragma unroll
        for (int j = 0; j < 32; ++j) hreg[j] = hb[j];
        for (int idx = t; idx < 2592; idx += 256){
            int d = idx / 81, p = idx - d * 81;
            const float4* wr = (const float4*)(relw2 + (size_t)idx * 32);
            float s = 0.f;
            #pragma unroll
            for (int j = 0; j < 8; ++j){
                float4 wv = wr[j];
                s += wv.x * hreg[4*j] + wv.y * hreg[4*j+1] + wv.z * hreg[4*j+2] + wv.w * hreg[4*j+3];
            }
            Rl[p * 40 + d] = f2bf(s);
        }
        for (int idx = t; idx < 15 * 32; idx += 256){
            int p = 81 + (idx >> 5), d = idx & 31;
            Rl[p * 40 + d] = 0;
        }
    }
    for (int idx = t; idx < 15 * 132; idx += 256){
        int r = idx / 132, c = idx - r * 132;
        *(unsigned int*)&x1s[(81 + r) * 264 + 2 * c] = 0;
    }
    {
        float* tb = (float*)qL;
        for (int cc = 0; cc < 4; ++cc){
            for (int idx = t; idx < 64 * 81; idx += 256){
                int c = idx / 81, p = idx - c * 81;
                tb[c * 85 + p] = xb[(cc * 64 + c) * 81 + p];
            }
            __syncthreads();
            for (int idx = t; idx < 32 * 81; idx += 256){
                int c2 = idx & 31, p = idx >> 5;
                int c = 2 * c2;
                unsigned int pk = (unsigned int)f2bf(tb[c * 85 + p])
                                | ((unsigned int)f2bf(tb[(c + 1) * 85 + p]) << 16);
                *(unsigned int*)&x1s[p * 264 + cc * 64 + c] = pk;
            }
            __syncthreads();
        }
    }

    unsigned short* q_  = qL[w];
    unsigned short* kr_ = krL[w];
    unsigned short* v_  = vL[w];
    unsigned short* p_  = pL[w];

    for (int hi = 0; hi < 2; ++hi){
        const int hh = w + hi * 4;
        const int qrow = hh * 32, krow = 256 + hh * 32, vrow = 512 + hh * 32;
        const int gq = (qrow / 96) * 32, gk = (krow / 96) * 32, gv = (vrow / 96) * 32;

        {
            short8v a0 = *(const short8v*)(qkvwb + (size_t)(qrow + lr) * 32 + lh * 8);
            short8v a1 = *(const short8v*)(qkvwb + (size_t)(qrow + 16 + lr) * 32 + lh * 8);
            #pragma unroll
            for (int nt = 0; nt < 6; ++nt){
                short8v bb = *(const short8v*)(x1s + (nt * 16 + lr) * 264 + gq + lh * 8);
                f32x4 c0 = {0.f,0.f,0.f,0.f}, c1 = {0.f,0.f,0.f,0.f};
                c0 = __builtin_amdgcn_mfma_f32_16x16x32_bf16(a0, bb, c0, 0, 0, 0);
                c1 = __builtin_amdgcn_mfma_f32_16x16x32_bf16(a1, bb, c1, 0, 0, 0);
                int p = nt * 16 + lr;
                short4v p0, p1;
                #pragma unroll
                for (int r = 0; r < 4; ++r){ p0[r] = (short)f2bf(c0[r]); p1[r] = (short)f2bf(c1[r]); }
                *(short4v*)(q_ + p * 40 + lh * 4)      = p0;
                *(short4v*)(q_ + p * 40 + 16 + lh * 4) = p1;
            }
        }
        {
            short8v a0 = *(const short8v*)(qkvwb + (size_t)(krow + lr) * 32 + lh * 8);
            short8v a1 = *(const short8v*)(qkvwb + (size_t)(krow + 16 + lr) * 32 + lh * 8);
            #pragma unroll
            for (int nt = 0; nt < 6; ++nt){
                int p = nt * 16 + lr;
                short4v r0 = *(const short4v*)(Rl + p * 40 + lh * 4);
                short4v r1 = *(const short4v*)(Rl + p * 40 + 16 + lh * 4);
                f32x4 c0, c1;
                #pragma unroll
                for (int r = 0; r < 4; ++r){
                    c0[r] = bf2f((unsigned short)r0[r]);
                    c1[r] = bf2f((unsigned short)r1[r]);
                }
                short8v bb = *(const short8v*)(x1s + p * 264 + gk + lh * 8);
                c0 = __builtin_amdgcn_mfma_f32_16x16x32_bf16(a0, bb, c0, 0, 0, 0);
                c1 = __builtin_amdgcn_mfma_f32_16x16x32_bf16(a1, bb, c1, 0, 0, 0);
                short4v p0, p1;
                #pragma unroll
                for (int r = 0; r < 4; ++r){ p0[r] = (short)f2bf(c0[r]); p1[r] = (short)f2bf(c1[r]); }
                *(short4v*)(kr_ + p * 40 + lh * 4)      = p0;
                *(short4v*)(kr_ + p * 40 + 16 + lh * 4) = p1;
            }
        }
        {
            short8v a0 = *(const short8v*)(qkvwb + (size_t)(vrow + lr) * 32 + lh * 8);
            short8v a1 = *(const short8v*)(qkvwb + (size_t)(vrow + 16 + lr) * 32 + lh * 8);
            #pragma unroll
            for (int nt = 0; nt < 6; ++nt){
                short8v bb = *(const short8v*)(x1s + (nt * 16 + lr) * 264 + gv + lh * 8);
                f32x4 c0 = {0.f,0.f,0.f,0.f}, c1 = {0.f,0.f,0.f,0.f};
                c0 = __builtin_amdgcn_mfma_f32_16x16x32_bf16(a0, bb, c0, 0, 0, 0);
                c1 = __builtin_amdgcn_mfma_f32_16x16x32_bf16(a1, bb, c1, 0, 0, 0);
                int pk = nt * 16 + lr;
                #pragma unroll
                for (int r = 0; r < 4; ++r){
                    v_[(lh * 4 + r) * 104 + pk]        = f2bf(c0[r]);
                    v_[(16 + lh * 4 + r) * 104 + pk]   = f2bf(c1[r]);
                }
            }
        }
        float* ob = att + (size_t)b * CHW + (size_t)(hh * 32) * 81;
        for (int nt = 0; nt < 6; ++nt){
            short8v bq = *(const short8v*)(q_ + (nt * 16 + lr) * 40 + lh * 8);
            f32x4 sc[6];
            #pragma unroll
            for (int mt = 0; mt < 6; ++mt){
                short8v ak = *(const short8v*)(kr_ + (mt * 16 + lr) * 40 + lh * 8);
                f32x4 z = {0.f,0.f,0.f,0.f};
                sc[mt] = __builtin_amdgcn_mfma_f32_16x16x32_bf16(ak, bq, z, 0, 0, 0);
            }
            sc[5][0] = (lh == 0) ? sc[5][0] : -1e30f;
            sc[5][1] = -1e30f; sc[5][2] = -1e30f; sc[5][3] = -1e30f;
            float mx = -1e30f;
            #pragma unroll
            for (int mt = 0; mt < 6; ++mt)
            #pragma unroll
            for (int r = 0; r < 4; ++r) mx = fmaxf(mx, sc[mt][r]);
            mx = fmaxf(mx, __shfl_xor(mx, 16));
            mx = fmaxf(mx, __shfl_xor(mx, 32));
            const float scl = 0.17677669529663687f;
            float sum = 0.f;
            #pragma unroll
            for (int mt = 0; mt < 6; ++mt)
            #pragma unroll
            for (int r = 0; r < 4; ++r){
                float e = __expf((sc[mt][r] - mx) * scl);
                sc[mt][r] = e; sum += e;
            }
            sum += __shfl_xor(sum, 16);
            sum += __shfl_xor(sum, 32);
            float inv = 1.f / sum;
            #pragma unroll
            for (int mt = 0; mt < 6; ++mt){
                short4v pv;
                #pragma unroll
                for (int r = 0; r < 4; ++r) pv[r] = (short)f2bf(sc[mt][r] * inv);
                *(short4v*)(p_ + lr * 104 + mt * 16 + lh * 4) = pv;
            }
            f32x4 o0 = {0.f,0.f,0.f,0.f}, o1 = {0.f,0.f,0.f,0.f};
            #pragma unroll
            for (int ks = 0; ks < 3; ++ks){
                short8v ap  = *(const short8v*)(p_ + lr * 104 + ks * 32 + lh * 8);
                short8v bv0 = *(const short8v*)(v_ + lr * 104 + ks * 32 + lh * 8);
                short8v bv1 = *(const short8v*)(v_ + (16 + lr) * 104 + ks * 32 + lh * 8);
                o0 = __builtin_amdgcn_mfma_f32_16x16x32_bf16(ap, bv0, o0, 0, 0, 0);
                o1 = __builtin_amdgcn_mfma_f32_16x16x32_bf16(ap, bv1, o1, 0, 0, 0);
            }
            int pq0 = nt * 16 + lh * 4;
            #pragma unroll
            for (int r = 0; r < 4; ++r){
                int pq = pq0 + r;
                if (pq < 81){
                    ob[lr * 81 + pq]        = o0[r];
                    ob[(16 + lr) * 81 + pq] = o1[r];
                }
            }
        }
    }
}

// ---------------- K1b: y = o_w @ att + x via MFMA (in-place over att in d_out) ----------------
// block = 1 batch, 4 waves; attT [96 p][264 c] bf16 (validated layout), A = ow bf16 rows.
__global__ __launch_bounds__(256, 2) void k_oproj_mfma(const float* __restrict__ x,
                                                       const unsigned short* __restrict__ owb,
                                                       float* __restrict__ yz){
    const int b = blockIdx.x, t = threadIdx.x;
    const int lane = t & 63, w = t >> 6;
    const int lr = lane & 15, lh = lane >> 4;
    float* zb = yz + (size_t)b * CHW;

    __shared__ __align__(16) unsigned short attT[96 * 264];  // 50688 B
    __shared__ __align__(16) float tb[64 * 85];              // 21760 B

    // zero pad rows p=81..95
    for (int idx = t; idx < 15 * 132; idx += 256){
        int r = idx / 132, c = idx - r * 132;
        *(unsigned int*)&attT[(81 + r) * 264 + 2 * c] = 0;
    }
    // transpose-pack att[c][p] -> attT[p][c] bf16
    for (int cc = 0; cc < 4; ++cc){
        for (int idx = t; idx < 64 * 81; idx += 256){
            int c = idx / 81, p = idx - c * 81;
            tb[c * 85 + p] = zb[(cc * 64 + c) * 81 + p];
        }
        __syncthreads();
        for (int idx = t; idx < 32 * 81; idx += 256){
            int c2 = idx & 31, p = idx >> 5;
            int c = 2 * c2;
            unsigned int pk = (unsigned int)f2bf(tb[c * 85 + p])
                            | ((unsigned int)f2bf(tb[(c + 1) * 85 + p]) << 16);
            *(unsigned int*)&attT[p * 264 + cc * 64 + c] = pk;
        }
        __syncthreads();
    }

    const int cw = w * 64;
    f32x4 acc[4][6];
    #pragma unroll
    for (int ci = 0; ci < 4; ++ci)
    #pragma unroll
    for (int pj = 0; pj < 6; ++pj)
        acc[ci][pj] = (f32x4){0.f, 0.f, 0.f, 0.f};

    for (int ks = 0; ks < 8; ++ks){
        const int k0 = ks * 32 + lh * 8;
        short8v a[4];
        #pragma unroll
        for (int ci = 0; ci < 4; ++ci)
            a[ci] = *(const short8v*)(owb + (size_t)(cw + ci * 16 + lr) * 256 + k0);
        #pragma unroll
        for (int pj = 0; pj < 6; ++pj){
            short8v bb = *(const short8v*)(attT + (pj * 16 + lr) * 264 + k0);
            #pragma unroll
            for (int ci = 0; ci < 4; ++ci)
                acc[ci][pj] = __builtin_amdgcn_mfma_f32_16x16x32_bf16(a[ci], bb, acc[ci][pj], 0, 0, 0);
        }
    }
    // epilogue: y = acc + x residual
    const float* xb = x + (size_t)b * CHW;
    #pragma unroll
    for (int ci = 0; ci < 4; ++ci)
    #pragma unroll
    for (int pj = 0; pj < 6; ++pj){
        int p = pj * 16 + lr;
        if (p < 81){
            int c = cw + ci * 16 + lh * 4;
            #pragma unroll
            for (int r = 0; r < 4; ++r)
                zb[(c + r) * 81 + p] = acc[ci][pj][r] + xb[(c + r) * 81 + p];
        }
    }
}

// ---------------- stats: per-channel mean / rstd over (B,P) ----------------
__global__ __launch_bounds__(256) void k_stats(const float* __restrict__ buf,
                                               float* __restrict__ mean, float* __restrict__ rstd){
    const int c = blockIdx.x, t = threadIdx.x;
    float s = 0.f, q = 0.f;
    for (int idx = t; idx < NPOS; idx += 256){
        int b = idx / 81, p = idx - b * 81;
        float v = buf[(size_t)b * CHW + c * 81 + p];
        s += v; q += v * v;
    }
    __shared__ float rs[256], rq[256];
    rs[t] = s; rq[t] = q;
    __syncthreads();
    for (int k = 128; k; k >>= 1){
        if (t < k){ rs[t] += rs[t + k]; rq[t] += rq[t + k]; }
        __syncthreads();
    }
    if (t == 0){
        float m = rs[0] / (float)NPOS;
        float var = rq[0] / (float)NPOS - m * m;
        mean[c] = m;
        rstd[c] = rsqrtf(var + EPS_);
    }
}

// ---------------- K3: fused FF via MFMA, in-place z = x1 + W2*gelu(W1*x1) ----------------
__global__ __launch_bounds__(256, 2) void k_ff_mfma(const unsigned short* __restrict__ w1bf,
                                                    const unsigned short* __restrict__ w2bf,
                                                    const float* __restrict__ mean1, const float* __restrict__ rstd1,
                                                    const float* __restrict__ g1, const float* __restrict__ b1,
                                                    float* __restrict__ yz){
    const int b = blockIdx.x, t = threadIdx.x;
    const int lane = t & 63, w = t >> 6;
    const int lr = lane & 15, lh = lane >> 4;
    float* zb = yz + (size_t)b * CHW;

    __shared__ __align__(16) unsigned short x1s[96 * 264];
    __shared__ __align__(16) unsigned char ubuf[26112];
    unsigned short* ffs = (unsigned short*)ubuf;
    float* tb = (float*)ubuf;

    for (int idx = t; idx < 15 * 132; idx += 256){
        int r = idx / 132, c = idx - r * 132;
        *(unsigned int*)&x1s[(81 + r) * 264 + 2 * c] = 0;
    }
    for (int cc = 0; cc < 4; ++cc){
        for (int idx = t; idx < 64 * 81; idx += 256){
            int c = idx / 81, p = idx - c * 81;
            int gc = cc * 64 + c;
            float v = zb[gc * 81 + p];
            v = (v - mean1[gc]) * rstd1[gc] * g1[gc] + b1[gc];
            tb[c * 85 + p] = v;
        }
        __syncthreads();
        for (int idx = t; idx < 32 * 81; idx += 256){
            int c2 = idx & 31, p = idx >> 5;
            int c = 2 * c2;
            unsigned int pk = (unsigned int)f2bf(tb[c * 85 + p])
                            | ((unsigned int)f2bf(tb[(c + 1) * 85 + p]) << 16);
            *(unsigned int*)&x1s[p * 264 + cc * 64 + c] = pk;
        }
        __syncthreads();
    }

    const int cw = w * 64;
    f32x4 acc2[4][6];
    #pragma unroll
    for (int ci = 0; ci < 4; ++ci)
    #pragma unroll
    for (int pj = 0; pj < 6; ++pj)
        acc2[ci][pj] = (f32x4){0.f, 0.f, 0.f, 0.f};

    for (int fc = 0; fc < 8; ++fc){
        f32x4 acc1[2][6];
        #pragma unroll
        for (int fi = 0; fi < 2; ++fi)
        #pragma unroll
        for (int pj = 0; pj < 6; ++pj)
            acc1[fi][pj] = (f32x4){0.f, 0.f, 0.f, 0.f};
        const int fbase = fc * 128 + w * 32;
        for (int ks = 0; ks < 8; ++ks){
            const int k0 = ks * 32 + lh * 8;
            short8v a0 = *(const short8v*)(w1bf + (size_t)(fbase + lr) * 256 + k0);
            short8v a1 = *(const short8v*)(w1bf + (size_t)(fbase + 16 + lr) * 256 + k0);
            #pragma unroll
            for (int pj = 0; pj < 6; ++pj){
                short8v bb = *(const short8v*)(x1s + (pj * 16 + lr) * 264 + k0);
                acc1[0][pj] = __builtin_amdgcn_mfma_f32_16x16x32_bf16(a0, bb, acc1[0][pj], 0, 0, 0);
                acc1[1][pj] = __builtin_amdgcn_mfma_f32_16x16x32_bf16(a1, bb, acc1[1][pj], 0, 0, 0);
            }
        }
        #pragma unroll
        for (int fi = 0; fi < 2; ++fi)
        #pragma unroll
        for (int pj = 0; pj < 6; ++pj){
            int p = pj * 16 + lr;
            int fl = w * 32 + fi * 16 + lh * 4;
            short4v pk;
            #pragma unroll
            for (int r = 0; r < 4; ++r){
                float v = acc1[fi][pj][r];
                v = 0.5f * v * (1.f + erff(v * 0.70710678118654752f));
                pk[r] = (short)f2bf(v);
            }
            *(short4v*)&ffs[p * 136 + fl] = pk;
        }
        __syncthreads();
        for (int ks = 0; ks < 4; ++ks){
            const int k0 = ks * 32 + lh * 8;
            short8v a2[4];
            #pragma unroll
            for (int ci = 0; ci < 4; ++ci)
                a2[ci] = *(const short8v*)(w2bf + (size_t)(cw + ci * 16 + lr) * 1024 + fc * 128 + k0);
            #pragma unroll
            for (int pj = 0; pj < 6; ++pj){
                short8v bb = *(const short8v*)(ffs + (pj * 16 + lr) * 136 + k0);
                #pragma unroll
                for (int ci = 0; ci < 4; ++ci)
                    acc2[ci][pj] = __builtin_amdgcn_mfma_f32_16x16x32_bf16(a2[ci], bb, acc2[ci][pj], 0, 0, 0);
            }
        }
        __syncthreads();
    }
    #pragma unroll
    for (int ci = 0; ci < 4; ++ci)
    #pragma unroll
    for (int pj = 0; pj < 6; ++pj){
        int p = pj * 16 + lr;
        if (p < 81){
            int c = cw + ci * 16 + lh * 4;
            short4v res = *(const short4v*)&x1s[p * 264 + c];
            #pragma unroll
            for (int r = 0; r < 4; ++r)
                zb[(c + r) * 81 + p] = acc2[ci][pj][r] + bf2f((unsigned short)res[r]);
        }
    }
}

// ---------------- K5: BN apply in-place ----------------
__global__ __launch_bounds__(256) void k_bnapply(float* __restrict__ z,
                                                 const float* __restrict__ mean, const float* __restrict__ rstd,
                                                 const float* __restrict__ g, const float* __restrict__ bia,
                                                 unsigned int n){
    unsigned int i = blockIdx.x * 256u + threadIdx.x;
    unsigned int st = gridDim.x * 256u;
    for (; i < n; i += st){
        int c = (int)((i / 81u) & 255u);
        float v = z[i];
        z[i] = (v - mean[c]) * rstd[c] * g[c] + bia[c];
    }
}

extern "C" void kernel_launch(void* const* d_in, const int* in_sizes, int n_in,
                              void* d_out, int out_size, void* d_ws, size_t ws_size,
                              hipStream_t stream){
    const float* x     = (const float*)d_in[0];
    const float* qkvw  = (const float*)d_in[1];
    const float* relw1 = (const float*)d_in[2];
    const float* relw2 = (const float*)d_in[3];
    const float* ow    = (const float*)d_in[4];
    const float* ffw1  = (const float*)d_in[5];
    const float* ffw2  = (const float*)d_in[6];
    const float* g1    = (const float*)d_in[7];
    const float* b1    = (const float*)d_in[8];
    const float* g2    = (const float*)d_in[9];
    const float* b2    = (const float*)d_in[10];
    float* out = (float*)d_out;
    char* ws = (char*)d_ws;

    unsigned short* w1rel = (unsigned short*)ws;            // 1,327,104 B
    float* h     = (float*)(ws + 1327104);                  // 262,144 B
    float* mean1 = (float*)(ws + 1589248);
    float* rstd1 = (float*)(ws + 1590272);
    float* mean2 = (float*)(ws + 1591296);
    float* rstd2 = (float*)(ws + 1592320);
    unsigned short* w1bf  = (unsigned short*)(ws + 1593344); // 524,288 B
    unsigned short* w2bf  = (unsigned short*)(ws + 2117632); // 524,288 B
    unsigned short* qkvwb = (unsigned short*)(ws + 2641920); // 49,152 B
    unsigned short* owb   = (unsigned short*)(ws + 2691072); // 131,072 B

    hipLaunchKernelGGL(k_f2bf, dim3(1024), dim3(256), 0, stream, relw1, w1rel, 663552);
    hipLaunchKernelGGL(k_f2bf, dim3(256),  dim3(256), 0, stream, ffw1, w1bf, 262144);
    hipLaunchKernelGGL(k_f2bf, dim3(256),  dim3(256), 0, stream, ffw2, w2bf, 262144);
    hipLaunchKernelGGL(k_f2bf, dim3(96),   dim3(256), 0, stream, qkvw, qkvwb, 24576);
    hipLaunchKernelGGL(k_f2bf, dim3(256),  dim3(256), 0, stream, ow, owb, 65536);
    hipLaunchKernelGGL(k_h,    dim3(2048), dim3(256), 0, stream, x, w1rel, h);
    hipLaunchKernelGGL(k_attn_mfma, dim3(2048), dim3(256), 0, stream, x, qkvwb, relw2, h, out);
    hipLaunchKernelGGL(k_oproj_mfma, dim3(2048), dim3(256), 0, stream, x, owb, out);
    hipLaunchKernelGGL(k_stats,dim3(256),  dim3(256), 0, stream, out, mean1, rstd1);
    hipLaunchKernelGGL(k_ff_mfma, dim3(2048), dim3(256), 0, stream, w1bf, w2bf, mean1, rstd1, g1, b1, out);
    hipLaunchKernelGGL(k_stats,dim3(256),  dim3(256), 0, stream, out, mean2, rstd2);
    hipLaunchKernelGGL(k_bnapply, dim3(2048), dim3(256), 0, stream, out, mean2, rstd2, g2, b2, (unsigned int)NTOT);
}

// Round 5
// 1335.461 us; speedup vs baseline: 7.2329x; 1.2769x over previous
//
#include <hip/hip_runtime.h>
#include <math.h>

#define B_   2048
#define D_   256
#define H_   8
#define DEP_ 32
#define P_   81
#define FF_  1024
#define CHW  (D_*P_)      // 20736
#define NPOS (B_*P_)      // 165888
#define KREL (D_*P_)      // 20736
#define NTOT (B_*CHW)     // 42467328
#define EPS_ 1e-5f
#define YTP  264          // yT row pitch (halfs)
#define YTSZ (96*YTP)     // 25344 halfs per batch

typedef __attribute__((ext_vector_type(8))) short short8v;
typedef __attribute__((ext_vector_type(4))) short short4v;
typedef __attribute__((ext_vector_type(4))) float f32x4;

__device__ __forceinline__ float bf2f(unsigned short u){
    return __uint_as_float(((unsigned int)u) << 16);
}
__device__ __forceinline__ unsigned short f2bf(float f){
    unsigned int x = __float_as_uint(f);
    return (unsigned short)((x + 0x7FFFu + ((x >> 16) & 1u)) >> 16); // RNE
}
// fast erf-based GELU: A&S 7.1.26, |erf err| < 1.5e-7
__device__ __forceinline__ float fast_gelu(float x){
    float u = 0.70710678118654752f * x;
    float a = fabsf(u);
    float t = __builtin_amdgcn_rcpf(fmaf(0.3275911f, a, 1.f));
    float p = t * fmaf(t, fmaf(t, fmaf(t, fmaf(t, 1.061405429f, -1.453152027f),
                         1.421413741f), -0.284496736f), 0.254829592f);
    float e = __expf(-u * u);
    float er = copysignf(fmaf(-p, e, 1.f), u);
    return 0.5f * x * (1.f + er);
}
__device__ __forceinline__ float wave16_red(float v){
    v += __shfl_xor(v, 1); v += __shfl_xor(v, 2);
    v += __shfl_xor(v, 4); v += __shfl_xor(v, 8);
    return v;
}

// ---------------- generic f32 -> bf16 cast ----------------
__global__ __launch_bounds__(256) void k_f2bf(const float* __restrict__ w,
                                              unsigned short* __restrict__ o, int n){
    int i = blockIdx.x * 256 + threadIdx.x;
    int st = gridDim.x * 256;
    for (; i < n; i += st) o[i] = f2bf(w[i]);
}

// ---------------- K0: h[b][j] = sum_i x[b,i]*rel_w1[j,i] ----------------
__global__ __launch_bounds__(256) void k_h(const float* __restrict__ x,
                                           const unsigned short* __restrict__ w1b,
                                           float* __restrict__ h){
    const int b = blockIdx.x, t = threadIdx.x;
    const float* xb = x + (size_t)b * CHW;
    float acc[32];
    #pragma unroll
    for (int j = 0; j < 32; ++j) acc[j] = 0.f;
    for (int i4 = t * 4; i4 < CHW; i4 += 1024){
        const float4 xv = *(const float4*)(xb + i4);
        #pragma unroll 8
        for (int j = 0; j < 32; ++j){
            const uint2 wv = *(const uint2*)(w1b + (size_t)j * KREL + i4);
            float w0 = bf2f((unsigned short)(wv.x & 0xffffu));
            float w1 = bf2f((unsigned short)(wv.x >> 16));
            float w2 = bf2f((unsigned short)(wv.y & 0xffffu));
            float w3 = bf2f((unsigned short)(wv.y >> 16));
            acc[j] += xv.x * w0 + xv.y * w1 + xv.z * w2 + xv.w * w3;
        }
    }
    __shared__ float red[264 * 33];
    #pragma unroll
    for (int j = 0; j < 32; ++j) red[t * 33 + j] = acc[j];
    __syncthreads();
    {
        const int j = t & 31, g = t >> 5;
        float s = 0.f;
        for (int r = g * 32; r < g * 32 + 32; ++r) s += red[r * 33 + j];
        red[(256 + g) * 33 + j] = s;
    }
    __syncthreads();
    if (t < 32){
        float v = 0.f;
        #pragma unroll
        for (int g2 = 0; g2 < 8; ++g2) v += red[(256 + g2) * 33 + t];
        h[b * 32 + t] = v;
    }
}

// ---------------- K1: per-batch MFMA attention -> att (into d_out) ----------------
__global__ __launch_bounds__(256, 1) void k_attn_mfma(const float* __restrict__ x,
                                                      const unsigned short* __restrict__ qkvwb,
                                                      const float* __restrict__ relw2,
                                                      const float* __restrict__ h,
                                                      float* __restrict__ att){
    const int b = blockIdx.x, t = threadIdx.x;
    const int lane = t & 63, w = t >> 6;
    const int lr = lane & 15, lh = lane >> 4;

    __shared__ __align__(16) unsigned short x1s[96 * 264];   // x^T bf16 [p][c]
    __shared__ __align__(16) unsigned short Rl[96 * 40];     // R [pk][d]
    __shared__ __align__(16) unsigned short qL[4][96 * 40];
    __shared__ __align__(16) unsigned short krL[4][96 * 40];
    __shared__ __align__(16) unsigned short vL[4][32 * 104];
    __shared__ __align__(16) unsigned short pL[4][16 * 104];

    const float* xb = x + (size_t)b * CHW;

    {
        const float* hb = h + b * 32;
        float hreg[32];
        #pragma unroll
        for (int j = 0; j < 32; ++j) hreg[j] = hb[j];
        for (int idx = t; idx < 2592; idx += 256){
            int d = idx / 81, p = idx - d * 81;
            const float4* wr = (const float4*)(relw2 + (size_t)idx * 32);
            float s = 0.f;
            #pragma unroll
            for (int j = 0; j < 8; ++j){
                float4 wv = wr[j];
                s += wv.x * hreg[4*j] + wv.y * hreg[4*j+1] + wv.z * hreg[4*j+2] + wv.w * hreg[4*j+3];
            }
            Rl[p * 40 + d] = f2bf(s);
        }
        for (int idx = t; idx < 15 * 32; idx += 256){
            int p = 81 + (idx >> 5), d = idx & 31;
            Rl[p * 40 + d] = 0;
        }
    }
    for (int idx = t; idx < 15 * 132; idx += 256){
        int r = idx / 132, c = idx - r * 132;
        *(unsigned int*)&x1s[(81 + r) * 264 + 2 * c] = 0;
    }
    {
        float* tb = (float*)qL;
        for (int cc = 0; cc < 4; ++cc){
            for (int idx = t; idx < 64 * 81; idx += 256){
                int c = idx / 81, p = idx - c * 81;
                tb[c * 85 + p] = xb[(cc * 64 + c) * 81 + p];
            }
            __syncthreads();
            for (int idx = t; idx < 32 * 81; idx += 256){
                int c2 = idx & 31, p = idx >> 5;
                int c = 2 * c2;
                unsigned int pk = (unsigned int)f2bf(tb[c * 85 + p])
                                | ((unsigned int)f2bf(tb[(c + 1) * 85 + p]) << 16);
                *(unsigned int*)&x1s[p * 264 + cc * 64 + c] = pk;
            }
            __syncthreads();
        }
    }

    unsigned short* q_  = qL[w];
    unsigned short* kr_ = krL[w];
    unsigned short* v_  = vL[w];
    unsigned short* p_  = pL[w];

    for (int hi = 0; hi < 2; ++hi){
        const int hh = w + hi * 4;
        const int qrow = hh * 32, krow = 256 + hh * 32, vrow = 512 + hh * 32;
        const int gq = (qrow / 96) * 32, gk = (krow / 96) * 32, gv = (vrow / 96) * 32;

        {
            short8v a0 = *(const short8v*)(qkvwb + (size_t)(qrow + lr) * 32 + lh * 8);
            short8v a1 = *(const short8v*)(qkvwb + (size_t)(qrow + 16 + lr) * 32 + lh * 8);
            #pragma unroll
            for (int nt = 0; nt < 6; ++nt){
                short8v bb = *(const short8v*)(x1s + (nt * 16 + lr) * 264 + gq + lh * 8);
                f32x4 c0 = {0.f,0.f,0.f,0.f}, c1 = {0.f,0.f,0.f,0.f};
                c0 = __builtin_amdgcn_mfma_f32_16x16x32_bf16(a0, bb, c0, 0, 0, 0);
                c1 = __builtin_amdgcn_mfma_f32_16x16x32_bf16(a1, bb, c1, 0, 0, 0);
                int p = nt * 16 + lr;
                short4v p0, p1;
                #pragma unroll
                for (int r = 0; r < 4; ++r){ p0[r] = (short)f2bf(c0[r]); p1[r] = (short)f2bf(c1[r]); }
                *(short4v*)(q_ + p * 40 + lh * 4)      = p0;
                *(short4v*)(q_ + p * 40 + 16 + lh * 4) = p1;
            }
        }
        {
            short8v a0 = *(const short8v*)(qkvwb + (size_t)(krow + lr) * 32 + lh * 8);
            short8v a1 = *(const short8v*)(qkvwb + (size_t)(krow + 16 + lr) * 32 + lh * 8);
            #pragma unroll
            for (int nt = 0; nt < 6; ++nt){
                int p = nt * 16 + lr;
                short4v r0 = *(const short4v*)(Rl + p * 40 + lh * 4);
                short4v r1 = *(const short4v*)(Rl + p * 40 + 16 + lh * 4);
                f32x4 c0, c1;
                #pragma unroll
                for (int r = 0; r < 4; ++r){
                    c0[r] = bf2f((unsigned short)r0[r]);
                    c1[r] = bf2f((unsigned short)r1[r]);
                }
                short8v bb = *(const short8v*)(x1s + p * 264 + gk + lh * 8);
                c0 = __builtin_amdgcn_mfma_f32_16x16x32_bf16(a0, bb, c0, 0, 0, 0);
                c1 = __builtin_amdgcn_mfma_f32_16x16x32_bf16(a1, bb, c1, 0, 0, 0);
                short4v p0, p1;
                #pragma unroll
                for (int r = 0; r < 4; ++r){ p0[r] = (short)f2bf(c0[r]); p1[r] = (short)f2bf(c1[r]); }
                *(short4v*)(kr_ + p * 40 + lh * 4)      = p0;
                *(short4v*)(kr_ + p * 40 + 16 + lh * 4) = p1;
            }
        }
        {
            short8v a0 = *(const short8v*)(qkvwb + (size_t)(vrow + lr) * 32 + lh * 8);
            short8v a1 = *(const short8v*)(qkvwb + (size_t)(vrow + 16 + lr) * 32 + lh * 8);
            #pragma unroll
            for (int nt = 0; nt < 6; ++nt){
                short8v bb = *(const short8v*)(x1s + (nt * 16 + lr) * 264 + gv + lh * 8);
                f32x4 c0 = {0.f,0.f,0.f,0.f}, c1 = {0.f,0.f,0.f,0.f};
                c0 = __builtin_amdgcn_mfma_f32_16x16x32_bf16(a0, bb, c0, 0, 0, 0);
                c1 = __builtin_amdgcn_mfma_f32_16x16x32_bf16(a1, bb, c1, 0, 0, 0);
                int pk = nt * 16 + lr;
                #pragma unroll
                for (int r = 0; r < 4; ++r){
                    v_[(lh * 4 + r) * 104 + pk]        = f2bf(c0[r]);
                    v_[(16 + lh * 4 + r) * 104 + pk]   = f2bf(c1[r]);
                }
            }
        }
        float* ob = att + (size_t)b * CHW + (size_t)(hh * 32) * 81;
        for (int nt = 0; nt < 6; ++nt){
            short8v bq = *(const short8v*)(q_ + (nt * 16 + lr) * 40 + lh * 8);
            f32x4 sc[6];
            #pragma unroll
            for (int mt = 0; mt < 6; ++mt){
                short8v ak = *(const short8v*)(kr_ + (mt * 16 + lr) * 40 + lh * 8);
                f32x4 z = {0.f,0.f,0.f,0.f};
                sc[mt] = __builtin_amdgcn_mfma_f32_16x16x32_bf16(ak, bq, z, 0, 0, 0);
            }
            sc[5][0] = (lh == 0) ? sc[5][0] : -1e30f;
            sc[5][1] = -1e30f; sc[5][2] = -1e30f; sc[5][3] = -1e30f;
            float mx = -1e30f;
            #pragma unroll
            for (int mt = 0; mt < 6; ++mt)
            #pragma unroll
            for (int r = 0; r < 4; ++r) mx = fmaxf(mx, sc[mt][r]);
            mx = fmaxf(mx, __shfl_xor(mx, 16));
            mx = fmaxf(mx, __shfl_xor(mx, 32));
            const float scl = 0.17677669529663687f;
            float sum = 0.f;
            #pragma unroll
            for (int mt = 0; mt < 6; ++mt)
            #pragma unroll
            for (int r = 0; r < 4; ++r){
                float e = __expf((sc[mt][r] - mx) * scl);
                sc[mt][r] = e; sum += e;
            }
            sum += __shfl_xor(sum, 16);
            sum += __shfl_xor(sum, 32);
            float inv = 1.f / sum;
            #pragma unroll
            for (int mt = 0; mt < 6; ++mt){
                short4v pv;
                #pragma unroll
                for (int r = 0; r < 4; ++r) pv[r] = (short)f2bf(sc[mt][r] * inv);
                *(short4v*)(p_ + lr * 104 + mt * 16 + lh * 4) = pv;
            }
            f32x4 o0 = {0.f,0.f,0.f,0.f}, o1 = {0.f,0.f,0.f,0.f};
            #pragma unroll
            for (int ks = 0; ks < 3; ++ks){
                short8v ap  = *(const short8v*)(p_ + lr * 104 + ks * 32 + lh * 8);
                short8v bv0 = *(const short8v*)(v_ + lr * 104 + ks * 32 + lh * 8);
                short8v bv1 = *(const short8v*)(v_ + (16 + lr) * 104 + ks * 32 + lh * 8);
                o0 = __builtin_amdgcn_mfma_f32_16x16x32_bf16(ap, bv0, o0, 0, 0, 0);
                o1 = __builtin_amdgcn_mfma_f32_16x16x32_bf16(ap, bv1, o1, 0, 0, 0);
            }
            int pq0 = nt * 16 + lh * 4;
            #pragma unroll
            for (int r = 0; r < 4; ++r){
                int pq = pq0 + r;
                if (pq < 81){
                    ob[lr * 81 + pq]        = o0[r];
                    ob[(16 + lr) * 81 + pq] = o1[r];
                }
            }
        }
    }
}

// ---------------- OLD K1b (fallback): y = o_w @ att + x in-place ----------------
__global__ __launch_bounds__(256, 2) void k_oproj_mfma(const float* __restrict__ x,
                                                       const unsigned short* __restrict__ owb,
                                                       float* __restrict__ yz){
    const int b = blockIdx.x, t = threadIdx.x;
    const int lane = t & 63, w = t >> 6;
    const int lr = lane & 15, lh = lane >> 4;
    float* zb = yz + (size_t)b * CHW;

    __shared__ __align__(16) unsigned short attT[96 * 264];
    __shared__ __align__(16) float tb[64 * 85];

    for (int idx = t; idx < 15 * 132; idx += 256){
        int r = idx / 132, c = idx - r * 132;
        *(unsigned int*)&attT[(81 + r) * 264 + 2 * c] = 0;
    }
    for (int cc = 0; cc < 4; ++cc){
        for (int idx = t; idx < 64 * 81; idx += 256){
            int c = idx / 81, p = idx - c * 81;
            tb[c * 85 + p] = zb[(cc * 64 + c) * 81 + p];
        }
        __syncthreads();
        for (int idx = t; idx < 32 * 81; idx += 256){
            int c2 = idx & 31, p = idx >> 5;
            int c = 2 * c2;
            unsigned int pk = (unsigned int)f2bf(tb[c * 85 + p])
                            | ((unsigned int)f2bf(tb[(c + 1) * 85 + p]) << 16);
            *(unsigned int*)&attT[p * 264 + cc * 64 + c] = pk;
        }
        __syncthreads();
    }

    const int cw = w * 64;
    f32x4 acc[4][6];
    #pragma unroll
    for (int ci = 0; ci < 4; ++ci)
    #pragma unroll
    for (int pj = 0; pj < 6; ++pj)
        acc[ci][pj] = (f32x4){0.f, 0.f, 0.f, 0.f};

    for (int ks = 0; ks < 8; ++ks){
        const int k0 = ks * 32 + lh * 8;
        short8v a[4];
        #pragma unroll
        for (int ci = 0; ci < 4; ++ci)
            a[ci] = *(const short8v*)(owb + (size_t)(cw + ci * 16 + lr) * 256 + k0);
        #pragma unroll
        for (int pj = 0; pj < 6; ++pj){
            short8v bb = *(const short8v*)(attT + (pj * 16 + lr) * 264 + k0);
            #pragma unroll
            for (int ci = 0; ci < 4; ++ci)
                acc[ci][pj] = __builtin_amdgcn_mfma_f32_16x16x32_bf16(a[ci], bb, acc[ci][pj], 0, 0, 0);
        }
    }
    const float* xb = x + (size_t)b * CHW;
    #pragma unroll
    for (int ci = 0; ci < 4; ++ci)
    #pragma unroll
    for (int pj = 0; pj < 6; ++pj){
        int p = pj * 16 + lr;
        if (p < 81){
            int c = cw + ci * 16 + lh * 4;
            #pragma unroll
            for (int r = 0; r < 4; ++r)
                zb[(c + r) * 81 + p] = acc[ci][pj][r] + xb[(c + r) * 81 + p];
        }
    }
}

// ---------------- NEW K1b: o-proj + residual -> yT bf16 (ws) + BN1 partials ----------------
__global__ __launch_bounds__(256, 2) void k_oproj_v2(const float* __restrict__ x,
                                                     const unsigned short* __restrict__ owb,
                                                     const float* __restrict__ att,
                                                     unsigned short* __restrict__ yT,
                                                     float* __restrict__ p1){
    const int b = blockIdx.x, t = threadIdx.x;
    const int lane = t & 63, w = t >> 6;
    const int lr = lane & 15, lh = lane >> 4;
    const float* ab = att + (size_t)b * CHW;

    __shared__ __align__(16) unsigned short attT[96 * 264];
    __shared__ __align__(16) float tb[64 * 85];

    for (int idx = t; idx < 15 * 132; idx += 256){
        int r = idx / 132, c = idx - r * 132;
        *(unsigned int*)&attT[(81 + r) * 264 + 2 * c] = 0;
    }
    for (int cc = 0; cc < 4; ++cc){
        for (int idx = t; idx < 64 * 81; idx += 256){
            int c = idx / 81, p = idx - c * 81;
            tb[c * 85 + p] = ab[(cc * 64 + c) * 81 + p];
        }
        __syncthreads();
        for (int idx = t; idx < 32 * 81; idx += 256){
            int c2 = idx & 31, p = idx >> 5;
            int c = 2 * c2;
            unsigned int pk = (unsigned int)f2bf(tb[c * 85 + p])
                            | ((unsigned int)f2bf(tb[(c + 1) * 85 + p]) << 16);
            *(unsigned int*)&attT[p * 264 + cc * 64 + c] = pk;
        }
        __syncthreads();
    }

    const int cw = w * 64;
    f32x4 acc[4][6];
    #pragma unroll
    for (int ci = 0; ci < 4; ++ci)
    #pragma unroll
    for (int pj = 0; pj < 6; ++pj)
        acc[ci][pj] = (f32x4){0.f, 0.f, 0.f, 0.f};

    for (int ks = 0; ks < 8; ++ks){
        const int k0 = ks * 32 + lh * 8;
        short8v a[4];
        #pragma unroll
        for (int ci = 0; ci < 4; ++ci)
            a[ci] = *(const short8v*)(owb + (size_t)(cw + ci * 16 + lr) * 256 + k0);
        #pragma unroll
        for (int pj = 0; pj < 6; ++pj){
            short8v bb = *(const short8v*)(attT + (pj * 16 + lr) * 264 + k0);
            #pragma unroll
            for (int ci = 0; ci < 4; ++ci)
                acc[ci][pj] = __builtin_amdgcn_mfma_f32_16x16x32_bf16(a[ci], bb, acc[ci][pj], 0, 0, 0);
        }
    }
    // epilogue: y = acc + x; write yT bf16; accumulate BN1 partials
    const float* xb = x + (size_t)b * CHW;
    unsigned short* yb = yT + (size_t)b * YTSZ;
    float cs[16], cq[16];
    #pragma unroll
    for (int i = 0; i < 16; ++i){ cs[i] = 0.f; cq[i] = 0.f; }
    #pragma unroll
    for (int ci = 0; ci < 4; ++ci)
    #pragma unroll
    for (int pj = 0; pj < 6; ++pj){
        int p = pj * 16 + lr;
        int c = cw + ci * 16 + lh * 4;
        short4v pk;
        if (p < 81){
            #pragma unroll
            for (int r = 0; r < 4; ++r){
                float y = acc[ci][pj][r] + xb[(c + r) * 81 + p];
                pk[r] = (short)f2bf(y);
                cs[ci * 4 + r] += y;
                cq[ci * 4 + r] += y * y;
            }
        } else {
            #pragma unroll
            for (int r = 0; r < 4; ++r) pk[r] = 0;
        }
        *(short4v*)(yb + p * YTP + c) = pk;
    }
    #pragma unroll
    for (int i = 0; i < 16; ++i){
        cs[i] = wave16_red(cs[i]);
        cq[i] = wave16_red(cq[i]);
    }
    if (lr == 0){
        #pragma unroll
        for (int ci = 0; ci < 4; ++ci)
        #pragma unroll
        for (int r = 0; r < 4; ++r){
            int c = cw + ci * 16 + lh * 4 + r;
            p1[(size_t)c * 2048 + b]         = cs[ci * 4 + r];
            p1[(size_t)(256 + c) * 2048 + b] = cq[ci * 4 + r];
        }
    }
}

// ---------------- OLD stats (fallback) ----------------
__global__ __launch_bounds__(256) void k_stats(const float* __restrict__ buf,
                                               float* __restrict__ mean, float* __restrict__ rstd){
    const int c = blockIdx.x, t = threadIdx.x;
    float s = 0.f, q = 0.f;
    for (int idx = t; idx < NPOS; idx += 256){
        int b = idx / 81, p = idx - b * 81;
        float v = buf[(size_t)b * CHW + c * 81 + p];
        s += v; q += v * v;
    }
    __shared__ float rs[256], rq[256];
    rs[t] = s; rq[t] = q;
    __syncthreads();
    for (int k = 128; k; k >>= 1){
        if (t < k){ rs[t] += rs[t + k]; rq[t] += rq[t + k]; }
        __syncthreads();
    }
    if (t == 0){
        float m = rs[0] / (float)NPOS;
        float var = rq[0] / (float)NPOS - m * m;
        mean[c] = m;
        rstd[c] = rsqrtf(var + EPS_);
    }
}

// ---------------- reduce partials -> (s,t) affine BN params ----------------
__global__ __launch_bounds__(256) void k_red(const float* __restrict__ part,
                                             const float* __restrict__ g, const float* __restrict__ bia,
                                             float* __restrict__ sOut, float* __restrict__ tOut){
    const int c = blockIdx.x, t = threadIdx.x;
    float s = 0.f, q = 0.f;
    #pragma unroll
    for (int i = 0; i < 8; ++i){
        s += part[(size_t)c * 2048 + t + i * 256];
        q += part[(size_t)(256 + c) * 2048 + t + i * 256];
    }
    __shared__ float rs[256], rq[256];
    rs[t] = s; rq[t] = q;
    __syncthreads();
    for (int k = 128; k; k >>= 1){
        if (t < k){ rs[t] += rs[t + k]; rq[t] += rq[t + k]; }
        __syncthreads();
    }
    if (t == 0){
        float m = rs[0] / (float)NPOS;
        float var = rq[0] / (float)NPOS - m * m;
        float sc = g[c] * rsqrtf(var + EPS_);
        sOut[c] = sc;
        tOut[c] = bia[c] - m * sc;
    }
}

// ---------------- w1s[f][c] = bf16(w1[f][c]*s1[c]) ----------------
__global__ __launch_bounds__(256) void k_w1scale(const float* __restrict__ w1,
                                                 const float* __restrict__ s1,
                                                 unsigned short* __restrict__ w1s){
    const int f = blockIdx.x, t = threadIdx.x;
    w1s[f * 256 + t] = f2bf(w1[f * 256 + t] * s1[t]);
}

// ---------------- bias1[f] = sum_c w1[f][c]*t1[c] ----------------
__global__ __launch_bounds__(64) void k_bias1(const float* __restrict__ w1,
                                              const float* __restrict__ t1,
                                              float* __restrict__ bias1){
    const int f = blockIdx.x, t = threadIdx.x;
    const float4 wv = *(const float4*)(w1 + f * 256 + t * 4);
    const float4 tv = *(const float4*)(t1 + t * 4);
    float s = wv.x * tv.x + wv.y * tv.y + wv.z * tv.z + wv.w * tv.w;
    #pragma unroll
    for (int m = 1; m < 64; m <<= 1) s += __shfl_xor(s, m);
    if (t == 0) bias1[f] = s;
}

// ---------------- OLD K3 (fallback) ----------------
__global__ __launch_bounds__(256, 2) void k_ff_mfma(const unsigned short* __restrict__ w1bf,
                                                    const unsigned short* __restrict__ w2bf,
                                                    const float* __restrict__ mean1, const float* __restrict__ rstd1,
                                                    const float* __restrict__ g1, const float* __restrict__ b1,
                                                    float* __restrict__ yz){
    const int b = blockIdx.x, t = threadIdx.x;
    const int lane = t & 63, w = t >> 6;
    const int lr = lane & 15, lh = lane >> 4;
    float* zb = yz + (size_t)b * CHW;

    __shared__ __align__(16) unsigned short x1s[96 * 264];
    __shared__ __align__(16) unsigned char ubuf[26112];
    unsigned short* ffs = (unsigned short*)ubuf;
    float* tb = (float*)ubuf;

    for (int idx = t; idx < 15 * 132; idx += 256){
        int r = idx / 132, c = idx - r * 132;
        *(unsigned int*)&x1s[(81 + r) * 264 + 2 * c] = 0;
    }
    for (int cc = 0; cc < 4; ++cc){
        for (int idx = t; idx < 64 * 81; idx += 256){
            int c = idx / 81, p = idx - c * 81;
            int gc = cc * 64 + c;
            float v = zb[gc * 81 + p];
            v = (v - mean1[gc]) * rstd1[gc] * g1[gc] + b1[gc];
            tb[c * 85 + p] = v;
        }
        __syncthreads();
        for (int idx = t; idx < 32 * 81; idx += 256){
            int c2 = idx & 31, p = idx >> 5;
            int c = 2 * c2;
            unsigned int pk = (unsigned int)f2bf(tb[c * 85 + p])
                            | ((unsigned int)f2bf(tb[(c + 1) * 85 + p]) << 16);
            *(unsigned int*)&x1s[p * 264 + cc * 64 + c] = pk;
        }
        __syncthreads();
    }

    const int cw = w * 64;
    f32x4 acc2[4][6];
    #pragma unroll
    for (int ci = 0; ci < 4; ++ci)
    #pragma unroll
    for (int pj = 0; pj < 6; ++pj)
        acc2[ci][pj] = (f32x4){0.f, 0.f, 0.f, 0.f};

    for (int fc = 0; fc < 8; ++fc){
        f32x4 acc1[2][6];
        #pragma unroll
        for (int fi = 0; fi < 2; ++fi)
        #pragma unroll
        for (int pj = 0; pj < 6; ++pj)
            acc1[fi][pj] = (f32x4){0.f, 0.f, 0.f, 0.f};
        const int fbase = fc * 128 + w * 32;
        for (int ks = 0; ks < 8; ++ks){
            const int k0 = ks * 32 + lh * 8;
            short8v a0 = *(const short8v*)(w1bf + (size_t)(fbase + lr) * 256 + k0);
            short8v a1 = *(const short8v*)(w1bf + (size_t)(fbase + 16 + lr) * 256 + k0);
            #pragma unroll
            for (int pj = 0; pj < 6; ++pj){
                short8v bb = *(const short8v*)(x1s + (pj * 16 + lr) * 264 + k0);
                acc1[0][pj] = __builtin_amdgcn_mfma_f32_16x16x32_bf16(a0, bb, acc1[0][pj], 0, 0, 0);
                acc1[1][pj] = __builtin_amdgcn_mfma_f32_16x16x32_bf16(a1, bb, acc1[1][pj], 0, 0, 0);
            }
        }
        #pragma unroll
        for (int fi = 0; fi < 2; ++fi)
        #pragma unroll
        for (int pj = 0; pj < 6; ++pj){
            int p = pj * 16 + lr;
            int fl = w * 32 + fi * 16 + lh * 4;
            short4v pk;
            #pragma unroll
            for (int r = 0; r < 4; ++r){
                float v = acc1[fi][pj][r];
                v = 0.5f * v * (1.f + erff(v * 0.70710678118654752f));
                pk[r] = (short)f2bf(v);
            }
            *(short4v*)&ffs[p * 136 + fl] = pk;
        }
        __syncthreads();
        for (int ks = 0; ks < 4; ++ks){
            const int k0 = ks * 32 + lh * 8;
            short8v a2[4];
            #pragma unroll
            for (int ci = 0; ci < 4; ++ci)
                a2[ci] = *(const short8v*)(w2bf + (size_t)(cw + ci * 16 + lr) * 1024 + fc * 128 + k0);
            #pragma unroll
            for (int pj = 0; pj < 6; ++pj){
                short8v bb = *(const short8v*)(ffs + (pj * 16 + lr) * 136 + k0);
                #pragma unroll
                for (int ci = 0; ci < 4; ++ci)
                    acc2[ci][pj] = __builtin_amdgcn_mfma_f32_16x16x32_bf16(a2[ci], bb, acc2[ci][pj], 0, 0, 0);
            }
        }
        __syncthreads();
    }
    #pragma unroll
    for (int ci = 0; ci < 4; ++ci)
    #pragma unroll
    for (int pj = 0; pj < 6; ++pj){
        int p = pj * 16 + lr;
        if (p < 81){
            int c = cw + ci * 16 + lh * 4;
            short4v res = *(const short4v*)&x1s[p * 264 + c];
            #pragma unroll
            for (int r = 0; r < 4; ++r)
                zb[(c + r) * 81 + p] = acc2[ci][pj][r] + bf2f((unsigned short)res[r]);
        }
    }
}

// ---------------- NEW K3: FF from yT, BN folded, fast gelu, BN2 partials ----------------
__global__ __launch_bounds__(256, 2) void k_ff_v2(const unsigned short* __restrict__ yT,
                                                  const unsigned short* __restrict__ w1s,
                                                  const unsigned short* __restrict__ w2bf,
                                                  const float* __restrict__ bias1,
                                                  const float* __restrict__ s1, const float* __restrict__ t1,
                                                  float* __restrict__ yz,
                                                  float* __restrict__ p2){
    const int b = blockIdx.x, t = threadIdx.x;
    const int lane = t & 63, w = t >> 6;
    const int lr = lane & 15, lh = lane >> 4;
    float* zb = yz + (size_t)b * CHW;

    __shared__ __align__(16) unsigned short x1s[96 * 264];   // raw y bf16 [p][c]
    __shared__ __align__(16) unsigned short ffs[96 * 136];

    // stage yT -> LDS (linear 16B copy)
    {
        const short8v* src = (const short8v*)(yT + (size_t)b * YTSZ);
        short8v* dst = (short8v*)x1s;
        for (int idx = t; idx < 3168; idx += 256) dst[idx] = src[idx];
    }
    __syncthreads();

    const int cw = w * 64;
    f32x4 acc2[4][6];
    #pragma unroll
    for (int ci = 0; ci < 4; ++ci)
    #pragma unroll
    for (int pj = 0; pj < 6; ++pj)
        acc2[ci][pj] = (f32x4){0.f, 0.f, 0.f, 0.f};

    for (int fc = 0; fc < 8; ++fc){
        const int fbase = fc * 128 + w * 32;
        // acc init = bias1[f]
        float b4[2][4];
        #pragma unroll
        for (int fi = 0; fi < 2; ++fi)
        #pragma unroll
        for (int r = 0; r < 4; ++r)
            b4[fi][r] = bias1[fbase + fi * 16 + lh * 4 + r];
        f32x4 acc1[2][6];
        #pragma unroll
        for (int fi = 0; fi < 2; ++fi)
        #pragma unroll
        for (int pj = 0; pj < 6; ++pj){
            acc1[fi][pj][0] = b4[fi][0]; acc1[fi][pj][1] = b4[fi][1];
            acc1[fi][pj][2] = b4[fi][2]; acc1[fi][pj][3] = b4[fi][3];
        }
        for (int ks = 0; ks < 8; ++ks){
            const int k0 = ks * 32 + lh * 8;
            short8v a0 = *(const short8v*)(w1s + (size_t)(fbase + lr) * 256 + k0);
            short8v a1 = *(const short8v*)(w1s + (size_t)(fbase + 16 + lr) * 256 + k0);
            #pragma unroll
            for (int pj = 0; pj < 6; ++pj){
                short8v bb = *(const short8v*)(x1s + (pj * 16 + lr) * 264 + k0);
                acc1[0][pj] = __builtin_amdgcn_mfma_f32_16x16x32_bf16(a0, bb, acc1[0][pj], 0, 0, 0);
                acc1[1][pj] = __builtin_amdgcn_mfma_f32_16x16x32_bf16(a1, bb, acc1[1][pj], 0, 0, 0);
            }
        }
        #pragma unroll
        for (int fi = 0; fi < 2; ++fi)
        #pragma unroll
        for (int pj = 0; pj < 6; ++pj){
            int p = pj * 16 + lr;
            int fl = w * 32 + fi * 16 + lh * 4;
            short4v pk;
            #pragma unroll
            for (int r = 0; r < 4; ++r)
                pk[r] = (short)f2bf(fast_gelu(acc1[fi][pj][r]));
            *(short4v*)&ffs[p * 136 + fl] = pk;
        }
        __syncthreads();
        for (int ks = 0; ks < 4; ++ks){
            const int k0 = ks * 32 + lh * 8;
            short8v a2[4];
            #pragma unroll
            for (int ci = 0; ci < 4; ++ci)
                a2[ci] = *(const short8v*)(w2bf + (size_t)(cw + ci * 16 + lr) * 1024 + fc * 128 + k0);
            #pragma unroll
            for (int pj = 0; pj < 6; ++pj){
                short8v bb = *(const short8v*)(ffs + (pj * 16 + lr) * 136 + k0);
                #pragma unroll
                for (int ci = 0; ci < 4; ++ci)
                    acc2[ci][pj] = __builtin_amdgcn_mfma_f32_16x16x32_bf16(a2[ci], bb, acc2[ci][pj], 0, 0, 0);
            }
        }
        __syncthreads();
    }
    // epilogue: z = x1 + ffout, x1 = y*s1 + t1; BN2 partials
    float sv[16], tv[16];
    #pragma unroll
    for (int ci = 0; ci < 4; ++ci)
    #pragma unroll
    for (int r = 0; r < 4; ++r){
        int c = cw + ci * 16 + lh * 4 + r;
        sv[ci * 4 + r] = s1[c];
        tv[ci * 4 + r] = t1[c];
    }
    float cs[16], cq[16];
    #pragma unroll
    for (int i = 0; i < 16; ++i){ cs[i] = 0.f; cq[i] = 0.f; }
    #pragma unroll
    for (int ci = 0; ci < 4; ++ci)
    #pragma unroll
    for (int pj = 0; pj < 6; ++pj){
        int p = pj * 16 + lr;
        if (p < 81){
            int c = cw + ci * 16 + lh * 4;
            short4v yv = *(const short4v*)&x1s[p * 264 + c];
            #pragma unroll
            for (int r = 0; r < 4; ++r){
                float x1 = fmaf(bf2f((unsigned short)yv[r]), sv[ci * 4 + r], tv[ci * 4 + r]);
                float z = acc2[ci][pj][r] + x1;
                zb[(c + r) * 81 + p] = z;
                cs[ci * 4 + r] += z;
                cq[ci * 4 + r] += z * z;
            }
        }
    }
    #pragma unroll
    for (int i = 0; i < 16; ++i){
        cs[i] = wave16_red(cs[i]);
        cq[i] = wave16_red(cq[i]);
    }
    if (lr == 0){
        #pragma unroll
        for (int ci = 0; ci < 4; ++ci)
        #pragma unroll
        for (int r = 0; r < 4; ++r){
            int c = cw + ci * 16 + lh * 4 + r;
            p2[(size_t)c * 2048 + b]         = cs[ci * 4 + r];
            p2[(size_t)(256 + c) * 2048 + b] = cq[ci * 4 + r];
        }
    }
}

// ---------------- OLD BN apply (fallback) ----------------
__global__ __launch_bounds__(256) void k_bnapply(float* __restrict__ z,
                                                 const float* __restrict__ mean, const float* __restrict__ rstd,
                                                 const float* __restrict__ g, const float* __restrict__ bia,
                                                 unsigned int n){
    unsigned int i = blockIdx.x * 256u + threadIdx.x;
    unsigned int st = gridDim.x * 256u;
    for (; i < n; i += st){
        int c = (int)((i / 81u) & 255u);
        float v = z[i];
        z[i] = (v - mean[c]) * rstd[c] * g[c] + bia[c];
    }
}

// ---------------- NEW BN apply via (s,t) ----------------
__global__ __launch_bounds__(256) void k_bnapply_st(float* __restrict__ z,
                                                    const float* __restrict__ s2, const float* __restrict__ t2,
                                                    unsigned int n){
    unsigned int i = blockIdx.x * 256u + threadIdx.x;
    unsigned int st = gridDim.x * 256u;
    for (; i < n; i += st){
        int c = (int)((i / 81u) & 255u);
        z[i] = fmaf(z[i], s2[c], t2[c]);
    }
}

extern "C" void kernel_launch(void* const* d_in, const int* in_sizes, int n_in,
                              void* d_out, int out_size, void* d_ws, size_t ws_size,
                              hipStream_t stream){
    const float* x     = (const float*)d_in[0];
    const float* qkvw  = (const float*)d_in[1];
    const float* relw1 = (const float*)d_in[2];
    const float* relw2 = (const float*)d_in[3];
    const float* ow    = (const float*)d_in[4];
    const float* ffw1  = (const float*)d_in[5];
    const float* ffw2  = (const float*)d_in[6];
    const float* g1    = (const float*)d_in[7];
    const float* b1    = (const float*)d_in[8];
    const float* g2    = (const float*)d_in[9];
    const float* b2    = (const float*)d_in[10];
    float* out = (float*)d_out;
    char* ws = (char*)d_ws;

    unsigned short* w1rel = (unsigned short*)ws;             // 1,327,104 B
    float* h     = (float*)(ws + 1327104);                   // 262,144 B
    float* mean1 = (float*)(ws + 1589248);
    float* rstd1 = (float*)(ws + 1590272);
    float* mean2 = (float*)(ws + 1591296);
    float* rstd2 = (float*)(ws + 1592320);
    unsigned short* w1bf  = (unsigned short*)(ws + 1593344); // 524,288 B (fallback)
    unsigned short* w2bf  = (unsigned short*)(ws + 2117632); // 524,288 B
    unsigned short* qkvwb = (unsigned short*)(ws + 2641920); // 49,152 B
    unsigned short* owb   = (unsigned short*)(ws + 2691072); // 131,072 B
    unsigned short* w1s   = (unsigned short*)(ws + 2822144); // 524,288 B
    float* bias1 = (float*)(ws + 3346432);                   // 4,096 B
    float* s1    = (float*)(ws + 3350528);
    float* t1    = (float*)(ws + 3351552);
    float* s2    = (float*)(ws + 3352576);
    float* t2    = (float*)(ws + 3353600);
    float* p1    = (float*)(ws + 3354624);                   // 4,194,304 B
    float* p2    = (float*)(ws + 7548928);                   // 4,194,304 B
    unsigned short* yT = (unsigned short*)(ws + 11743232);   // 103,809,024 B
    const size_t WS_NEED = 11743232ull + 103809024ull;

    hipLaunchKernelGGL(k_f2bf, dim3(1024), dim3(256), 0, stream, relw1, w1rel, 663552);
    hipLaunchKernelGGL(k_f2bf, dim3(256),  dim3(256), 0, stream, ffw2, w2bf, 262144);
    hipLaunchKernelGGL(k_f2bf, dim3(96),   dim3(256), 0, stream, qkvw, qkvwb, 24576);
    hipLaunchKernelGGL(k_f2bf, dim3(256),  dim3(256), 0, stream, ow, owb, 65536);
    hipLaunchKernelGGL(k_h,    dim3(2048), dim3(256), 0, stream, x, w1rel, h);
    hipLaunchKernelGGL(k_attn_mfma, dim3(2048), dim3(256), 0, stream, x, qkvwb, relw2, h, out);

    if (ws_size >= WS_NEED){
        hipLaunchKernelGGL(k_oproj_v2, dim3(2048), dim3(256), 0, stream, x, owb, out, yT, p1);
        hipLaunchKernelGGL(k_red,      dim3(256),  dim3(256), 0, stream, p1, g1, b1, s1, t1);
        hipLaunchKernelGGL(k_w1scale,  dim3(1024), dim3(256), 0, stream, ffw1, s1, w1s);
        hipLaunchKernelGGL(k_bias1,    dim3(1024), dim3(64),  0, stream, ffw1, t1, bias1);
        hipLaunchKernelGGL(k_ff_v2,    dim3(2048), dim3(256), 0, stream, yT, w1s, w2bf, bias1, s1, t1, out, p2);
        hipLaunchKernelGGL(k_red,      dim3(256),  dim3(256), 0, stream, p2, g2, b2, s2, t2);
        hipLaunchKernelGGL(k_bnapply_st, dim3(2048), dim3(256), 0, stream, out, s2, t2, (unsigned int)NTOT);
    } else {
        hipLaunchKernelGGL(k_f2bf, dim3(256), dim3(256), 0, stream, ffw1, w1bf, 262144);
        hipLaunchKernelGGL(k_oproj_mfma, dim3(2048), dim3(256), 0, stream, x, owb, out);
        hipLaunchKernelGGL(k_stats, dim3(256), dim3(256), 0, stream, out, mean1, rstd1);
        hipLaunchKernelGGL(k_ff_mfma, dim3(2048), dim3(256), 0, stream, w1bf, w2bf, mean1, rstd1, g1, b1, out);
        hipLaunchKernelGGL(k_stats, dim3(256), dim3(256), 0, stream, out, mean2, rstd2);
        hipLaunchKernelGGL(k_bnapply, dim3(2048), dim3(256), 0, stream, out, mean2, rstd2, g2, b2, (unsigned int)NTOT);
    }
}

// Round 6
// 969.702 us; speedup vs baseline: 9.9611x; 1.3772x over previous
//
#include <hip/hip_runtime.h>
#include <math.h>

#define B_   2048
#define D_   256
#define H_   8
#define DEP_ 32
#define P_   81
#define FF_  1024
#define CHW  (D_*P_)      // 20736
#define NPOS (B_*P_)      // 165888
#define KREL (D_*P_)      // 20736
#define NTOT (B_*CHW)     // 42467328
#define EPS_ 1e-5f
#define YTP  264          // yT row pitch (halfs)
#define YTSZ (96*YTP)     // 25344 halfs per batch

typedef __attribute__((ext_vector_type(8))) short short8v;
typedef __attribute__((ext_vector_type(4))) short short4v;
typedef __attribute__((ext_vector_type(4))) float f32x4;

__device__ __forceinline__ float bf2f(unsigned short u){
    return __uint_as_float(((unsigned int)u) << 16);
}
__device__ __forceinline__ unsigned short f2bf(float f){
    unsigned int x = __float_as_uint(f);
    return (unsigned short)((x + 0x7FFFu + ((x >> 16) & 1u)) >> 16); // RNE
}
// fast erf-based GELU: A&S 7.1.26, |erf err| < 1.5e-7
__device__ __forceinline__ float fast_gelu(float x){
    float u = 0.70710678118654752f * x;
    float a = fabsf(u);
    float t = __builtin_amdgcn_rcpf(fmaf(0.3275911f, a, 1.f));
    float p = t * fmaf(t, fmaf(t, fmaf(t, fmaf(t, 1.061405429f, -1.453152027f),
                         1.421413741f), -0.284496736f), 0.254829592f);
    float e = __expf(-u * u);
    float er = copysignf(fmaf(-p, e, 1.f), u);
    return 0.5f * x * (1.f + er);
}
__device__ __forceinline__ float wave16_red(float v){
    v += __shfl_xor(v, 1); v += __shfl_xor(v, 2);
    v += __shfl_xor(v, 4); v += __shfl_xor(v, 8);
    return v;
}

// ---------------- generic f32 -> bf16 cast ----------------
__global__ __launch_bounds__(256) void k_f2bf(const float* __restrict__ w,
                                              unsigned short* __restrict__ o, int n){
    int i = blockIdx.x * 256 + threadIdx.x;
    int st = gridDim.x * 256;
    for (; i < n; i += st) o[i] = f2bf(w[i]);
}

// ---------------- OLD K0 (fallback): scalar h ----------------
__global__ __launch_bounds__(256) void k_h(const float* __restrict__ x,
                                           const unsigned short* __restrict__ w1b,
                                           float* __restrict__ h){
    const int b = blockIdx.x, t = threadIdx.x;
    const float* xb = x + (size_t)b * CHW;
    float acc[32];
    #pragma unroll
    for (int j = 0; j < 32; ++j) acc[j] = 0.f;
    for (int i4 = t * 4; i4 < CHW; i4 += 1024){
        const float4 xv = *(const float4*)(xb + i4);
        #pragma unroll 8
        for (int j = 0; j < 32; ++j){
            const uint2 wv = *(const uint2*)(w1b + (size_t)j * KREL + i4);
            float w0 = bf2f((unsigned short)(wv.x & 0xffffu));
            float w1 = bf2f((unsigned short)(wv.x >> 16));
            float w2 = bf2f((unsigned short)(wv.y & 0xffffu));
            float w3 = bf2f((unsigned short)(wv.y >> 16));
            acc[j] += xv.x * w0 + xv.y * w1 + xv.z * w2 + xv.w * w3;
        }
    }
    __shared__ float red[264 * 33];
    #pragma unroll
    for (int j = 0; j < 32; ++j) red[t * 33 + j] = acc[j];
    __syncthreads();
    {
        const int j = t & 31, g = t >> 5;
        float s = 0.f;
        for (int r = g * 32; r < g * 32 + 32; ++r) s += red[r * 33 + j];
        red[(256 + g) * 33 + j] = s;
    }
    __syncthreads();
    if (t < 32){
        float v = 0.f;
        #pragma unroll
        for (int g2 = 0; g2 < 8; ++g2) v += red[(256 + g2) * 33 + t];
        h[b * 32 + t] = v;
    }
}

// ---------------- NEW K0: MFMA h-partials ----------------
// grid = 128 batch-tiles x 4 K-slices; block = 4 waves.
// wave computes mfma(A=w1 rows, B=16 batch rows of x) over interleaved k-steps.
// output: j = lh*4+r (A row), batch = lr (B row)  [validated C/D convention]
__global__ __launch_bounds__(256) void k_h_mfma(const float* __restrict__ x,
                                                const unsigned short* __restrict__ w1b,
                                                float* __restrict__ ph){
    const int bt = blockIdx.x >> 2, ks = blockIdx.x & 3;
    const int t = threadIdx.x, w = t >> 6, lane = t & 63;
    const int lr = lane & 15, lh = lane >> 4;
    const int b0 = bt * 16;
    f32x4 acc0 = {0.f,0.f,0.f,0.f}, acc1 = {0.f,0.f,0.f,0.f};
    const float* xrow = x + (size_t)(b0 + lr) * KREL;
    const unsigned short* wr0 = w1b + (size_t)lr * KREL;
    const unsigned short* wr1 = w1b + (size_t)(16 + lr) * KREL;
    for (int kk = w; kk < 162; kk += 4){
        const int k0 = (ks * 162 + kk) * 32 + lh * 8;
        short8v a0 = *(const short8v*)(wr0 + k0);
        short8v a1 = *(const short8v*)(wr1 + k0);
        const float4 xv0 = *(const float4*)(xrow + k0);
        const float4 xv1 = *(const float4*)(xrow + k0 + 4);
        short8v bb;
        bb[0] = (short)f2bf(xv0.x); bb[1] = (short)f2bf(xv0.y);
        bb[2] = (short)f2bf(xv0.z); bb[3] = (short)f2bf(xv0.w);
        bb[4] = (short)f2bf(xv1.x); bb[5] = (short)f2bf(xv1.y);
        bb[6] = (short)f2bf(xv1.z); bb[7] = (short)f2bf(xv1.w);
        acc0 = __builtin_amdgcn_mfma_f32_16x16x32_bf16(a0, bb, acc0, 0, 0, 0);
        acc1 = __builtin_amdgcn_mfma_f32_16x16x32_bf16(a1, bb, acc1, 0, 0, 0);
    }
    __shared__ float red[4][32][17];
    #pragma unroll
    for (int r = 0; r < 4; ++r){
        red[w][lh * 4 + r][lr]      = acc0[r];
        red[w][16 + lh * 4 + r][lr] = acc1[r];
    }
    __syncthreads();
    for (int i = t; i < 512; i += 256){
        int j = i >> 4, bb2 = i & 15;
        float s = red[0][j][bb2] + red[1][j][bb2] + red[2][j][bb2] + red[3][j][bb2];
        ph[(size_t)ks * 65536 + (size_t)(b0 + bb2) * 32 + j] = s;
    }
}

__global__ __launch_bounds__(256) void k_h_red(const float* __restrict__ ph,
                                               float* __restrict__ h){
    int i = blockIdx.x * 256 + threadIdx.x;   // 65536 outputs
    h[i] = ph[i] + ph[65536 + i] + ph[131072 + i] + ph[196608 + i];
}

// ---------------- K1: per-batch MFMA attention -> att (into d_out) ----------------
__global__ __launch_bounds__(256, 1) void k_attn_mfma(const float* __restrict__ x,
                                                      const unsigned short* __restrict__ qkvwb,
                                                      const float* __restrict__ relw2,
                                                      const float* __restrict__ h,
                                                      float* __restrict__ att){
    const int b = blockIdx.x, t = threadIdx.x;
    const int lane = t & 63, w = t >> 6;
    const int lr = lane & 15, lh = lane >> 4;

    __shared__ __align__(16) unsigned short x1s[96 * 264];   // x^T bf16 [p][c]
    __shared__ __align__(16) unsigned short Rl[96 * 40];     // R [pk][d]
    __shared__ __align__(16) unsigned short qL[4][96 * 40];
    __shared__ __align__(16) unsigned short krL[4][96 * 40];
    __shared__ __align__(16) unsigned short vL[4][32 * 104];
    __shared__ __align__(16) unsigned short pL[4][16 * 104];

    const float* xb = x + (size_t)b * CHW;

    {
        const float* hb = h + b * 32;
        float hreg[32];
        #pragma unroll
        for (int j = 0; j < 32; ++j) hreg[j] = hb[j];
        for (int idx = t; idx < 2592; idx += 256){
            int d = idx / 81, p = idx - d * 81;
            const float4* wr = (const float4*)(relw2 + (size_t)idx * 32);
            float s = 0.f;
            #pragma unroll
            for (int j = 0; j < 8; ++j){
                float4 wv = wr[j];
                s += wv.x * hreg[4*j] + wv.y * hreg[4*j+1] + wv.z * hreg[4*j+2] + wv.w * hreg[4*j+3];
            }
            Rl[p * 40 + d] = f2bf(s);
        }
        for (int idx = t; idx < 15 * 32; idx += 256){
            int p = 81 + (idx >> 5), d = idx & 31;
            Rl[p * 40 + d] = 0;
        }
    }
    for (int idx = t; idx < 15 * 132; idx += 256){
        int r = idx / 132, c = idx - r * 132;
        *(unsigned int*)&x1s[(81 + r) * 264 + 2 * c] = 0;
    }
    {
        float* tb = (float*)qL;
        for (int cc = 0; cc < 4; ++cc){
            for (int idx = t; idx < 64 * 81; idx += 256){
                int c = idx / 81, p = idx - c * 81;
                tb[c * 85 + p] = xb[(cc * 64 + c) * 81 + p];
            }
            __syncthreads();
            for (int idx = t; idx < 32 * 81; idx += 256){
                int c2 = idx & 31, p = idx >> 5;
                int c = 2 * c2;
                unsigned int pk = (unsigned int)f2bf(tb[c * 85 + p])
                                | ((unsigned int)f2bf(tb[(c + 1) * 85 + p]) << 16);
                *(unsigned int*)&x1s[p * 264 + cc * 64 + c] = pk;
            }
            __syncthreads();
        }
    }

    unsigned short* q_  = qL[w];
    unsigned short* kr_ = krL[w];
    unsigned short* v_  = vL[w];
    unsigned short* p_  = pL[w];

    for (int hi = 0; hi < 2; ++hi){
        const int hh = w + hi * 4;
        const int qrow = hh * 32, krow = 256 + hh * 32, vrow = 512 + hh * 32;
        const int gq = (qrow / 96) * 32, gk = (krow / 96) * 32, gv = (vrow / 96) * 32;

        {
            short8v a0 = *(const short8v*)(qkvwb + (size_t)(qrow + lr) * 32 + lh * 8);
            short8v a1 = *(const short8v*)(qkvwb + (size_t)(qrow + 16 + lr) * 32 + lh * 8);
            #pragma unroll
            for (int nt = 0; nt < 6; ++nt){
                short8v bb = *(const short8v*)(x1s + (nt * 16 + lr) * 264 + gq + lh * 8);
                f32x4 c0 = {0.f,0.f,0.f,0.f}, c1 = {0.f,0.f,0.f,0.f};
                c0 = __builtin_amdgcn_mfma_f32_16x16x32_bf16(a0, bb, c0, 0, 0, 0);
                c1 = __builtin_amdgcn_mfma_f32_16x16x32_bf16(a1, bb, c1, 0, 0, 0);
                int p = nt * 16 + lr;
                short4v p0, p1;
                #pragma unroll
                for (int r = 0; r < 4; ++r){ p0[r] = (short)f2bf(c0[r]); p1[r] = (short)f2bf(c1[r]); }
                *(short4v*)(q_ + p * 40 + lh * 4)      = p0;
                *(short4v*)(q_ + p * 40 + 16 + lh * 4) = p1;
            }
        }
        {
            short8v a0 = *(const short8v*)(qkvwb + (size_t)(krow + lr) * 32 + lh * 8);
            short8v a1 = *(const short8v*)(qkvwb + (size_t)(krow + 16 + lr) * 32 + lh * 8);
            #pragma unroll
            for (int nt = 0; nt < 6; ++nt){
                int p = nt * 16 + lr;
                short4v r0 = *(const short4v*)(Rl + p * 40 + lh * 4);
                short4v r1 = *(const short4v*)(Rl + p * 40 + 16 + lh * 4);
                f32x4 c0, c1;
                #pragma unroll
                for (int r = 0; r < 4; ++r){
                    c0[r] = bf2f((unsigned short)r0[r]);
                    c1[r] = bf2f((unsigned short)r1[r]);
                }
                short8v bb = *(const short8v*)(x1s + p * 264 + gk + lh * 8);
                c0 = __builtin_amdgcn_mfma_f32_16x16x32_bf16(a0, bb, c0, 0, 0, 0);
                c1 = __builtin_amdgcn_mfma_f32_16x16x32_bf16(a1, bb, c1, 0, 0, 0);
                short4v p0, p1;
                #pragma unroll
                for (int r = 0; r < 4; ++r){ p0[r] = (short)f2bf(c0[r]); p1[r] = (short)f2bf(c1[r]); }
                *(short4v*)(kr_ + p * 40 + lh * 4)      = p0;
                *(short4v*)(kr_ + p * 40 + 16 + lh * 4) = p1;
            }
        }
        {
            short8v a0 = *(const short8v*)(qkvwb + (size_t)(vrow + lr) * 32 + lh * 8);
            short8v a1 = *(const short8v*)(qkvwb + (size_t)(vrow + 16 + lr) * 32 + lh * 8);
            #pragma unroll
            for (int nt = 0; nt < 6; ++nt){
                short8v bb = *(const short8v*)(x1s + (nt * 16 + lr) * 264 + gv + lh * 8);
                f32x4 c0 = {0.f,0.f,0.f,0.f}, c1 = {0.f,0.f,0.f,0.f};
                c0 = __builtin_amdgcn_mfma_f32_16x16x32_bf16(a0, bb, c0, 0, 0, 0);
                c1 = __builtin_amdgcn_mfma_f32_16x16x32_bf16(a1, bb, c1, 0, 0, 0);
                int pk = nt * 16 + lr;
                #pragma unroll
                for (int r = 0; r < 4; ++r){
                    v_[(lh * 4 + r) * 104 + pk]        = f2bf(c0[r]);
                    v_[(16 + lh * 4 + r) * 104 + pk]   = f2bf(c1[r]);
                }
            }
        }
        float* ob = att + (size_t)b * CHW + (size_t)(hh * 32) * 81;
        for (int nt = 0; nt < 6; ++nt){
            short8v bq = *(const short8v*)(q_ + (nt * 16 + lr) * 40 + lh * 8);
            f32x4 sc[6];
            #pragma unroll
            for (int mt = 0; mt < 6; ++mt){
                short8v ak = *(const short8v*)(kr_ + (mt * 16 + lr) * 40 + lh * 8);
                f32x4 z = {0.f,0.f,0.f,0.f};
                sc[mt] = __builtin_amdgcn_mfma_f32_16x16x32_bf16(ak, bq, z, 0, 0, 0);
            }
            sc[5][0] = (lh == 0) ? sc[5][0] : -1e30f;
            sc[5][1] = -1e30f; sc[5][2] = -1e30f; sc[5][3] = -1e30f;
            float mx = -1e30f;
            #pragma unroll
            for (int mt = 0; mt < 6; ++mt)
            #pragma unroll
            for (int r = 0; r < 4; ++r) mx = fmaxf(mx, sc[mt][r]);
            mx = fmaxf(mx, __shfl_xor(mx, 16));
            mx = fmaxf(mx, __shfl_xor(mx, 32));
            const float scl = 0.17677669529663687f;
            float sum = 0.f;
            #pragma unroll
            for (int mt = 0; mt < 6; ++mt)
            #pragma unroll
            for (int r = 0; r < 4; ++r){
                float e = __expf((sc[mt][r] - mx) * scl);
                sc[mt][r] = e; sum += e;
            }
            sum += __shfl_xor(sum, 16);
            sum += __shfl_xor(sum, 32);
            float inv = 1.f / sum;
            #pragma unroll
            for (int mt = 0; mt < 6; ++mt){
                short4v pv;
                #pragma unroll
                for (int r = 0; r < 4; ++r) pv[r] = (short)f2bf(sc[mt][r] * inv);
                *(short4v*)(p_ + lr * 104 + mt * 16 + lh * 4) = pv;
            }
            f32x4 o0 = {0.f,0.f,0.f,0.f}, o1 = {0.f,0.f,0.f,0.f};
            #pragma unroll
            for (int ks = 0; ks < 3; ++ks){
                short8v ap  = *(const short8v*)(p_ + lr * 104 + ks * 32 + lh * 8);
                short8v bv0 = *(const short8v*)(v_ + lr * 104 + ks * 32 + lh * 8);
                short8v bv1 = *(const short8v*)(v_ + (16 + lr) * 104 + ks * 32 + lh * 8);
                o0 = __builtin_amdgcn_mfma_f32_16x16x32_bf16(ap, bv0, o0, 0, 0, 0);
                o1 = __builtin_amdgcn_mfma_f32_16x16x32_bf16(ap, bv1, o1, 0, 0, 0);
            }
            int pq0 = nt * 16 + lh * 4;
            #pragma unroll
            for (int r = 0; r < 4; ++r){
                int pq = pq0 + r;
                if (pq < 81){
                    ob[lr * 81 + pq]        = o0[r];
                    ob[(16 + lr) * 81 + pq] = o1[r];
                }
            }
        }
    }
}

// ---------------- OLD K1b (fallback): y = o_w @ att + x in-place ----------------
__global__ __launch_bounds__(256, 2) void k_oproj_mfma(const float* __restrict__ x,
                                                       const unsigned short* __restrict__ owb,
                                                       float* __restrict__ yz){
    const int b = blockIdx.x, t = threadIdx.x;
    const int lane = t & 63, w = t >> 6;
    const int lr = lane & 15, lh = lane >> 4;
    float* zb = yz + (size_t)b * CHW;

    __shared__ __align__(16) unsigned short attT[96 * 264];
    __shared__ __align__(16) float tb[64 * 85];

    for (int idx = t; idx < 15 * 132; idx += 256){
        int r = idx / 132, c = idx - r * 132;
        *(unsigned int*)&attT[(81 + r) * 264 + 2 * c] = 0;
    }
    for (int cc = 0; cc < 4; ++cc){
        for (int idx = t; idx < 64 * 81; idx += 256){
            int c = idx / 81, p = idx - c * 81;
            tb[c * 85 + p] = zb[(cc * 64 + c) * 81 + p];
        }
        __syncthreads();
        for (int idx = t; idx < 32 * 81; idx += 256){
            int c2 = idx & 31, p = idx >> 5;
            int c = 2 * c2;
            unsigned int pk = (unsigned int)f2bf(tb[c * 85 + p])
                            | ((unsigned int)f2bf(tb[(c + 1) * 85 + p]) << 16);
            *(unsigned int*)&attT[p * 264 + cc * 64 + c] = pk;
        }
        __syncthreads();
    }

    const int cw = w * 64;
    f32x4 acc[4][6];
    #pragma unroll
    for (int ci = 0; ci < 4; ++ci)
    #pragma unroll
    for (int pj = 0; pj < 6; ++pj)
        acc[ci][pj] = (f32x4){0.f, 0.f, 0.f, 0.f};

    for (int ks = 0; ks < 8; ++ks){
        const int k0 = ks * 32 + lh * 8;
        short8v a[4];
        #pragma unroll
        for (int ci = 0; ci < 4; ++ci)
            a[ci] = *(const short8v*)(owb + (size_t)(cw + ci * 16 + lr) * 256 + k0);
        #pragma unroll
        for (int pj = 0; pj < 6; ++pj){
            short8v bb = *(const short8v*)(attT + (pj * 16 + lr) * 264 + k0);
            #pragma unroll
            for (int ci = 0; ci < 4; ++ci)
                acc[ci][pj] = __builtin_amdgcn_mfma_f32_16x16x32_bf16(a[ci], bb, acc[ci][pj], 0, 0, 0);
        }
    }
    const float* xb = x + (size_t)b * CHW;
    #pragma unroll
    for (int ci = 0; ci < 4; ++ci)
    #pragma unroll
    for (int pj = 0; pj < 6; ++pj){
        int p = pj * 16 + lr;
        if (p < 81){
            int c = cw + ci * 16 + lh * 4;
            #pragma unroll
            for (int r = 0; r < 4; ++r)
                zb[(c + r) * 81 + p] = acc[ci][pj][r] + xb[(c + r) * 81 + p];
        }
    }
}

// ---------------- NEW K1b: o-proj + residual -> yT bf16 (ws) + BN1 partials ----------------
__global__ __launch_bounds__(256, 2) void k_oproj_v2(const float* __restrict__ x,
                                                     const unsigned short* __restrict__ owb,
                                                     const float* __restrict__ att,
                                                     unsigned short* __restrict__ yT,
                                                     float* __restrict__ p1){
    const int b = blockIdx.x, t = threadIdx.x;
    const int lane = t & 63, w = t >> 6;
    const int lr = lane & 15, lh = lane >> 4;
    const float* ab = att + (size_t)b * CHW;

    __shared__ __align__(16) unsigned short attT[96 * 264];
    __shared__ __align__(16) float tb[64 * 85];

    for (int idx = t; idx < 15 * 132; idx += 256){
        int r = idx / 132, c = idx - r * 132;
        *(unsigned int*)&attT[(81 + r) * 264 + 2 * c] = 0;
    }
    for (int cc = 0; cc < 4; ++cc){
        for (int idx = t; idx < 64 * 81; idx += 256){
            int c = idx / 81, p = idx - c * 81;
            tb[c * 85 + p] = ab[(cc * 64 + c) * 81 + p];
        }
        __syncthreads();
        for (int idx = t; idx < 32 * 81; idx += 256){
            int c2 = idx & 31, p = idx >> 5;
            int c = 2 * c2;
            unsigned int pk = (unsigned int)f2bf(tb[c * 85 + p])
                            | ((unsigned int)f2bf(tb[(c + 1) * 85 + p]) << 16);
            *(unsigned int*)&attT[p * 264 + cc * 64 + c] = pk;
        }
        __syncthreads();
    }

    const int cw = w * 64;
    f32x4 acc[4][6];
    #pragma unroll
    for (int ci = 0; ci < 4; ++ci)
    #pragma unroll
    for (int pj = 0; pj < 6; ++pj)
        acc[ci][pj] = (f32x4){0.f, 0.f, 0.f, 0.f};

    for (int ks = 0; ks < 8; ++ks){
        const int k0 = ks * 32 + lh * 8;
        short8v a[4];
        #pragma unroll
        for (int ci = 0; ci < 4; ++ci)
            a[ci] = *(const short8v*)(owb + (size_t)(cw + ci * 16 + lr) * 256 + k0);
        #pragma unroll
        for (int pj = 0; pj < 6; ++pj){
            short8v bb = *(const short8v*)(attT + (pj * 16 + lr) * 264 + k0);
            #pragma unroll
            for (int ci = 0; ci < 4; ++ci)
                acc[ci][pj] = __builtin_amdgcn_mfma_f32_16x16x32_bf16(a[ci], bb, acc[ci][pj], 0, 0, 0);
        }
    }
    // epilogue: y = acc + x; write yT bf16; accumulate BN1 partials
    const float* xb = x + (size_t)b * CHW;
    unsigned short* yb = yT + (size_t)b * YTSZ;
    float cs[16], cq[16];
    #pragma unroll
    for (int i = 0; i < 16; ++i){ cs[i] = 0.f; cq[i] = 0.f; }
    #pragma unroll
    for (int ci = 0; ci < 4; ++ci)
    #pragma unroll
    for (int pj = 0; pj < 6; ++pj){
        int p = pj * 16 + lr;
        int c = cw + ci * 16 + lh * 4;
        short4v pk;
        if (p < 81){
            #pragma unroll
            for (int r = 0; r < 4; ++r){
                float y = acc[ci][pj][r] + xb[(c + r) * 81 + p];
                pk[r] = (short)f2bf(y);
                cs[ci * 4 + r] += y;
                cq[ci * 4 + r] += y * y;
            }
        } else {
            #pragma unroll
            for (int r = 0; r < 4; ++r) pk[r] = 0;
        }
        *(short4v*)(yb + p * YTP + c) = pk;
    }
    #pragma unroll
    for (int i = 0; i < 16; ++i){
        cs[i] = wave16_red(cs[i]);
        cq[i] = wave16_red(cq[i]);
    }
    if (lr == 0){
        #pragma unroll
        for (int ci = 0; ci < 4; ++ci)
        #pragma unroll
        for (int r = 0; r < 4; ++r){
            int c = cw + ci * 16 + lh * 4 + r;
            p1[(size_t)c * 2048 + b]         = cs[ci * 4 + r];
            p1[(size_t)(256 + c) * 2048 + b] = cq[ci * 4 + r];
        }
    }
}

// ---------------- OLD stats (fallback) ----------------
__global__ __launch_bounds__(256) void k_stats(const float* __restrict__ buf,
                                               float* __restrict__ mean, float* __restrict__ rstd){
    const int c = blockIdx.x, t = threadIdx.x;
    float s = 0.f, q = 0.f;
    for (int idx = t; idx < NPOS; idx += 256){
        int b = idx / 81, p = idx - b * 81;
        float v = buf[(size_t)b * CHW + c * 81 + p];
        s += v; q += v * v;
    }
    __shared__ float rs[256], rq[256];
    rs[t] = s; rq[t] = q;
    __syncthreads();
    for (int k = 128; k; k >>= 1){
        if (t < k){ rs[t] += rs[t + k]; rq[t] += rq[t + k]; }
        __syncthreads();
    }
    if (t == 0){
        float m = rs[0] / (float)NPOS;
        float var = rq[0] / (float)NPOS - m * m;
        mean[c] = m;
        rstd[c] = rsqrtf(var + EPS_);
    }
}

// ---------------- reduce partials -> (s,t) affine BN params ----------------
__global__ __launch_bounds__(256) void k_red(const float* __restrict__ part,
                                             const float* __restrict__ g, const float* __restrict__ bia,
                                             float* __restrict__ sOut, float* __restrict__ tOut){
    const int c = blockIdx.x, t = threadIdx.x;
    float s = 0.f, q = 0.f;
    #pragma unroll
    for (int i = 0; i < 8; ++i){
        s += part[(size_t)c * 2048 + t + i * 256];
        q += part[(size_t)(256 + c) * 2048 + t + i * 256];
    }
    __shared__ float rs[256], rq[256];
    rs[t] = s; rq[t] = q;
    __syncthreads();
    for (int k = 128; k; k >>= 1){
        if (t < k){ rs[t] += rs[t + k]; rq[t] += rq[t + k]; }
        __syncthreads();
    }
    if (t == 0){
        float m = rs[0] / (float)NPOS;
        float var = rq[0] / (float)NPOS - m * m;
        float sc = g[c] * rsqrtf(var + EPS_);
        sOut[c] = sc;
        tOut[c] = bia[c] - m * sc;
    }
}

// ---------------- w1s[f][c] = bf16(w1[f][c]*s1[c]) ----------------
__global__ __launch_bounds__(256) void k_w1scale(const float* __restrict__ w1,
                                                 const float* __restrict__ s1,
                                                 unsigned short* __restrict__ w1s){
    const int f = blockIdx.x, t = threadIdx.x;
    w1s[f * 256 + t] = f2bf(w1[f * 256 + t] * s1[t]);
}

// ---------------- bias1[f] = sum_c w1[f][c]*t1[c] ----------------
__global__ __launch_bounds__(64) void k_bias1(const float* __restrict__ w1,
                                              const float* __restrict__ t1,
                                              float* __restrict__ bias1){
    const int f = blockIdx.x, t = threadIdx.x;
    const float4 wv = *(const float4*)(w1 + f * 256 + t * 4);
    const float4 tv = *(const float4*)(t1 + t * 4);
    float s = wv.x * tv.x + wv.y * tv.y + wv.z * tv.z + wv.w * tv.w;
    #pragma unroll
    for (int m = 1; m < 64; m <<= 1) s += __shfl_xor(s, m);
    if (t == 0) bias1[f] = s;
}

// ---------------- OLD K3 (fallback) ----------------
__global__ __launch_bounds__(256, 2) void k_ff_mfma(const unsigned short* __restrict__ w1bf,
                                                    const unsigned short* __restrict__ w2bf,
                                                    const float* __restrict__ mean1, const float* __restrict__ rstd1,
                                                    const float* __restrict__ g1, const float* __restrict__ b1,
                                                    float* __restrict__ yz){
    const int b = blockIdx.x, t = threadIdx.x;
    const int lane = t & 63, w = t >> 6;
    const int lr = lane & 15, lh = lane >> 4;
    float* zb = yz + (size_t)b * CHW;

    __shared__ __align__(16) unsigned short x1s[96 * 264];
    __shared__ __align__(16) unsigned char ubuf[26112];
    unsigned short* ffs = (unsigned short*)ubuf;
    float* tb = (float*)ubuf;

    for (int idx = t; idx < 15 * 132; idx += 256){
        int r = idx / 132, c = idx - r * 132;
        *(unsigned int*)&x1s[(81 + r) * 264 + 2 * c] = 0;
    }
    for (int cc = 0; cc < 4; ++cc){
        for (int idx = t; idx < 64 * 81; idx += 256){
            int c = idx / 81, p = idx - c * 81;
            int gc = cc * 64 + c;
            float v = zb[gc * 81 + p];
            v = (v - mean1[gc]) * rstd1[gc] * g1[gc] + b1[gc];
            tb[c * 85 + p] = v;
        }
        __syncthreads();
        for (int idx = t; idx < 32 * 81; idx += 256){
            int c2 = idx & 31, p = idx >> 5;
            int c = 2 * c2;
            unsigned int pk = (unsigned int)f2bf(tb[c * 85 + p])
                            | ((unsigned int)f2bf(tb[(c + 1) * 85 + p]) << 16);
            *(unsigned int*)&x1s[p * 264 + cc * 64 + c] = pk;
        }
        __syncthreads();
    }

    const int cw = w * 64;
    f32x4 acc2[4][6];
    #pragma unroll
    for (int ci = 0; ci < 4; ++ci)
    #pragma unroll
    for (int pj = 0; pj < 6; ++pj)
        acc2[ci][pj] = (f32x4){0.f, 0.f, 0.f, 0.f};

    for (int fc = 0; fc < 8; ++fc){
        f32x4 acc1[2][6];
        #pragma unroll
        for (int fi = 0; fi < 2; ++fi)
        #pragma unroll
        for (int pj = 0; pj < 6; ++pj)
            acc1[fi][pj] = (f32x4){0.f, 0.f, 0.f, 0.f};
        const int fbase = fc * 128 + w * 32;
        for (int ks = 0; ks < 8; ++ks){
            const int k0 = ks * 32 + lh * 8;
            short8v a0 = *(const short8v*)(w1bf + (size_t)(fbase + lr) * 256 + k0);
            short8v a1 = *(const short8v*)(w1bf + (size_t)(fbase + 16 + lr) * 256 + k0);
            #pragma unroll
            for (int pj = 0; pj < 6; ++pj){
                short8v bb = *(const short8v*)(x1s + (pj * 16 + lr) * 264 + k0);
                acc1[0][pj] = __builtin_amdgcn_mfma_f32_16x16x32_bf16(a0, bb, acc1[0][pj], 0, 0, 0);
                acc1[1][pj] = __builtin_amdgcn_mfma_f32_16x16x32_bf16(a1, bb, acc1[1][pj], 0, 0, 0);
            }
        }
        #pragma unroll
        for (int fi = 0; fi < 2; ++fi)
        #pragma unroll
        for (int pj = 0; pj < 6; ++pj){
            int p = pj * 16 + lr;
            int fl = w * 32 + fi * 16 + lh * 4;
            short4v pk;
            #pragma unroll
            for (int r = 0; r < 4; ++r){
                float v = acc1[fi][pj][r];
                v = 0.5f * v * (1.f + erff(v * 0.70710678118654752f));
                pk[r] = (short)f2bf(v);
            }
            *(short4v*)&ffs[p * 136 + fl] = pk;
        }
        __syncthreads();
        for (int ks = 0; ks < 4; ++ks){
            const int k0 = ks * 32 + lh * 8;
            short8v a2[4];
            #pragma unroll
            for (int ci = 0; ci < 4; ++ci)
                a2[ci] = *(const short8v*)(w2bf + (size_t)(cw + ci * 16 + lr) * 1024 + fc * 128 + k0);
            #pragma unroll
            for (int pj = 0; pj < 6; ++pj){
                short8v bb = *(const short8v*)(ffs + (pj * 16 + lr) * 136 + k0);
                #pragma unroll
                for (int ci = 0; ci < 4; ++ci)
                    acc2[ci][pj] = __builtin_amdgcn_mfma_f32_16x16x32_bf16(a2[ci], bb, acc2[ci][pj], 0, 0, 0);
            }
        }
        __syncthreads();
    }
    #pragma unroll
    for (int ci = 0; ci < 4; ++ci)
    #pragma unroll
    for (int pj = 0; pj < 6; ++pj){
        int p = pj * 16 + lr;
        if (p < 81){
            int c = cw + ci * 16 + lh * 4;
            short4v res = *(const short4v*)&x1s[p * 264 + c];
            #pragma unroll
            for (int r = 0; r < 4; ++r)
                zb[(c + r) * 81 + p] = acc2[ci][pj][r] + bf2f((unsigned short)res[r]);
        }
    }
}

// ---------------- NEW K3: FF from yT, BN folded, fast gelu, BN2 partials ----------------
__global__ __launch_bounds__(256, 2) void k_ff_v2(const unsigned short* __restrict__ yT,
                                                  const unsigned short* __restrict__ w1s,
                                                  const unsigned short* __restrict__ w2bf,
                                                  const float* __restrict__ bias1,
                                                  const float* __restrict__ s1, const float* __restrict__ t1,
                                                  float* __restrict__ yz,
                                                  float* __restrict__ p2){
    const int b = blockIdx.x, t = threadIdx.x;
    const int lane = t & 63, w = t >> 6;
    const int lr = lane & 15, lh = lane >> 4;
    float* zb = yz + (size_t)b * CHW;

    __shared__ __align__(16) unsigned short x1s[96 * 264];   // raw y bf16 [p][c]
    __shared__ __align__(16) unsigned short ffs[96 * 136];

    // stage yT -> LDS (linear 16B copy)
    {
        const short8v* src = (const short8v*)(yT + (size_t)b * YTSZ);
        short8v* dst = (short8v*)x1s;
        for (int idx = t; idx < 3168; idx += 256) dst[idx] = src[idx];
    }
    __syncthreads();

    const int cw = w * 64;
    f32x4 acc2[4][6];
    #pragma unroll
    for (int ci = 0; ci < 4; ++ci)
    #pragma unroll
    for (int pj = 0; pj < 6; ++pj)
        acc2[ci][pj] = (f32x4){0.f, 0.f, 0.f, 0.f};

    for (int fc = 0; fc < 8; ++fc){
        const int fbase = fc * 128 + w * 32;
        float b4[2][4];
        #pragma unroll
        for (int fi = 0; fi < 2; ++fi)
        #pragma unroll
        for (int r = 0; r < 4; ++r)
            b4[fi][r] = bias1[fbase + fi * 16 + lh * 4 + r];
        f32x4 acc1[2][6];
        #pragma unroll
        for (int fi = 0; fi < 2; ++fi)
        #pragma unroll
        for (int pj = 0; pj < 6; ++pj){
            acc1[fi][pj][0] = b4[fi][0]; acc1[fi][pj][1] = b4[fi][1];
            acc1[fi][pj][2] = b4[fi][2]; acc1[fi][pj][3] = b4[fi][3];
        }
        for (int ks = 0; ks < 8; ++ks){
            const int k0 = ks * 32 + lh * 8;
            short8v a0 = *(const short8v*)(w1s + (size_t)(fbase + lr) * 256 + k0);
            short8v a1 = *(const short8v*)(w1s + (size_t)(fbase + 16 + lr) * 256 + k0);
            #pragma unroll
            for (int pj = 0; pj < 6; ++pj){
                short8v bb = *(const short8v*)(x1s + (pj * 16 + lr) * 264 + k0);
                acc1[0][pj] = __builtin_amdgcn_mfma_f32_16x16x32_bf16(a0, bb, acc1[0][pj], 0, 0, 0);
                acc1[1][pj] = __builtin_amdgcn_mfma_f32_16x16x32_bf16(a1, bb, acc1[1][pj], 0, 0, 0);
            }
        }
        #pragma unroll
        for (int fi = 0; fi < 2; ++fi)
        #pragma unroll
        for (int pj = 0; pj < 6; ++pj){
            int p = pj * 16 + lr;
            int fl = w * 32 + fi * 16 + lh * 4;
            short4v pk;
            #pragma unroll
            for (int r = 0; r < 4; ++r)
                pk[r] = (short)f2bf(fast_gelu(acc1[fi][pj][r]));
            *(short4v*)&ffs[p * 136 + fl] = pk;
        }
        __syncthreads();
        for (int ks = 0; ks < 4; ++ks){
            const int k0 = ks * 32 + lh * 8;
            short8v a2[4];
            #pragma unroll
            for (int ci = 0; ci < 4; ++ci)
                a2[ci] = *(const short8v*)(w2bf + (size_t)(cw + ci * 16 + lr) * 1024 + fc * 128 + k0);
            #pragma unroll
            for (int pj = 0; pj < 6; ++pj){
                short8v bb = *(const short8v*)(ffs + (pj * 16 + lr) * 136 + k0);
                #pragma unroll
                for (int ci = 0; ci < 4; ++ci)
                    acc2[ci][pj] = __builtin_amdgcn_mfma_f32_16x16x32_bf16(a2[ci], bb, acc2[ci][pj], 0, 0, 0);
            }
        }
        __syncthreads();
    }
    // epilogue: z = x1 + ffout, x1 = y*s1 + t1; BN2 partials
    float sv[16], tv[16];
    #pragma unroll
    for (int ci = 0; ci < 4; ++ci)
    #pragma unroll
    for (int r = 0; r < 4; ++r){
        int c = cw + ci * 16 + lh * 4 + r;
        sv[ci * 4 + r] = s1[c];
        tv[ci * 4 + r] = t1[c];
    }
    float cs[16], cq[16];
    #pragma unroll
    for (int i = 0; i < 16; ++i){ cs[i] = 0.f; cq[i] = 0.f; }
    #pragma unroll
    for (int ci = 0; ci < 4; ++ci)
    #pragma unroll
    for (int pj = 0; pj < 6; ++pj){
        int p = pj * 16 + lr;
        if (p < 81){
            int c = cw + ci * 16 + lh * 4;
            short4v yv = *(const short4v*)&x1s[p * 264 + c];
            #pragma unroll
            for (int r = 0; r < 4; ++r){
                float x1 = fmaf(bf2f((unsigned short)yv[r]), sv[ci * 4 + r], tv[ci * 4 + r]);
                float z = acc2[ci][pj][r] + x1;
                zb[(c + r) * 81 + p] = z;
                cs[ci * 4 + r] += z;
                cq[ci * 4 + r] += z * z;
            }
        }
    }
    #pragma unroll
    for (int i = 0; i < 16; ++i){
        cs[i] = wave16_red(cs[i]);
        cq[i] = wave16_red(cq[i]);
    }
    if (lr == 0){
        #pragma unroll
        for (int ci = 0; ci < 4; ++ci)
        #pragma unroll
        for (int r = 0; r < 4; ++r){
            int c = cw + ci * 16 + lh * 4 + r;
            p2[(size_t)c * 2048 + b]         = cs[ci * 4 + r];
            p2[(size_t)(256 + c) * 2048 + b] = cq[ci * 4 + r];
        }
    }
}

// ---------------- OLD BN apply (fallback) ----------------
__global__ __launch_bounds__(256) void k_bnapply(float* __restrict__ z,
                                                 const float* __restrict__ mean, const float* __restrict__ rstd,
                                                 const float* __restrict__ g, const float* __restrict__ bia,
                                                 unsigned int n){
    unsigned int i = blockIdx.x * 256u + threadIdx.x;
    unsigned int st = gridDim.x * 256u;
    for (; i < n; i += st){
        int c = (int)((i / 81u) & 255u);
        float v = z[i];
        z[i] = (v - mean[c]) * rstd[c] * g[c] + bia[c];
    }
}

// ---------------- NEW BN apply via (s,t) ----------------
__global__ __launch_bounds__(256) void k_bnapply_st(float* __restrict__ z,
                                                    const float* __restrict__ s2, const float* __restrict__ t2,
                                                    unsigned int n){
    unsigned int i = blockIdx.x * 256u + threadIdx.x;
    unsigned int st = gridDim.x * 256u;
    for (; i < n; i += st){
        int c = (int)((i / 81u) & 255u);
        z[i] = fmaf(z[i], s2[c], t2[c]);
    }
}

extern "C" void kernel_launch(void* const* d_in, const int* in_sizes, int n_in,
                              void* d_out, int out_size, void* d_ws, size_t ws_size,
                              hipStream_t stream){
    const float* x     = (const float*)d_in[0];
    const float* qkvw  = (const float*)d_in[1];
    const float* relw1 = (const float*)d_in[2];
    const float* relw2 = (const float*)d_in[3];
    const float* ow    = (const float*)d_in[4];
    const float* ffw1  = (const float*)d_in[5];
    const float* ffw2  = (const float*)d_in[6];
    const float* g1    = (const float*)d_in[7];
    const float* b1    = (const float*)d_in[8];
    const float* g2    = (const float*)d_in[9];
    const float* b2    = (const float*)d_in[10];
    float* out = (float*)d_out;
    char* ws = (char*)d_ws;

    unsigned short* w1rel = (unsigned short*)ws;             // 1,327,104 B
    float* h     = (float*)(ws + 1327104);                   // 262,144 B
    float* mean1 = (float*)(ws + 1589248);
    float* rstd1 = (float*)(ws + 1590272);
    float* mean2 = (float*)(ws + 1591296);
    float* rstd2 = (float*)(ws + 1592320);
    unsigned short* w1bf  = (unsigned short*)(ws + 1593344); // 524,288 B (fallback)
    unsigned short* w2bf  = (unsigned short*)(ws + 2117632); // 524,288 B
    unsigned short* qkvwb = (unsigned short*)(ws + 2641920); // 49,152 B
    unsigned short* owb   = (unsigned short*)(ws + 2691072); // 131,072 B
    unsigned short* w1s   = (unsigned short*)(ws + 2822144); // 524,288 B
    float* bias1 = (float*)(ws + 3346432);                   // 4,096 B
    float* s1    = (float*)(ws + 3350528);
    float* t1    = (float*)(ws + 3351552);
    float* s2    = (float*)(ws + 3352576);
    float* t2    = (float*)(ws + 3353600);
    float* p1    = (float*)(ws + 3354624);                   // 4,194,304 B
    float* p2    = (float*)(ws + 7548928);                   // 4,194,304 B
    unsigned short* yT = (unsigned short*)(ws + 11743232);   // 103,809,024 B
    const size_t WS_NEED = 11743232ull + 103809024ull;
    // p_h (1 MB) reuses the p1 region: dead until k_oproj_v2 runs.
    float* p_h = p1;

    hipLaunchKernelGGL(k_f2bf, dim3(1024), dim3(256), 0, stream, relw1, w1rel, 663552);
    hipLaunchKernelGGL(k_f2bf, dim3(256),  dim3(256), 0, stream, ffw2, w2bf, 262144);
    hipLaunchKernelGGL(k_f2bf, dim3(96),   dim3(256), 0, stream, qkvw, qkvwb, 24576);
    hipLaunchKernelGGL(k_f2bf, dim3(256),  dim3(256), 0, stream, ow, owb, 65536);

    if (ws_size >= WS_NEED){
        hipLaunchKernelGGL(k_h_mfma, dim3(512), dim3(256), 0, stream, x, w1rel, p_h);
        hipLaunchKernelGGL(k_h_red,  dim3(256), dim3(256), 0, stream, p_h, h);
        hipLaunchKernelGGL(k_attn_mfma, dim3(2048), dim3(256), 0, stream, x, qkvwb, relw2, h, out);
        hipLaunchKernelGGL(k_oproj_v2, dim3(2048), dim3(256), 0, stream, x, owb, out, yT, p1);
        hipLaunchKernelGGL(k_red,      dim3(256),  dim3(256), 0, stream, p1, g1, b1, s1, t1);
        hipLaunchKernelGGL(k_w1scale,  dim3(1024), dim3(256), 0, stream, ffw1, s1, w1s);
        hipLaunchKernelGGL(k_bias1,    dim3(1024), dim3(64),  0, stream, ffw1, t1, bias1);
        hipLaunchKernelGGL(k_ff_v2,    dim3(2048), dim3(256), 0, stream, yT, w1s, w2bf, bias1, s1, t1, out, p2);
        hipLaunchKernelGGL(k_red,      dim3(256),  dim3(256), 0, stream, p2, g2, b2, s2, t2);
        hipLaunchKernelGGL(k_bnapply_st, dim3(2048), dim3(256), 0, stream, out, s2, t2, (unsigned int)NTOT);
    } else {
        hipLaunchKernelGGL(k_h, dim3(2048), dim3(256), 0, stream, x, w1rel, h);
        hipLaunchKernelGGL(k_attn_mfma, dim3(2048), dim3(256), 0, stream, x, qkvwb, relw2, h, out);
        hipLaunchKernelGGL(k_f2bf, dim3(256), dim3(256), 0, stream, ffw1, w1bf, 262144);
        hipLaunchKernelGGL(k_oproj_mfma, dim3(2048), dim3(256), 0, stream, x, owb, out);
        hipLaunchKernelGGL(k_stats, dim3(256), dim3(256), 0, stream, out, mean1, rstd1);
        hipLaunchKernelGGL(k_ff_mfma, dim3(2048), dim3(256), 0, stream, w1bf, w2bf, mean1, rstd1, g1, b1, out);
        hipLaunchKernelGGL(k_stats, dim3(256), dim3(256), 0, stream, out, mean2, rstd2);
        hipLaunchKernelGGL(k_bnapply, dim3(2048), dim3(256), 0, stream, out, mean2, rstd2, g2, b2, (unsigned int)NTOT);
    }
}

// Round 7
// 869.768 us; speedup vs baseline: 11.1056x; 1.1149x over previous
//
#include <hip/hip_runtime.h>
#include <math.h>

#define B_   2048
#define D_   256
#define H_   8
#define DEP_ 32
#define P_   81
#define FF_  1024
#define CHW  (D_*P_)      // 20736
#define NPOS (B_*P_)      // 165888
#define KREL (D_*P_)      // 20736
#define NTOT (B_*CHW)     // 42467328
#define EPS_ 1e-5f
#define YTP  264          // yT row pitch (halfs)
#define YTSZ (96*YTP)     // 25344 halfs per batch

typedef __attribute__((ext_vector_type(8))) short short8v;
typedef __attribute__((ext_vector_type(4))) short short4v;
typedef __attribute__((ext_vector_type(4))) float f32x4;

__device__ __forceinline__ float bf2f(unsigned short u){
    return __uint_as_float(((unsigned int)u) << 16);
}
__device__ __forceinline__ unsigned short f2bf(float f){
    unsigned int x = __float_as_uint(f);
    return (unsigned short)((x + 0x7FFFu + ((x >> 16) & 1u)) >> 16); // RNE
}
// fast erf-based GELU: A&S 7.1.26, |erf err| < 1.5e-7
__device__ __forceinline__ float fast_gelu(float x){
    float u = 0.70710678118654752f * x;
    float a = fabsf(u);
    float t = __builtin_amdgcn_rcpf(fmaf(0.3275911f, a, 1.f));
    float p = t * fmaf(t, fmaf(t, fmaf(t, fmaf(t, 1.061405429f, -1.453152027f),
                         1.421413741f), -0.284496736f), 0.254829592f);
    float e = __expf(-u * u);
    float er = copysignf(fmaf(-p, e, 1.f), u);
    return 0.5f * x * (1.f + er);
}
__device__ __forceinline__ float wave16_red(float v){
    v += __shfl_xor(v, 1); v += __shfl_xor(v, 2);
    v += __shfl_xor(v, 4); v += __shfl_xor(v, 8);
    return v;
}

// ---------------- generic f32 -> bf16 cast ----------------
__global__ __launch_bounds__(256) void k_f2bf(const float* __restrict__ w,
                                              unsigned short* __restrict__ o, int n){
    int i = blockIdx.x * 256 + threadIdx.x;
    int st = gridDim.x * 256;
    for (; i < n; i += st) o[i] = f2bf(w[i]);
}

// ---------------- OLD K0 (fallback): scalar h ----------------
__global__ __launch_bounds__(256) void k_h(const float* __restrict__ x,
                                           const unsigned short* __restrict__ w1b,
                                           float* __restrict__ h){
    const int b = blockIdx.x, t = threadIdx.x;
    const float* xb = x + (size_t)b * CHW;
    float acc[32];
    #pragma unroll
    for (int j = 0; j < 32; ++j) acc[j] = 0.f;
    for (int i4 = t * 4; i4 < CHW; i4 += 1024){
        const float4 xv = *(const float4*)(xb + i4);
        #pragma unroll 8
        for (int j = 0; j < 32; ++j){
            const uint2 wv = *(const uint2*)(w1b + (size_t)j * KREL + i4);
            float w0 = bf2f((unsigned short)(wv.x & 0xffffu));
            float w1 = bf2f((unsigned short)(wv.x >> 16));
            float w2 = bf2f((unsigned short)(wv.y & 0xffffu));
            float w3 = bf2f((unsigned short)(wv.y >> 16));
            acc[j] += xv.x * w0 + xv.y * w1 + xv.z * w2 + xv.w * w3;
        }
    }
    __shared__ float red[264 * 33];
    #pragma unroll
    for (int j = 0; j < 32; ++j) red[t * 33 + j] = acc[j];
    __syncthreads();
    {
        const int j = t & 31, g = t >> 5;
        float s = 0.f;
        for (int r = g * 32; r < g * 32 + 32; ++r) s += red[r * 33 + j];
        red[(256 + g) * 33 + j] = s;
    }
    __syncthreads();
    if (t < 32){
        float v = 0.f;
        #pragma unroll
        for (int g2 = 0; g2 < 8; ++g2) v += red[(256 + g2) * 33 + t];
        h[b * 32 + t] = v;
    }
}

// ---------------- NEW K0: MFMA h-partials ----------------
__global__ __launch_bounds__(256) void k_h_mfma(const float* __restrict__ x,
                                                const unsigned short* __restrict__ w1b,
                                                float* __restrict__ ph){
    const int bt = blockIdx.x >> 2, ks = blockIdx.x & 3;
    const int t = threadIdx.x, w = t >> 6, lane = t & 63;
    const int lr = lane & 15, lh = lane >> 4;
    const int b0 = bt * 16;
    f32x4 acc0 = {0.f,0.f,0.f,0.f}, acc1 = {0.f,0.f,0.f,0.f};
    const float* xrow = x + (size_t)(b0 + lr) * KREL;
    const unsigned short* wr0 = w1b + (size_t)lr * KREL;
    const unsigned short* wr1 = w1b + (size_t)(16 + lr) * KREL;
    for (int kk = w; kk < 162; kk += 4){
        const int k0 = (ks * 162 + kk) * 32 + lh * 8;
        short8v a0 = *(const short8v*)(wr0 + k0);
        short8v a1 = *(const short8v*)(wr1 + k0);
        const float4 xv0 = *(const float4*)(xrow + k0);
        const float4 xv1 = *(const float4*)(xrow + k0 + 4);
        short8v bb;
        bb[0] = (short)f2bf(xv0.x); bb[1] = (short)f2bf(xv0.y);
        bb[2] = (short)f2bf(xv0.z); bb[3] = (short)f2bf(xv0.w);
        bb[4] = (short)f2bf(xv1.x); bb[5] = (short)f2bf(xv1.y);
        bb[6] = (short)f2bf(xv1.z); bb[7] = (short)f2bf(xv1.w);
        acc0 = __builtin_amdgcn_mfma_f32_16x16x32_bf16(a0, bb, acc0, 0, 0, 0);
        acc1 = __builtin_amdgcn_mfma_f32_16x16x32_bf16(a1, bb, acc1, 0, 0, 0);
    }
    __shared__ float red[4][32][17];
    #pragma unroll
    for (int r = 0; r < 4; ++r){
        red[w][lh * 4 + r][lr]      = acc0[r];
        red[w][16 + lh * 4 + r][lr] = acc1[r];
    }
    __syncthreads();
    for (int i = t; i < 512; i += 256){
        int j = i >> 4, bb2 = i & 15;
        float s = red[0][j][bb2] + red[1][j][bb2] + red[2][j][bb2] + red[3][j][bb2];
        ph[(size_t)ks * 65536 + (size_t)(b0 + bb2) * 32 + j] = s;
    }
}

__global__ __launch_bounds__(256) void k_h_red(const float* __restrict__ ph,
                                               float* __restrict__ h){
    int i = blockIdx.x * 256 + threadIdx.x;   // 65536 outputs
    h[i] = ph[i] + ph[65536 + i] + ph[131072 + i] + ph[196608 + i];
}

// ---------------- FUSED K1: attention + o-proj + residual -> yT bf16 + BN1 partials ----------------
// Per batch, 4 waves; wave w handles heads w and w+4. PV outputs stay in registers;
// after one barrier the x1s region is rewritten in place as attT [96 p][264 c] bf16
// (pad rows still zero from phase A), then the validated oproj GEMM runs from LDS.
__global__ __launch_bounds__(256, 1) void k_attn_oproj(const float* __restrict__ x,
                                                       const unsigned short* __restrict__ qkvwb,
                                                       const float* __restrict__ relw2,
                                                       const float* __restrict__ h,
                                                       const unsigned short* __restrict__ owb,
                                                       unsigned short* __restrict__ yT,
                                                       float* __restrict__ p1){
    const int b = blockIdx.x, t = threadIdx.x;
    const int lane = t & 63, w = t >> 6;
    const int lr = lane & 15, lh = lane >> 4;

    __shared__ __align__(16) unsigned short x1s[96 * 264];   // x^T bf16 [p][c]; later attT
    __shared__ __align__(16) unsigned short Rl[96 * 40];     // R [pk][d]
    __shared__ __align__(16) unsigned short qL[4][96 * 40];
    __shared__ __align__(16) unsigned short krL[4][96 * 40];
    __shared__ __align__(16) unsigned short vL[4][32 * 104];
    __shared__ __align__(16) unsigned short pL[4][16 * 104];

    const float* xb = x + (size_t)b * CHW;

    // ---- R = relw2 @ h_b -> Rl
    {
        const float* hb = h + b * 32;
        float hreg[32];
        #pragma unroll
        for (int j = 0; j < 32; ++j) hreg[j] = hb[j];
        for (int idx = t; idx < 2592; idx += 256){
            int d = idx / 81, p = idx - d * 81;
            const float4* wr = (const float4*)(relw2 + (size_t)idx * 32);
            float s = 0.f;
            #pragma unroll
            for (int j = 0; j < 8; ++j){
                float4 wv = wr[j];
                s += wv.x * hreg[4*j] + wv.y * hreg[4*j+1] + wv.z * hreg[4*j+2] + wv.w * hreg[4*j+3];
            }
            Rl[p * 40 + d] = f2bf(s);
        }
        for (int idx = t; idx < 15 * 32; idx += 256){
            int p = 81 + (idx >> 5), d = idx & 31;
            Rl[p * 40 + d] = 0;
        }
    }
    // ---- zero x1s pad rows
    for (int idx = t; idx < 15 * 132; idx += 256){
        int r = idx / 132, c = idx - r * 132;
        *(unsigned int*)&x1s[(81 + r) * 264 + 2 * c] = 0;
    }
    // ---- stage x^T -> x1s bf16
    {
        float* tb = (float*)qL;
        for (int cc = 0; cc < 4; ++cc){
            for (int idx = t; idx < 64 * 81; idx += 256){
                int c = idx / 81, p = idx - c * 81;
                tb[c * 85 + p] = xb[(cc * 64 + c) * 81 + p];
            }
            __syncthreads();
            for (int idx = t; idx < 32 * 81; idx += 256){
                int c2 = idx & 31, p = idx >> 5;
                int c = 2 * c2;
                unsigned int pk = (unsigned int)f2bf(tb[c * 85 + p])
                                | ((unsigned int)f2bf(tb[(c + 1) * 85 + p]) << 16);
                *(unsigned int*)&x1s[p * 264 + cc * 64 + c] = pk;
            }
            __syncthreads();
        }
    }

    unsigned short* q_  = qL[w];
    unsigned short* kr_ = krL[w];
    unsigned short* v_  = vL[w];
    unsigned short* p_  = pL[w];

    f32x4 oA[2][6], oB[2][6];   // PV outputs, both heads, kept in registers

    #pragma unroll
    for (int hi = 0; hi < 2; ++hi){
        const int hh = w + hi * 4;
        const int qrow = hh * 32, krow = 256 + hh * 32, vrow = 512 + hh * 32;
        const int gq = (qrow / 96) * 32, gk = (krow / 96) * 32, gv = (vrow / 96) * 32;

        {
            short8v a0 = *(const short8v*)(qkvwb + (size_t)(qrow + lr) * 32 + lh * 8);
            short8v a1 = *(const short8v*)(qkvwb + (size_t)(qrow + 16 + lr) * 32 + lh * 8);
            #pragma unroll
            for (int nt = 0; nt < 6; ++nt){
                short8v bb = *(const short8v*)(x1s + (nt * 16 + lr) * 264 + gq + lh * 8);
                f32x4 c0 = {0.f,0.f,0.f,0.f}, c1 = {0.f,0.f,0.f,0.f};
                c0 = __builtin_amdgcn_mfma_f32_16x16x32_bf16(a0, bb, c0, 0, 0, 0);
                c1 = __builtin_amdgcn_mfma_f32_16x16x32_bf16(a1, bb, c1, 0, 0, 0);
                int p = nt * 16 + lr;
                short4v p0, p1;
                #pragma unroll
                for (int r = 0; r < 4; ++r){ p0[r] = (short)f2bf(c0[r]); p1[r] = (short)f2bf(c1[r]); }
                *(short4v*)(q_ + p * 40 + lh * 4)      = p0;
                *(short4v*)(q_ + p * 40 + 16 + lh * 4) = p1;
            }
        }
        {
            short8v a0 = *(const short8v*)(qkvwb + (size_t)(krow + lr) * 32 + lh * 8);
            short8v a1 = *(const short8v*)(qkvwb + (size_t)(krow + 16 + lr) * 32 + lh * 8);
            #pragma unroll
            for (int nt = 0; nt < 6; ++nt){
                int p = nt * 16 + lr;
                short4v r0 = *(const short4v*)(Rl + p * 40 + lh * 4);
                short4v r1 = *(const short4v*)(Rl + p * 40 + 16 + lh * 4);
                f32x4 c0, c1;
                #pragma unroll
                for (int r = 0; r < 4; ++r){
                    c0[r] = bf2f((unsigned short)r0[r]);
                    c1[r] = bf2f((unsigned short)r1[r]);
                }
                short8v bb = *(const short8v*)(x1s + p * 264 + gk + lh * 8);
                c0 = __builtin_amdgcn_mfma_f32_16x16x32_bf16(a0, bb, c0, 0, 0, 0);
                c1 = __builtin_amdgcn_mfma_f32_16x16x32_bf16(a1, bb, c1, 0, 0, 0);
                short4v p0, p1;
                #pragma unroll
                for (int r = 0; r < 4; ++r){ p0[r] = (short)f2bf(c0[r]); p1[r] = (short)f2bf(c1[r]); }
                *(short4v*)(kr_ + p * 40 + lh * 4)      = p0;
                *(short4v*)(kr_ + p * 40 + 16 + lh * 4) = p1;
            }
        }
        {
            short8v a0 = *(const short8v*)(qkvwb + (size_t)(vrow + lr) * 32 + lh * 8);
            short8v a1 = *(const short8v*)(qkvwb + (size_t)(vrow + 16 + lr) * 32 + lh * 8);
            #pragma unroll
            for (int nt = 0; nt < 6; ++nt){
                short8v bb = *(const short8v*)(x1s + (nt * 16 + lr) * 264 + gv + lh * 8);
                f32x4 c0 = {0.f,0.f,0.f,0.f}, c1 = {0.f,0.f,0.f,0.f};
                c0 = __builtin_amdgcn_mfma_f32_16x16x32_bf16(a0, bb, c0, 0, 0, 0);
                c1 = __builtin_amdgcn_mfma_f32_16x16x32_bf16(a1, bb, c1, 0, 0, 0);
                int pk = nt * 16 + lr;
                #pragma unroll
                for (int r = 0; r < 4; ++r){
                    v_[(lh * 4 + r) * 104 + pk]        = f2bf(c0[r]);
                    v_[(16 + lh * 4 + r) * 104 + pk]   = f2bf(c1[r]);
                }
            }
        }
        #pragma unroll
        for (int nt = 0; nt < 6; ++nt){
            short8v bq = *(const short8v*)(q_ + (nt * 16 + lr) * 40 + lh * 8);
            f32x4 sc[6];
            #pragma unroll
            for (int mt = 0; mt < 6; ++mt){
                short8v ak = *(const short8v*)(kr_ + (mt * 16 + lr) * 40 + lh * 8);
                f32x4 z = {0.f,0.f,0.f,0.f};
                sc[mt] = __builtin_amdgcn_mfma_f32_16x16x32_bf16(ak, bq, z, 0, 0, 0);
            }
            sc[5][0] = (lh == 0) ? sc[5][0] : -1e30f;
            sc[5][1] = -1e30f; sc[5][2] = -1e30f; sc[5][3] = -1e30f;
            float mx = -1e30f;
            #pragma unroll
            for (int mt = 0; mt < 6; ++mt)
            #pragma unroll
            for (int r = 0; r < 4; ++r) mx = fmaxf(mx, sc[mt][r]);
            mx = fmaxf(mx, __shfl_xor(mx, 16));
            mx = fmaxf(mx, __shfl_xor(mx, 32));
            const float scl = 0.17677669529663687f;
            float sum = 0.f;
            #pragma unroll
            for (int mt = 0; mt < 6; ++mt)
            #pragma unroll
            for (int r = 0; r < 4; ++r){
                float e = __expf((sc[mt][r] - mx) * scl);
                sc[mt][r] = e; sum += e;
            }
            sum += __shfl_xor(sum, 16);
            sum += __shfl_xor(sum, 32);
            float inv = 1.f / sum;
            #pragma unroll
            for (int mt = 0; mt < 6; ++mt){
                short4v pv;
                #pragma unroll
                for (int r = 0; r < 4; ++r) pv[r] = (short)f2bf(sc[mt][r] * inv);
                *(short4v*)(p_ + lr * 104 + mt * 16 + lh * 4) = pv;
            }
            f32x4 o0 = {0.f,0.f,0.f,0.f}, o1 = {0.f,0.f,0.f,0.f};
            #pragma unroll
            for (int ks = 0; ks < 3; ++ks){
                short8v ap  = *(const short8v*)(p_ + lr * 104 + ks * 32 + lh * 8);
                short8v bv0 = *(const short8v*)(v_ + lr * 104 + ks * 32 + lh * 8);
                short8v bv1 = *(const short8v*)(v_ + (16 + lr) * 104 + ks * 32 + lh * 8);
                o0 = __builtin_amdgcn_mfma_f32_16x16x32_bf16(ap, bv0, o0, 0, 0, 0);
                o1 = __builtin_amdgcn_mfma_f32_16x16x32_bf16(ap, bv1, o1, 0, 0, 0);
            }
            oA[hi][nt] = o0;
            oB[hi][nt] = o1;
        }
    }

    // ---- all x1s reads done; rewrite x1s region as attT [p][chan] bf16
    __syncthreads();
    #pragma unroll
    for (int hi = 0; hi < 2; ++hi){
        const int hh = w + hi * 4;
        #pragma unroll
        for (int nt = 0; nt < 6; ++nt){
            #pragma unroll
            for (int r = 0; r < 4; ++r){
                int pq = nt * 16 + lh * 4 + r;
                if (pq < 81){
                    x1s[pq * 264 + hh * 32 + lr]      = f2bf(oA[hi][nt][r]);
                    x1s[pq * 264 + hh * 32 + 16 + lr] = f2bf(oB[hi][nt][r]);
                }
            }
        }
    }
    __syncthreads();

    // ---- o-proj GEMM from attT (=x1s) + residual -> yT + BN1 partials
    const int cw = w * 64;
    f32x4 acc[4][6];
    #pragma unroll
    for (int ci = 0; ci < 4; ++ci)
    #pragma unroll
    for (int pj = 0; pj < 6; ++pj)
        acc[ci][pj] = (f32x4){0.f, 0.f, 0.f, 0.f};

    for (int ks = 0; ks < 8; ++ks){
        const int k0 = ks * 32 + lh * 8;
        short8v a[4];
        #pragma unroll
        for (int ci = 0; ci < 4; ++ci)
            a[ci] = *(const short8v*)(owb + (size_t)(cw + ci * 16 + lr) * 256 + k0);
        #pragma unroll
        for (int pj = 0; pj < 6; ++pj){
            short8v bb = *(const short8v*)(x1s + (pj * 16 + lr) * 264 + k0);
            #pragma unroll
            for (int ci = 0; ci < 4; ++ci)
                acc[ci][pj] = __builtin_amdgcn_mfma_f32_16x16x32_bf16(a[ci], bb, acc[ci][pj], 0, 0, 0);
        }
    }
    unsigned short* yb = yT + (size_t)b * YTSZ;
    float cs[16], cq[16];
    #pragma unroll
    for (int i = 0; i < 16; ++i){ cs[i] = 0.f; cq[i] = 0.f; }
    #pragma unroll
    for (int ci = 0; ci < 4; ++ci)
    #pragma unroll
    for (int pj = 0; pj < 6; ++pj){
        int p = pj * 16 + lr;
        int c = cw + ci * 16 + lh * 4;
        short4v pk;
        if (p < 81){
            #pragma unroll
            for (int r = 0; r < 4; ++r){
                float y = acc[ci][pj][r] + xb[(c + r) * 81 + p];
                pk[r] = (short)f2bf(y);
                cs[ci * 4 + r] += y;
                cq[ci * 4 + r] += y * y;
            }
        } else {
            #pragma unroll
            for (int r = 0; r < 4; ++r) pk[r] = 0;
        }
        *(short4v*)(yb + p * YTP + c) = pk;
    }
    #pragma unroll
    for (int i = 0; i < 16; ++i){
        cs[i] = wave16_red(cs[i]);
        cq[i] = wave16_red(cq[i]);
    }
    if (lr == 0){
        #pragma unroll
        for (int ci = 0; ci < 4; ++ci)
        #pragma unroll
        for (int r = 0; r < 4; ++r){
            int c = cw + ci * 16 + lh * 4 + r;
            p1[(size_t)c * 2048 + b]         = cs[ci * 4 + r];
            p1[(size_t)(256 + c) * 2048 + b] = cq[ci * 4 + r];
        }
    }
}

// ---------------- OLD K1 (fallback): attention -> att ----------------
__global__ __launch_bounds__(256, 1) void k_attn_mfma(const float* __restrict__ x,
                                                      const unsigned short* __restrict__ qkvwb,
                                                      const float* __restrict__ relw2,
                                                      const float* __restrict__ h,
                                                      float* __restrict__ att){
    const int b = blockIdx.x, t = threadIdx.x;
    const int lane = t & 63, w = t >> 6;
    const int lr = lane & 15, lh = lane >> 4;

    __shared__ __align__(16) unsigned short x1s[96 * 264];
    __shared__ __align__(16) unsigned short Rl[96 * 40];
    __shared__ __align__(16) unsigned short qL[4][96 * 40];
    __shared__ __align__(16) unsigned short krL[4][96 * 40];
    __shared__ __align__(16) unsigned short vL[4][32 * 104];
    __shared__ __align__(16) unsigned short pL[4][16 * 104];

    const float* xb = x + (size_t)b * CHW;

    {
        const float* hb = h + b * 32;
        float hreg[32];
        #pragma unroll
        for (int j = 0; j < 32; ++j) hreg[j] = hb[j];
        for (int idx = t; idx < 2592; idx += 256){
            int d = idx / 81, p = idx - d * 81;
            const float4* wr = (const float4*)(relw2 + (size_t)idx * 32);
            float s = 0.f;
            #pragma unroll
            for (int j = 0; j < 8; ++j){
                float4 wv = wr[j];
                s += wv.x * hreg[4*j] + wv.y * hreg[4*j+1] + wv.z * hreg[4*j+2] + wv.w * hreg[4*j+3];
            }
            Rl[p * 40 + d] = f2bf(s);
        }
        for (int idx = t; idx < 15 * 32; idx += 256){
            int p = 81 + (idx >> 5), d = idx & 31;
            Rl[p * 40 + d] = 0;
        }
    }
    for (int idx = t; idx < 15 * 132; idx += 256){
        int r = idx / 132, c = idx - r * 132;
        *(unsigned int*)&x1s[(81 + r) * 264 + 2 * c] = 0;
    }
    {
        float* tb = (float*)qL;
        for (int cc = 0; cc < 4; ++cc){
            for (int idx = t; idx < 64 * 81; idx += 256){
                int c = idx / 81, p = idx - c * 81;
                tb[c * 85 + p] = xb[(cc * 64 + c) * 81 + p];
            }
            __syncthreads();
            for (int idx = t; idx < 32 * 81; idx += 256){
                int c2 = idx & 31, p = idx >> 5;
                int c = 2 * c2;
                unsigned int pk = (unsigned int)f2bf(tb[c * 85 + p])
                                | ((unsigned int)f2bf(tb[(c + 1) * 85 + p]) << 16);
                *(unsigned int*)&x1s[p * 264 + cc * 64 + c] = pk;
            }
            __syncthreads();
        }
    }

    unsigned short* q_  = qL[w];
    unsigned short* kr_ = krL[w];
    unsigned short* v_  = vL[w];
    unsigned short* p_  = pL[w];

    for (int hi = 0; hi < 2; ++hi){
        const int hh = w + hi * 4;
        const int qrow = hh * 32, krow = 256 + hh * 32, vrow = 512 + hh * 32;
        const int gq = (qrow / 96) * 32, gk = (krow / 96) * 32, gv = (vrow / 96) * 32;

        {
            short8v a0 = *(const short8v*)(qkvwb + (size_t)(qrow + lr) * 32 + lh * 8);
            short8v a1 = *(const short8v*)(qkvwb + (size_t)(qrow + 16 + lr) * 32 + lh * 8);
            #pragma unroll
            for (int nt = 0; nt < 6; ++nt){
                short8v bb = *(const short8v*)(x1s + (nt * 16 + lr) * 264 + gq + lh * 8);
                f32x4 c0 = {0.f,0.f,0.f,0.f}, c1 = {0.f,0.f,0.f,0.f};
                c0 = __builtin_amdgcn_mfma_f32_16x16x32_bf16(a0, bb, c0, 0, 0, 0);
                c1 = __builtin_amdgcn_mfma_f32_16x16x32_bf16(a1, bb, c1, 0, 0, 0);
                int p = nt * 16 + lr;
                short4v p0, p1;
                #pragma unroll
                for (int r = 0; r < 4; ++r){ p0[r] = (short)f2bf(c0[r]); p1[r] = (short)f2bf(c1[r]); }
                *(short4v*)(q_ + p * 40 + lh * 4)      = p0;
                *(short4v*)(q_ + p * 40 + 16 + lh * 4) = p1;
            }
        }
        {
            short8v a0 = *(const short8v*)(qkvwb + (size_t)(krow + lr) * 32 + lh * 8);
            short8v a1 = *(const short8v*)(qkvwb + (size_t)(krow + 16 + lr) * 32 + lh * 8);
            #pragma unroll
            for (int nt = 0; nt < 6; ++nt){
                int p = nt * 16 + lr;
                short4v r0 = *(const short4v*)(Rl + p * 40 + lh * 4);
                short4v r1 = *(const short4v*)(Rl + p * 40 + 16 + lh * 4);
                f32x4 c0, c1;
                #pragma unroll
                for (int r = 0; r < 4; ++r){
                    c0[r] = bf2f((unsigned short)r0[r]);
                    c1[r] = bf2f((unsigned short)r1[r]);
                }
                short8v bb = *(const short8v*)(x1s + p * 264 + gk + lh * 8);
                c0 = __builtin_amdgcn_mfma_f32_16x16x32_bf16(a0, bb, c0, 0, 0, 0);
                c1 = __builtin_amdgcn_mfma_f32_16x16x32_bf16(a1, bb, c1, 0, 0, 0);
                short4v p0, p1;
                #pragma unroll
                for (int r = 0; r < 4; ++r){ p0[r] = (short)f2bf(c0[r]); p1[r] = (short)f2bf(c1[r]); }
                *(short4v*)(kr_ + p * 40 + lh * 4)      = p0;
                *(short4v*)(kr_ + p * 40 + 16 + lh * 4) = p1;
            }
        }
        {
            short8v a0 = *(const short8v*)(qkvwb + (size_t)(vrow + lr) * 32 + lh * 8);
            short8v a1 = *(const short8v*)(qkvwb + (size_t)(vrow + 16 + lr) * 32 + lh * 8);
            #pragma unroll
            for (int nt = 0; nt < 6; ++nt){
                short8v bb = *(const short8v*)(x1s + (nt * 16 + lr) * 264 + gv + lh * 8);
                f32x4 c0 = {0.f,0.f,0.f,0.f}, c1 = {0.f,0.f,0.f,0.f};
                c0 = __builtin_amdgcn_mfma_f32_16x16x32_bf16(a0, bb, c0, 0, 0, 0);
                c1 = __builtin_amdgcn_mfma_f32_16x16x32_bf16(a1, bb, c1, 0, 0, 0);
                int pk = nt * 16 + lr;
                #pragma unroll
                for (int r = 0; r < 4; ++r){
                    v_[(lh * 4 + r) * 104 + pk]        = f2bf(c0[r]);
                    v_[(16 + lh * 4 + r) * 104 + pk]   = f2bf(c1[r]);
                }
            }
        }
        float* ob = att + (size_t)b * CHW + (size_t)(hh * 32) * 81;
        for (int nt = 0; nt < 6; ++nt){
            short8v bq = *(const short8v*)(q_ + (nt * 16 + lr) * 40 + lh * 8);
            f32x4 sc[6];
            #pragma unroll
            for (int mt = 0; mt < 6; ++mt){
                short8v ak = *(const short8v*)(kr_ + (mt * 16 + lr) * 40 + lh * 8);
                f32x4 z = {0.f,0.f,0.f,0.f};
                sc[mt] = __builtin_amdgcn_mfma_f32_16x16x32_bf16(ak, bq, z, 0, 0, 0);
            }
            sc[5][0] = (lh == 0) ? sc[5][0] : -1e30f;
            sc[5][1] = -1e30f; sc[5][2] = -1e30f; sc[5][3] = -1e30f;
            float mx = -1e30f;
            #pragma unroll
            for (int mt = 0; mt < 6; ++mt)
            #pragma unroll
            for (int r = 0; r < 4; ++r) mx = fmaxf(mx, sc[mt][r]);
            mx = fmaxf(mx, __shfl_xor(mx, 16));
            mx = fmaxf(mx, __shfl_xor(mx, 32));
            const float scl = 0.17677669529663687f;
            float sum = 0.f;
            #pragma unroll
            for (int mt = 0; mt < 6; ++mt)
            #pragma unroll
            for (int r = 0; r < 4; ++r){
                float e = __expf((sc[mt][r] - mx) * scl);
                sc[mt][r] = e; sum += e;
            }
            sum += __shfl_xor(sum, 16);
            sum += __shfl_xor(sum, 32);
            float inv = 1.f / sum;
            #pragma unroll
            for (int mt = 0; mt < 6; ++mt){
                short4v pv;
                #pragma unroll
                for (int r = 0; r < 4; ++r) pv[r] = (short)f2bf(sc[mt][r] * inv);
                *(short4v*)(p_ + lr * 104 + mt * 16 + lh * 4) = pv;
            }
            f32x4 o0 = {0.f,0.f,0.f,0.f}, o1 = {0.f,0.f,0.f,0.f};
            #pragma unroll
            for (int ks = 0; ks < 3; ++ks){
                short8v ap  = *(const short8v*)(p_ + lr * 104 + ks * 32 + lh * 8);
                short8v bv0 = *(const short8v*)(v_ + lr * 104 + ks * 32 + lh * 8);
                short8v bv1 = *(const short8v*)(v_ + (16 + lr) * 104 + ks * 32 + lh * 8);
                o0 = __builtin_amdgcn_mfma_f32_16x16x32_bf16(ap, bv0, o0, 0, 0, 0);
                o1 = __builtin_amdgcn_mfma_f32_16x16x32_bf16(ap, bv1, o1, 0, 0, 0);
            }
            int pq0 = nt * 16 + lh * 4;
            #pragma unroll
            for (int r = 0; r < 4; ++r){
                int pq = pq0 + r;
                if (pq < 81){
                    ob[lr * 81 + pq]        = o0[r];
                    ob[(16 + lr) * 81 + pq] = o1[r];
                }
            }
        }
    }
}

// ---------------- OLD K1b (fallback): y = o_w @ att + x in-place ----------------
__global__ __launch_bounds__(256, 2) void k_oproj_mfma(const float* __restrict__ x,
                                                       const unsigned short* __restrict__ owb,
                                                       float* __restrict__ yz){
    const int b = blockIdx.x, t = threadIdx.x;
    const int lane = t & 63, w = t >> 6;
    const int lr = lane & 15, lh = lane >> 4;
    float* zb = yz + (size_t)b * CHW;

    __shared__ __align__(16) unsigned short attT[96 * 264];
    __shared__ __align__(16) float tb[64 * 85];

    for (int idx = t; idx < 15 * 132; idx += 256){
        int r = idx / 132, c = idx - r * 132;
        *(unsigned int*)&attT[(81 + r) * 264 + 2 * c] = 0;
    }
    for (int cc = 0; cc < 4; ++cc){
        for (int idx = t; idx < 64 * 81; idx += 256){
            int c = idx / 81, p = idx - c * 81;
            tb[c * 85 + p] = zb[(cc * 64 + c) * 81 + p];
        }
        __syncthreads();
        for (int idx = t; idx < 32 * 81; idx += 256){
            int c2 = idx & 31, p = idx >> 5;
            int c = 2 * c2;
            unsigned int pk = (unsigned int)f2bf(tb[c * 85 + p])
                            | ((unsigned int)f2bf(tb[(c + 1) * 85 + p]) << 16);
            *(unsigned int*)&attT[p * 264 + cc * 64 + c] = pk;
        }
        __syncthreads();
    }

    const int cw = w * 64;
    f32x4 acc[4][6];
    #pragma unroll
    for (int ci = 0; ci < 4; ++ci)
    #pragma unroll
    for (int pj = 0; pj < 6; ++pj)
        acc[ci][pj] = (f32x4){0.f, 0.f, 0.f, 0.f};

    for (int ks = 0; ks < 8; ++ks){
        const int k0 = ks * 32 + lh * 8;
        short8v a[4];
        #pragma unroll
        for (int ci = 0; ci < 4; ++ci)
            a[ci] = *(const short8v*)(owb + (size_t)(cw + ci * 16 + lr) * 256 + k0);
        #pragma unroll
        for (int pj = 0; pj < 6; ++pj){
            short8v bb = *(const short8v*)(attT + (pj * 16 + lr) * 264 + k0);
            #pragma unroll
            for (int ci = 0; ci < 4; ++ci)
                acc[ci][pj] = __builtin_amdgcn_mfma_f32_16x16x32_bf16(a[ci], bb, acc[ci][pj], 0, 0, 0);
        }
    }
    const float* xb = x + (size_t)b * CHW;
    #pragma unroll
    for (int ci = 0; ci < 4; ++ci)
    #pragma unroll
    for (int pj = 0; pj < 6; ++pj){
        int p = pj * 16 + lr;
        if (p < 81){
            int c = cw + ci * 16 + lh * 4;
            #pragma unroll
            for (int r = 0; r < 4; ++r)
                zb[(c + r) * 81 + p] = acc[ci][pj][r] + xb[(c + r) * 81 + p];
        }
    }
}

// ---------------- OLD stats (fallback) ----------------
__global__ __launch_bounds__(256) void k_stats(const float* __restrict__ buf,
                                               float* __restrict__ mean, float* __restrict__ rstd){
    const int c = blockIdx.x, t = threadIdx.x;
    float s = 0.f, q = 0.f;
    for (int idx = t; idx < NPOS; idx += 256){
        int b = idx / 81, p = idx - b * 81;
        float v = buf[(size_t)b * CHW + c * 81 + p];
        s += v; q += v * v;
    }
    __shared__ float rs[256], rq[256];
    rs[t] = s; rq[t] = q;
    __syncthreads();
    for (int k = 128; k; k >>= 1){
        if (t < k){ rs[t] += rs[t + k]; rq[t] += rq[t + k]; }
        __syncthreads();
    }
    if (t == 0){
        float m = rs[0] / (float)NPOS;
        float var = rq[0] / (float)NPOS - m * m;
        mean[c] = m;
        rstd[c] = rsqrtf(var + EPS_);
    }
}

// ---------------- reduce partials -> (s,t) affine BN params ----------------
__global__ __launch_bounds__(256) void k_red(const float* __restrict__ part,
                                             const float* __restrict__ g, const float* __restrict__ bia,
                                             float* __restrict__ sOut, float* __restrict__ tOut){
    const int c = blockIdx.x, t = threadIdx.x;
    float s = 0.f, q = 0.f;
    #pragma unroll
    for (int i = 0; i < 8; ++i){
        s += part[(size_t)c * 2048 + t + i * 256];
        q += part[(size_t)(256 + c) * 2048 + t + i * 256];
    }
    __shared__ float rs[256], rq[256];
    rs[t] = s; rq[t] = q;
    __syncthreads();
    for (int k = 128; k; k >>= 1){
        if (t < k){ rs[t] += rs[t + k]; rq[t] += rq[t + k]; }
        __syncthreads();
    }
    if (t == 0){
        float m = rs[0] / (float)NPOS;
        float var = rq[0] / (float)NPOS - m * m;
        float sc = g[c] * rsqrtf(var + EPS_);
        sOut[c] = sc;
        tOut[c] = bia[c] - m * sc;
    }
}

// ---------------- w1s[f][c] = bf16(w1[f][c]*s1[c]) ----------------
__global__ __launch_bounds__(256) void k_w1scale(const float* __restrict__ w1,
                                                 const float* __restrict__ s1,
                                                 unsigned short* __restrict__ w1s){
    const int f = blockIdx.x, t = threadIdx.x;
    w1s[f * 256 + t] = f2bf(w1[f * 256 + t] * s1[t]);
}

// ---------------- bias1[f] = sum_c w1[f][c]*t1[c] ----------------
__global__ __launch_bounds__(64) void k_bias1(const float* __restrict__ w1,
                                              const float* __restrict__ t1,
                                              float* __restrict__ bias1){
    const int f = blockIdx.x, t = threadIdx.x;
    const float4 wv = *(const float4*)(w1 + f * 256 + t * 4);
    const float4 tv = *(const float4*)(t1 + t * 4);
    float s = wv.x * tv.x + wv.y * tv.y + wv.z * tv.z + wv.w * tv.w;
    #pragma unroll
    for (int m = 1; m < 64; m <<= 1) s += __shfl_xor(s, m);
    if (t == 0) bias1[f] = s;
}

// ---------------- OLD K3 (fallback) ----------------
__global__ __launch_bounds__(256, 2) void k_ff_mfma(const unsigned short* __restrict__ w1bf,
                                                    const unsigned short* __restrict__ w2bf,
                                                    const float* __restrict__ mean1, const float* __restrict__ rstd1,
                                                    const float* __restrict__ g1, const float* __restrict__ b1,
                                                    float* __restrict__ yz){
    const int b = blockIdx.x, t = threadIdx.x;
    const int lane = t & 63, w = t >> 6;
    const int lr = lane & 15, lh = lane >> 4;
    float* zb = yz + (size_t)b * CHW;

    __shared__ __align__(16) unsigned short x1s[96 * 264];
    __shared__ __align__(16) unsigned char ubuf[26112];
    unsigned short* ffs = (unsigned short*)ubuf;
    float* tb = (float*)ubuf;

    for (int idx = t; idx < 15 * 132; idx += 256){
        int r = idx / 132, c = idx - r * 132;
        *(unsigned int*)&x1s[(81 + r) * 264 + 2 * c] = 0;
    }
    for (int cc = 0; cc < 4; ++cc){
        for (int idx = t; idx < 64 * 81; idx += 256){
            int c = idx / 81, p = idx - c * 81;
            int gc = cc * 64 + c;
            float v = zb[gc * 81 + p];
            v = (v - mean1[gc]) * rstd1[gc] * g1[gc] + b1[gc];
            tb[c * 85 + p] = v;
        }
        __syncthreads();
        for (int idx = t; idx < 32 * 81; idx += 256){
            int c2 = idx & 31, p = idx >> 5;
            int c = 2 * c2;
            unsigned int pk = (unsigned int)f2bf(tb[c * 85 + p])
                            | ((unsigned int)f2bf(tb[(c + 1) * 85 + p]) << 16);
            *(unsigned int*)&x1s[p * 264 + cc * 64 + c] = pk;
        }
        __syncthreads();
    }

    const int cw = w * 64;
    f32x4 acc2[4][6];
    #pragma unroll
    for (int ci = 0; ci < 4; ++ci)
    #pragma unroll
    for (int pj = 0; pj < 6; ++pj)
        acc2[ci][pj] = (f32x4){0.f, 0.f, 0.f, 0.f};

    for (int fc = 0; fc < 8; ++fc){
        f32x4 acc1[2][6];
        #pragma unroll
        for (int fi = 0; fi < 2; ++fi)
        #pragma unroll
        for (int pj = 0; pj < 6; ++pj)
            acc1[fi][pj] = (f32x4){0.f, 0.f, 0.f, 0.f};
        const int fbase = fc * 128 + w * 32;
        for (int ks = 0; ks < 8; ++ks){
            const int k0 = ks * 32 + lh * 8;
            short8v a0 = *(const short8v*)(w1bf + (size_t)(fbase + lr) * 256 + k0);
            short8v a1 = *(const short8v*)(w1bf + (size_t)(fbase + 16 + lr) * 256 + k0);
            #pragma unroll
            for (int pj = 0; pj < 6; ++pj){
                short8v bb = *(const short8v*)(x1s + (pj * 16 + lr) * 264 + k0);
                acc1[0][pj] = __builtin_amdgcn_mfma_f32_16x16x32_bf16(a0, bb, acc1[0][pj], 0, 0, 0);
                acc1[1][pj] = __builtin_amdgcn_mfma_f32_16x16x32_bf16(a1, bb, acc1[1][pj], 0, 0, 0);
            }
        }
        #pragma unroll
        for (int fi = 0; fi < 2; ++fi)
        #pragma unroll
        for (int pj = 0; pj < 6; ++pj){
            int p = pj * 16 + lr;
            int fl = w * 32 + fi * 16 + lh * 4;
            short4v pk;
            #pragma unroll
            for (int r = 0; r < 4; ++r){
                float v = acc1[fi][pj][r];
                v = 0.5f * v * (1.f + erff(v * 0.70710678118654752f));
                pk[r] = (short)f2bf(v);
            }
            *(short4v*)&ffs[p * 136 + fl] = pk;
        }
        __syncthreads();
        for (int ks = 0; ks < 4; ++ks){
            const int k0 = ks * 32 + lh * 8;
            short8v a2[4];
            #pragma unroll
            for (int ci = 0; ci < 4; ++ci)
                a2[ci] = *(const short8v*)(w2bf + (size_t)(cw + ci * 16 + lr) * 1024 + fc * 128 + k0);
            #pragma unroll
            for (int pj = 0; pj < 6; ++pj){
                short8v bb = *(const short8v*)(ffs + (pj * 16 + lr) * 136 + k0);
                #pragma unroll
                for (int ci = 0; ci < 4; ++ci)
                    acc2[ci][pj] = __builtin_amdgcn_mfma_f32_16x16x32_bf16(a2[ci], bb, acc2[ci][pj], 0, 0, 0);
            }
        }
        __syncthreads();
    }
    #pragma unroll
    for (int ci = 0; ci < 4; ++ci)
    #pragma unroll
    for (int pj = 0; pj < 6; ++pj){
        int p = pj * 16 + lr;
        if (p < 81){
            int c = cw + ci * 16 + lh * 4;
            short4v res = *(const short4v*)&x1s[p * 264 + c];
            #pragma unroll
            for (int r = 0; r < 4; ++r)
                zb[(c + r) * 81 + p] = acc2[ci][pj][r] + bf2f((unsigned short)res[r]);
        }
    }
}

// ---------------- NEW K3: FF from yT, BN folded, fast gelu, BN2 partials ----------------
__global__ __launch_bounds__(256, 2) void k_ff_v2(const unsigned short* __restrict__ yT,
                                                  const unsigned short* __restrict__ w1s,
                                                  const unsigned short* __restrict__ w2bf,
                                                  const float* __restrict__ bias1,
                                                  const float* __restrict__ s1, const float* __restrict__ t1,
                                                  float* __restrict__ yz,
                                                  float* __restrict__ p2){
    const int b = blockIdx.x, t = threadIdx.x;
    const int lane = t & 63, w = t >> 6;
    const int lr = lane & 15, lh = lane >> 4;
    float* zb = yz + (size_t)b * CHW;

    __shared__ __align__(16) unsigned short x1s[96 * 264];   // raw y bf16 [p][c]
    __shared__ __align__(16) unsigned short ffs[96 * 136];

    {
        const short8v* src = (const short8v*)(yT + (size_t)b * YTSZ);
        short8v* dst = (short8v*)x1s;
        for (int idx = t; idx < 3168; idx += 256) dst[idx] = src[idx];
    }
    __syncthreads();

    const int cw = w * 64;
    f32x4 acc2[4][6];
    #pragma unroll
    for (int ci = 0; ci < 4; ++ci)
    #pragma unroll
    for (int pj = 0; pj < 6; ++pj)
        acc2[ci][pj] = (f32x4){0.f, 0.f, 0.f, 0.f};

    for (int fc = 0; fc < 8; ++fc){
        const int fbase = fc * 128 + w * 32;
        float b4[2][4];
        #pragma unroll
        for (int fi = 0; fi < 2; ++fi)
        #pragma unroll
        for (int r = 0; r < 4; ++r)
            b4[fi][r] = bias1[fbase + fi * 16 + lh * 4 + r];
        f32x4 acc1[2][6];
        #pragma unroll
        for (int fi = 0; fi < 2; ++fi)
        #pragma unroll
        for (int pj = 0; pj < 6; ++pj){
            acc1[fi][pj][0] = b4[fi][0]; acc1[fi][pj][1] = b4[fi][1];
            acc1[fi][pj][2] = b4[fi][2]; acc1[fi][pj][3] = b4[fi][3];
        }
        for (int ks = 0; ks < 8; ++ks){
            const int k0 = ks * 32 + lh * 8;
            short8v a0 = *(const short8v*)(w1s + (size_t)(fbase + lr) * 256 + k0);
            short8v a1 = *(const short8v*)(w1s + (size_t)(fbase + 16 + lr) * 256 + k0);
            #pragma unroll
            for (int pj = 0; pj < 6; ++pj){
                short8v bb = *(const short8v*)(x1s + (pj * 16 + lr) * 264 + k0);
                acc1[0][pj] = __builtin_amdgcn_mfma_f32_16x16x32_bf16(a0, bb, acc1[0][pj], 0, 0, 0);
                acc1[1][pj] = __builtin_amdgcn_mfma_f32_16x16x32_bf16(a1, bb, acc1[1][pj], 0, 0, 0);
            }
        }
        #pragma unroll
        for (int fi = 0; fi < 2; ++fi)
        #pragma unroll
        for (int pj = 0; pj < 6; ++pj){
            int p = pj * 16 + lr;
            int fl = w * 32 + fi * 16 + lh * 4;
            short4v pk;
            #pragma unroll
            for (int r = 0; r < 4; ++r)
                pk[r] = (short)f2bf(fast_gelu(acc1[fi][pj][r]));
            *(short4v*)&ffs[p * 136 + fl] = pk;
        }
        __syncthreads();
        for (int ks = 0; ks < 4; ++ks){
            const int k0 = ks * 32 + lh * 8;
            short8v a2[4];
            #pragma unroll
            for (int ci = 0; ci < 4; ++ci)
                a2[ci] = *(const short8v*)(w2bf + (size_t)(cw + ci * 16 + lr) * 1024 + fc * 128 + k0);
            #pragma unroll
            for (int pj = 0; pj < 6; ++pj){
                short8v bb = *(const short8v*)(ffs + (pj * 16 + lr) * 136 + k0);
                #pragma unroll
                for (int ci = 0; ci < 4; ++ci)
                    acc2[ci][pj] = __builtin_amdgcn_mfma_f32_16x16x32_bf16(a2[ci], bb, acc2[ci][pj], 0, 0, 0);
            }
        }
        __syncthreads();
    }
    float sv[16], tv[16];
    #pragma unroll
    for (int ci = 0; ci < 4; ++ci)
    #pragma unroll
    for (int r = 0; r < 4; ++r){
        int c = cw + ci * 16 + lh * 4 + r;
        sv[ci * 4 + r] = s1[c];
        tv[ci * 4 + r] = t1[c];
    }
    float cs[16], cq[16];
    #pragma unroll
    for (int i = 0; i < 16; ++i){ cs[i] = 0.f; cq[i] = 0.f; }
    #pragma unroll
    for (int ci = 0; ci < 4; ++ci)
    #pragma unroll
    for (int pj = 0; pj < 6; ++pj){
        int p = pj * 16 + lr;
        if (p < 81){
            int c = cw + ci * 16 + lh * 4;
            short4v yv = *(const short4v*)&x1s[p * 264 + c];
            #pragma unroll
            for (int r = 0; r < 4; ++r){
                float x1 = fmaf(bf2f((unsigned short)yv[r]), sv[ci * 4 + r], tv[ci * 4 + r]);
                float z = acc2[ci][pj][r] + x1;
                zb[(c + r) * 81 + p] = z;
                cs[ci * 4 + r] += z;
                cq[ci * 4 + r] += z * z;
            }
        }
    }
    #pragma unroll
    for (int i = 0; i < 16; ++i){
        cs[i] = wave16_red(cs[i]);
        cq[i] = wave16_red(cq[i]);
    }
    if (lr == 0){
        #pragma unroll
        for (int ci = 0; ci < 4; ++ci)
        #pragma unroll
        for (int r = 0; r < 4; ++r){
            int c = cw + ci * 16 + lh * 4 + r;
            p2[(size_t)c * 2048 + b]         = cs[ci * 4 + r];
            p2[(size_t)(256 + c) * 2048 + b] = cq[ci * 4 + r];
        }
    }
}

// ---------------- OLD BN apply (fallback) ----------------
__global__ __launch_bounds__(256) void k_bnapply(float* __restrict__ z,
                                                 const float* __restrict__ mean, const float* __restrict__ rstd,
                                                 const float* __restrict__ g, const float* __restrict__ bia,
                                                 unsigned int n){
    unsigned int i = blockIdx.x * 256u + threadIdx.x;
    unsigned int st = gridDim.x * 256u;
    for (; i < n; i += st){
        int c = (int)((i / 81u) & 255u);
        float v = z[i];
        z[i] = (v - mean[c]) * rstd[c] * g[c] + bia[c];
    }
}

// ---------------- NEW BN apply via (s,t) ----------------
__global__ __launch_bounds__(256) void k_bnapply_st(float* __restrict__ z,
                                                    const float* __restrict__ s2, const float* __restrict__ t2,
                                                    unsigned int n){
    unsigned int i = blockIdx.x * 256u + threadIdx.x;
    unsigned int st = gridDim.x * 256u;
    for (; i < n; i += st){
        int c = (int)((i / 81u) & 255u);
        z[i] = fmaf(z[i], s2[c], t2[c]);
    }
}

extern "C" void kernel_launch(void* const* d_in, const int* in_sizes, int n_in,
                              void* d_out, int out_size, void* d_ws, size_t ws_size,
                              hipStream_t stream){
    const float* x     = (const float*)d_in[0];
    const float* qkvw  = (const float*)d_in[1];
    const float* relw1 = (const float*)d_in[2];
    const float* relw2 = (const float*)d_in[3];
    const float* ow    = (const float*)d_in[4];
    const float* ffw1  = (const float*)d_in[5];
    const float* ffw2  = (const float*)d_in[6];
    const float* g1    = (const float*)d_in[7];
    const float* b1    = (const float*)d_in[8];
    const float* g2    = (const float*)d_in[9];
    const float* b2    = (const float*)d_in[10];
    float* out = (float*)d_out;
    char* ws = (char*)d_ws;

    unsigned short* w1rel = (unsigned short*)ws;             // 1,327,104 B
    float* h     = (float*)(ws + 1327104);                   // 262,144 B
    float* mean1 = (float*)(ws + 1589248);
    float* rstd1 = (float*)(ws + 1590272);
    float* mean2 = (float*)(ws + 1591296);
    float* rstd2 = (float*)(ws + 1592320);
    unsigned short* w1bf  = (unsigned short*)(ws + 1593344); // 524,288 B (fallback)
    unsigned short* w2bf  = (unsigned short*)(ws + 2117632); // 524,288 B
    unsigned short* qkvwb = (unsigned short*)(ws + 2641920); // 49,152 B
    unsigned short* owb   = (unsigned short*)(ws + 2691072); // 131,072 B
    unsigned short* w1s   = (unsigned short*)(ws + 2822144); // 524,288 B
    float* bias1 = (float*)(ws + 3346432);                   // 4,096 B
    float* s1    = (float*)(ws + 3350528);
    float* t1    = (float*)(ws + 3351552);
    float* s2    = (float*)(ws + 3352576);
    float* t2    = (float*)(ws + 3353600);
    float* p1    = (float*)(ws + 3354624);                   // 4,194,304 B
    float* p2    = (float*)(ws + 7548928);                   // 4,194,304 B
    unsigned short* yT = (unsigned short*)(ws + 11743232);   // 103,809,024 B
    const size_t WS_NEED = 11743232ull + 103809024ull;
    float* p_h = p1;   // reuses p1 region (dead until k_attn_oproj writes it)

    hipLaunchKernelGGL(k_f2bf, dim3(1024), dim3(256), 0, stream, relw1, w1rel, 663552);
    hipLaunchKernelGGL(k_f2bf, dim3(256),  dim3(256), 0, stream, ffw2, w2bf, 262144);
    hipLaunchKernelGGL(k_f2bf, dim3(96),   dim3(256), 0, stream, qkvw, qkvwb, 24576);
    hipLaunchKernelGGL(k_f2bf, dim3(256),  dim3(256), 0, stream, ow, owb, 65536);

    if (ws_size >= WS_NEED){
        hipLaunchKernelGGL(k_h_mfma, dim3(512), dim3(256), 0, stream, x, w1rel, p_h);
        hipLaunchKernelGGL(k_h_red,  dim3(256), dim3(256), 0, stream, p_h, h);
        hipLaunchKernelGGL(k_attn_oproj, dim3(2048), dim3(256), 0, stream, x, qkvwb, relw2, h, owb, yT, p1);
        hipLaunchKernelGGL(k_red,      dim3(256),  dim3(256), 0, stream, p1, g1, b1, s1, t1);
        hipLaunchKernelGGL(k_w1scale,  dim3(1024), dim3(256), 0, stream, ffw1, s1, w1s);
        hipLaunchKernelGGL(k_bias1,    dim3(1024), dim3(64),  0, stream, ffw1, t1, bias1);
        hipLaunchKernelGGL(k_ff_v2,    dim3(2048), dim3(256), 0, stream, yT, w1s, w2bf, bias1, s1, t1, out, p2);
        hipLaunchKernelGGL(k_red,      dim3(256),  dim3(256), 0, stream, p2, g2, b2, s2, t2);
        hipLaunchKernelGGL(k_bnapply_st, dim3(2048), dim3(256), 0, stream, out, s2, t2, (unsigned int)NTOT);
    } else {
        hipLaunchKernelGGL(k_h, dim3(2048), dim3(256), 0, stream, x, w1rel, h);
        hipLaunchKernelGGL(k_attn_mfma, dim3(2048), dim3(256), 0, stream, x, qkvwb, relw2, h, out);
        hipLaunchKernelGGL(k_f2bf, dim3(256), dim3(256), 0, stream, ffw1, w1bf, 262144);
        hipLaunchKernelGGL(k_oproj_mfma, dim3(2048), dim3(256), 0, stream, x, owb, out);
        hipLaunchKernelGGL(k_stats, dim3(256), dim3(256), 0, stream, out, mean1, rstd1);
        hipLaunchKernelGGL(k_ff_mfma, dim3(2048), dim3(256), 0, stream, w1bf, w2bf, mean1, rstd1, g1, b1, out);
        hipLaunchKernelGGL(k_stats, dim3(256), dim3(256), 0, stream, out, mean2, rstd2);
        hipLaunchKernelGGL(k_bnapply, dim3(2048), dim3(256), 0, stream, out, mean2, rstd2, g2, b2, (unsigned int)NTOT);
    }
}